// Round 13
// baseline (570.568 us; speedup 1.0000x reference)
//
#include <hip/hip_runtime.h>
#include <math.h>

// ---------------------------------------------------------------------------
// LowToHighMultiLevelReconstruction — round 13.
// Changes vs round 12 (attention only; arithmetic bit-identical):
//  1. Dual-row interleaved ballot top-k: two independent threshold chains
//     (rows j, j+1) share one bit loop — hides the v_cmp->ballot->s_bcnt
//     serial latency. Early-exit kept via per-row wave-uniform done flags.
//  2. s_setprio(1) around sim/PV MFMA clusters (T5; attn-applicable).
// ---------------------------------------------------------------------------

#define GS   128
#define WIN  256        // 2*GS
#define DQK  64
#define DV   64
#define DIMC 512
#define NTOK 8192
#define WSZ  262144     // 512*512 elements per weight matrix

typedef unsigned long long u64;
typedef unsigned short u16;
typedef __attribute__((ext_vector_type(8))) short bf16x8;
typedef __attribute__((ext_vector_type(4))) float f32x4;

__device__ __forceinline__ u16 f2b(float f) {     // f32 -> bf16 RNE
  unsigned u = __float_as_uint(f);
  u = (u + 0x7fffu + ((u >> 16) & 1u)) >> 16;
  return (u16)u;
}
__device__ __forceinline__ float b2f(u16 h) { return __uint_as_float(((unsigned)h) << 16); }
__device__ __forceinline__ float b2f_lo(unsigned u) { return __uint_as_float(u << 16); }
__device__ __forceinline__ float b2f_hi(unsigned u) { return __uint_as_float(u & 0xffff0000u); }

__device__ __forceinline__ float wave_max64(float v) {
#pragma unroll
  for (int m = 1; m < 64; m <<= 1) v = fmaxf(v, __shfl_xor(v, m, 64));
  return v;
}
__device__ __forceinline__ float wave_sum64(float v) {
#pragma unroll
  for (int m = 1; m < 64; m <<= 1) v += __shfl_xor(v, m, 64);
  return v;
}

// --------------------------------------------- pooling (writes split bf16) --
__global__ void pool_split_kernel(const float* __restrict__ x,
                                  const float* __restrict__ scores,
                                  u16* __restrict__ xhi, u16* __restrict__ xlo,
                                  float* __restrict__ sl, int n, int scale) {
  int npool = n / scale;
  int total = 2 * npool * (DIMC / 4);
  int tid = blockIdx.x * blockDim.x + threadIdx.x;
  if (tid >= total) return;
  int c4 = tid & 127;
  int g  = (tid >> 7) % npool;
  int b  = (tid >> 7) / npool;
  const float* xp = x + ((size_t)b * n + (size_t)g * scale) * DIMC + c4 * 4;
  float ax = 0.f, ay = 0.f, az = 0.f, aw = 0.f, wsum = 0.f, ssum = 0.f;
  for (int s = 0; s < scale; ++s) {
    float sc = scores[(size_t)b * n + (size_t)g * scale + s];
    float w  = fmaxf(sc, 1e-6f);
    float4 xv = *reinterpret_cast<const float4*>(xp + (size_t)s * DIMC);
    ax += xv.x * w; ay += xv.y * w; az += xv.z * w; aw += xv.w * w;
    wsum += w; ssum += sc;
  }
  float o[4] = { ax / wsum, ay / wsum, az / wsum, aw / wsum };
  ushort4 h, l;
  h.x = f2b(o[0]); h.y = f2b(o[1]); h.z = f2b(o[2]); h.w = f2b(o[3]);
  l.x = f2b(o[0] - b2f(h.x)); l.y = f2b(o[1] - b2f(h.y));
  l.z = f2b(o[2] - b2f(h.z)); l.w = f2b(o[3] - b2f(h.w));
  size_t off = ((size_t)b * npool + g) * DIMC + c4 * 4;
  *reinterpret_cast<ushort4*>(xhi + off) = h;
  *reinterpret_cast<ushort4*>(xlo + off) = l;
  if (c4 == 0) sl[(size_t)b * npool + g] = ssum / (float)scale;
}

// --------------------------------------------------- raw x split (lvl 2) ----
__global__ void asplit_kernel(const float* __restrict__ x,
                              u16* __restrict__ xhi, u16* __restrict__ xlo) {
  int tid = blockIdx.x * 256 + threadIdx.x;     // over 2*NTOK*128 float4s
  float4 v = *reinterpret_cast<const float4*>(x + (size_t)tid * 4);
  ushort4 h, l;
  h.x = f2b(v.x); h.y = f2b(v.y); h.z = f2b(v.z); h.w = f2b(v.w);
  l.x = f2b(v.x - b2f(h.x)); l.y = f2b(v.y - b2f(h.y));
  l.z = f2b(v.z - b2f(h.z)); l.w = f2b(v.w - b2f(h.w));
  *reinterpret_cast<ushort4*>(xhi + (size_t)tid * 4) = h;
  *reinterpret_cast<ushort4*>(xlo + (size_t)tid * 4) = l;
}

__global__ void pool_label_kernel(const int* __restrict__ labels,
                                  const float* __restrict__ scores,
                                  int* __restrict__ ll, int n, int scale) {
  int npool = n / scale;
  int tid = blockIdx.x * blockDim.x + threadIdx.x;
  if (tid >= 2 * npool) return;
  int b = tid / npool, g = tid % npool;
  float counts[4] = {0.f, 0.f, 0.f, 0.f};
  float ssum[4]   = {0.f, 0.f, 0.f, 0.f};
  int firstp[4];
  for (int c = 0; c < 4; ++c) firstp[c] = scale;
  for (int s = 0; s < scale; ++s) {
    int   L = labels[(size_t)b * n + (size_t)g * scale + s];
    float S = scores[(size_t)b * n + (size_t)g * scale + s];
    counts[L] += 1.0f;
    ssum[L]   += S;
    if (s < firstp[L]) firstp[L] = s;
  }
  float cmax = fmaxf(fmaxf(counts[0], counts[1]), fmaxf(counts[2], counts[3]));
  float s2[4];
  for (int c = 0; c < 4; ++c) s2[c] = (counts[c] == cmax) ? ssum[c] : -1e9f;
  float smax = fmaxf(fmaxf(s2[0], s2[1]), fmaxf(s2[2], s2[3]));
  int fp[4];
  for (int c = 0; c < 4; ++c) fp[c] = (s2[c] == smax) ? firstp[c] : scale;
  int best = 0, bv = fp[0];
  for (int c = 1; c < 4; ++c) if (fp[c] < bv) { bv = fp[c]; best = c; }
  ll[(size_t)b * npool + g] = best;
}

// ------------------------------------------------------------ keep (focus) --
__global__ void keep_kernel(const int* __restrict__ ll, const float* __restrict__ sl,
                            int* __restrict__ keep, int total) {
  int tid = blockIdx.x * blockDim.x + threadIdx.x;
  if (tid >= total) return;
  const int*   lp = ll + (size_t)tid * GS;
  const float* sp = sl + (size_t)tid * GS;
  float counts[4] = {0.f, 0.f, 0.f, 0.f};
  for (int i = 0; i < GS; ++i) counts[lp[i]] += 1.f;
  int mode = 0; float bv = counts[0];
  for (int c = 1; c < 4; ++c) if (counts[c] > bv) { bv = counts[c]; mode = c; }
  float pm = 0.f, mean = 0.f;
  for (int i = 0; i < GS; ++i) { pm += (lp[i] == mode) ? 1.f : 0.f; mean += sp[i]; }
  float purity = pm / (float)GS;
  mean /= (float)GS;
  float var = 0.f;
  for (int i = 0; i < GS; ++i) { float d = sp[i] - mean; var += d * d; }
  var /= (float)GS;
  float focus = 0.5f + 0.25f * purity - 0.25f * var;
  focus = fminf(fmaxf(focus, 0.25f), 0.75f);
  keep[tid] = (int)ceilf(focus * (float)WIN);
}

// --------------------- ALL weight transpose+split in one launch (12 mats) ---
__global__ __launch_bounds__(256) void wprep_kernel(
    const float* __restrict__ Wq, const float* __restrict__ Wk,
    const float* __restrict__ Wv, const float* __restrict__ Wp,
    u16* __restrict__ whiAll, u16* __restrict__ wloAll) {
  __shared__ float tile[32][33];
  int blk = blockIdx.x;            // 0..3071
  int mat = blk >> 8;              // 0..11
  int sub = blk & 255;
  int kind = mat / 3, lvl = mat % 3;
  const float* W = (kind == 0 ? Wq : kind == 1 ? Wk : kind == 2 ? Wv : Wp)
                   + (size_t)lvl * WSZ;
  u16* bthi = whiAll + (size_t)mat * WSZ;
  u16* btlo = (mat < 6) ? (wloAll + (size_t)mat * WSZ) : nullptr;

  int bx = sub & 15;               // n block
  int by = sub >> 4;               // k block
  int tx = threadIdx.x & 31;
  int ty = threadIdx.x >> 5;       // 0..7
#pragma unroll
  for (int i = 0; i < 4; ++i) {
    int kk = ty + i * 8;
    tile[kk][tx] = W[(size_t)(by * 32 + kk) * 512 + bx * 32 + tx];
  }
  __syncthreads();
#pragma unroll
  for (int i = 0; i < 4; ++i) {
    int nn = ty + i * 8;
    float v = tile[tx][nn];        // = W[by*32+tx][bx*32+nn]
    u16 h = f2b(v);
    size_t o = (size_t)(bx * 32 + nn) * 512 + by * 32 + tx;
    bthi[o] = h;
    if (btlo) btlo[o] = f2b(v - b2f(h));
  }
}

// ---------------------------------------------------- fused q/k/v GEMM ------
// grid (12, M/128): sel=blockIdx.x>>2 (0=q split, 1=k split, 2=v hi-only).
// q,k emitted as pre-split bf16 hi/lo; v as bf16 hi.
__global__ __launch_bounds__(256) void qkv_gemm_kernel(
    const u16* __restrict__ Ahi, const u16* __restrict__ Alo,
    const u16* __restrict__ whiAll, const u16* __restrict__ wloAll,
    u16* __restrict__ qhi, u16* __restrict__ qlo,
    u16* __restrict__ khi, u16* __restrict__ klo, u16* __restrict__ vbf,
    int M, int lvl) {
  __shared__ u16 smem[4 * 4096];
  u16* sAhi = smem;
  u16* sBhi = smem + 4096;
  u16* sAlo = smem + 2 * 4096;
  u16* sBlo = smem + 3 * 4096;

  int sel = blockIdx.x >> 2;       // 0=q, 1=k, 2=v
  int cx  = blockIdx.x & 3;
  bool split = (sel < 2);
  const u16* Bh = whiAll + (size_t)(sel * 3 + lvl) * WSZ;
  const u16* Bl = wloAll + (size_t)(sel * 3 + lvl) * WSZ;   // valid only sel<2

  int t = threadIdx.x, lane = t & 63, wave = t >> 6;
  int wr = wave >> 1, wc = wave & 1;
  int row0 = blockIdx.y * 128, col0 = cx * 128;

  int srow = (lane >> 2);
  int schk = (lane & 3) * 8;

  const f32x4 zero = { 0.f, 0.f, 0.f, 0.f };
  f32x4 acc[4][4];
#pragma unroll
  for (int i = 0; i < 4; ++i)
#pragma unroll
    for (int j = 0; j < 4; ++j) acc[i][j] = zero;

  for (int k0 = 0; k0 < 512; k0 += 32) {
#pragma unroll
    for (int j = 0; j < 2; ++j) {
      int r = wave * 32 + j * 16 + srow;
      const u16* gA = Ahi + (size_t)(row0 + r) * 512 + k0 + schk;
      const u16* gB = Bh + (size_t)(col0 + r) * 512 + k0 + schk;
      __builtin_amdgcn_global_load_lds(
          (const __attribute__((address_space(1))) void*)gA,
          (__attribute__((address_space(3))) void*)&sAhi[(wave * 32 + j * 16) * 32],
          16, 0, 0);
      __builtin_amdgcn_global_load_lds(
          (const __attribute__((address_space(1))) void*)gB,
          (__attribute__((address_space(3))) void*)&sBhi[(wave * 32 + j * 16) * 32],
          16, 0, 0);
      if (split) {
        const u16* gAl = Alo + (size_t)(row0 + r) * 512 + k0 + schk;
        const u16* gBl = Bl + (size_t)(col0 + r) * 512 + k0 + schk;
        __builtin_amdgcn_global_load_lds(
            (const __attribute__((address_space(1))) void*)gAl,
            (__attribute__((address_space(3))) void*)&sAlo[(wave * 32 + j * 16) * 32],
            16, 0, 0);
        __builtin_amdgcn_global_load_lds(
            (const __attribute__((address_space(1))) void*)gBl,
            (__attribute__((address_space(3))) void*)&sBlo[(wave * 32 + j * 16) * 32],
            16, 0, 0);
      }
    }
    __syncthreads();

    int fr = lane & 15;
    int kf = (lane >> 4) * 8;
    bf16x8 ah[4], bh[4], al[4], bl[4];
#pragma unroll
    for (int i = 0; i < 4; ++i) {
      ah[i] = *reinterpret_cast<const bf16x8*>(&sAhi[(wr * 64 + i * 16 + fr) * 32 + kf]);
      bh[i] = *reinterpret_cast<const bf16x8*>(&sBhi[(wc * 64 + i * 16 + fr) * 32 + kf]);
      if (split) {
        al[i] = *reinterpret_cast<const bf16x8*>(&sAlo[(wr * 64 + i * 16 + fr) * 32 + kf]);
        bl[i] = *reinterpret_cast<const bf16x8*>(&sBlo[(wc * 64 + i * 16 + fr) * 32 + kf]);
      }
    }
#pragma unroll
    for (int i = 0; i < 4; ++i)
#pragma unroll
      for (int j = 0; j < 4; ++j) {
        acc[i][j] = __builtin_amdgcn_mfma_f32_16x16x32_bf16(ah[i], bh[j], acc[i][j], 0, 0, 0);
        if (split) {
          acc[i][j] = __builtin_amdgcn_mfma_f32_16x16x32_bf16(ah[i], bl[j], acc[i][j], 0, 0, 0);
          acc[i][j] = __builtin_amdgcn_mfma_f32_16x16x32_bf16(al[i], bh[j], acc[i][j], 0, 0, 0);
        }
      }
    __syncthreads();
  }

  int ccol = col0 + wc * 64 + (lane & 15);
  int crow = row0 + wr * 64 + (lane >> 4) * 4;
  if (sel == 2) {
#pragma unroll
    for (int i = 0; i < 4; ++i)
#pragma unroll
      for (int r = 0; r < 4; ++r) {
        int gr = crow + i * 16 + r;
#pragma unroll
        for (int j = 0; j < 4; ++j)
          vbf[(size_t)gr * 512 + ccol + j * 16] = f2b(acc[i][j][r]);
      }
  } else {
    u16* Ch = (sel == 0) ? qhi : khi;
    u16* Cl = (sel == 0) ? qlo : klo;
#pragma unroll
    for (int i = 0; i < 4; ++i)
#pragma unroll
      for (int r = 0; r < 4; ++r) {
        int gr = crow + i * 16 + r;
#pragma unroll
        for (int j = 0; j < 4; ++j) {
          float v = acc[i][j][r];
          u16 hh = f2b(v);
          Ch[(size_t)gr * 512 + ccol + j * 16] = hh;
          Cl[(size_t)gr * 512 + ccol + j * 16] = f2b(v - b2f(hh));
        }
      }
  }
}

// --------------------------------------------------- Wp GEMM (scatter) ------
template<int EMODE>
__global__ __launch_bounds__(256) void wp_gemm_kernel(
    const u16* __restrict__ Ahi, const u16* __restrict__ Bthi,
    float* __restrict__ C, const int* __restrict__ idx,
    int M, int scale, int n_l) {
  __shared__ u16 smem[2 * 4096];
  u16* sAhi = smem;
  u16* sBhi = smem + 4096;

  int t = threadIdx.x, lane = t & 63, wave = t >> 6;
  int wr = wave >> 1, wc = wave & 1;
  int row0 = blockIdx.y * 128, col0 = blockIdx.x * 128;

  int srow = (lane >> 2);
  int schk = (lane & 3) * 8;

  const f32x4 zero = { 0.f, 0.f, 0.f, 0.f };
  f32x4 acc[4][4];
#pragma unroll
  for (int i = 0; i < 4; ++i)
#pragma unroll
    for (int j = 0; j < 4; ++j) acc[i][j] = zero;

  for (int k0 = 0; k0 < 512; k0 += 32) {
#pragma unroll
    for (int j = 0; j < 2; ++j) {
      int r = wave * 32 + j * 16 + srow;
      const u16* gA = Ahi + (size_t)(row0 + r) * 512 + k0 + schk;
      const u16* gB = Bthi + (size_t)(col0 + r) * 512 + k0 + schk;
      __builtin_amdgcn_global_load_lds(
          (const __attribute__((address_space(1))) void*)gA,
          (__attribute__((address_space(3))) void*)&sAhi[(wave * 32 + j * 16) * 32],
          16, 0, 0);
      __builtin_amdgcn_global_load_lds(
          (const __attribute__((address_space(1))) void*)gB,
          (__attribute__((address_space(3))) void*)&sBhi[(wave * 32 + j * 16) * 32],
          16, 0, 0);
    }
    __syncthreads();

    int fr = lane & 15;
    int kf = (lane >> 4) * 8;
    bf16x8 ah[4], bh[4];
#pragma unroll
    for (int i = 0; i < 4; ++i) {
      ah[i] = *reinterpret_cast<const bf16x8*>(&sAhi[(wr * 64 + i * 16 + fr) * 32 + kf]);
      bh[i] = *reinterpret_cast<const bf16x8*>(&sBhi[(wc * 64 + i * 16 + fr) * 32 + kf]);
    }
#pragma unroll
    for (int i = 0; i < 4; ++i)
#pragma unroll
      for (int j = 0; j < 4; ++j)
        acc[i][j] = __builtin_amdgcn_mfma_f32_16x16x32_bf16(ah[i], bh[j], acc[i][j], 0, 0, 0);
    __syncthreads();
  }

  int ccol = col0 + wc * 64 + (lane & 15);
  int crow = row0 + wr * 64 + (lane >> 4) * 4;
#pragma unroll
  for (int i = 0; i < 4; ++i) {
#pragma unroll
    for (int r = 0; r < 4; ++r) {
      int gr = crow + i * 16 + r;
      int bb = gr / n_l, rr = gr - bb * n_l;
      for (int s = 0; s < scale; ++s) {
        int dst = idx[(size_t)bb * NTOK + (size_t)rr * scale + s];
        float* p = C + ((size_t)bb * NTOK + dst) * 512 + ccol;
        if (EMODE == 3) {
#pragma unroll
          for (int j = 0; j < 4; ++j) p[j * 16] += acc[i][j][r];
        } else {
#pragma unroll
          for (int j = 0; j < 4; ++j) p[j * 16] = acc[i][j][r];
        }
      }
    }
  }
}

// ----------------------------------------------- fused windowed attention ---
// TWO blocks (512 thr, 8 waves) per (b,g,h), each owns 64 q-rows (p=bid&1).
// Phase A: sim via split-bf16 MFMA (K/Q hi/lo staged per d-half), setprio(1).
// S -> LDS f32 [32][264] in two q-halves -> DUAL-ROW interleaved ballot
// top-k (two independent chains per bit loop, early-exit per row) ->
// softmax (unmasked max, early for ILP) -> prior mix (pre-normalized).
// Phase B: PV via MFMA with per-j-half P (P_half[64][136]) + Vt[64][136].
__global__ __launch_bounds__(512) void attn_fused_kernel(
    const u16* __restrict__ qhi, const u16* __restrict__ qlo,
    const u16* __restrict__ khi, const u16* __restrict__ klo,
    const u16* __restrict__ vbf, const int* __restrict__ keepArr,
    const u16* __restrict__ prevA, u16* __restrict__ curA,
    const float* __restrict__ betaL, u16* __restrict__ outp,
    int lvl, int n_l, int ng, int prev_ng) {
  __shared__ u64 smem8[5120];             // 40960 B
  u16*   Khi_s  = (u16*)smem8;            // [256][32] @0     (phase A stage)
  u16*   Klo_s  = Khi_s + 256 * 32;       // @16384
  u16*   Qhi_s  = Klo_s + 256 * 32;       // [64][32] @32768
  u16*   Qlo_s  = Qhi_s + 64 * 32;        // @36864 (..40960)
  float* S_lds  = (float*)smem8;          // [32][264] f32 @0..33792
  u16*   P_half = (u16*)smem8;            // [64][136] @0..17408   (phase B)
  u16*   Vt     = P_half + 64 * 136;      // [64][136] @17408..34816

  int t = threadIdx.x;
  int lane = t & 63, wave = t >> 6;
  int bid = blockIdx.x;
  int p   = bid & 1;
  int h   = (bid >> 1) & 7;
  int gl  = bid >> 4;
  int g   = gl % ng;
  int b   = gl / ng;
  int bgh = bid >> 1;                     // (b,g,h) index for attn state

  const u16* qhbase = qhi + ((size_t)b * n_l + (size_t)g * GS + p * 64) * DIMC + h * DQK;
  const u16* qlbase = qlo + ((size_t)b * n_l + (size_t)g * GS + p * 64) * DIMC + h * DQK;
  const u16* khbase = khi + (size_t)b * n_l * DIMC + h * DQK;
  const u16* klbase = klo + (size_t)b * n_l * DIMC + h * DQK;

  // ---- phase A: sim via MFMA (3-product split), acc over 2 d-halves ----
  int qt  = wave >> 1;                    // q-tile 0..3
  int ktb = (wave & 1) * 8;               // key-tile base 0 or 8
  f32x4 acc[8];
#pragma unroll
  for (int i = 0; i < 8; ++i) acc[i] = (f32x4){0.f, 0.f, 0.f, 0.f};

#pragma unroll
  for (int dp = 0; dp < 2; ++dp) {
    if (dp) __syncthreads();              // previous half's frags consumed
    int d0 = dp * 32;
#pragma unroll
    for (int ii = 0; ii < 2; ++ii) {
      int row = wave * 32 + ii * 16 + (lane >> 2);
      int pp = g * GS + row;
      int src = (pp < n_l) ? pp : (2 * n_l - 1 - pp);
      const u16* gH = khbase + (size_t)src * DIMC + d0 + (lane & 3) * 8;
      const u16* gL = klbase + (size_t)src * DIMC + d0 + (lane & 3) * 8;
      __builtin_amdgcn_global_load_lds(
          (const __attribute__((address_space(1))) void*)gH,
          (__attribute__((address_space(3))) void*)&Khi_s[(wave * 32 + ii * 16) * 32],
          16, 0, 0);
      __builtin_amdgcn_global_load_lds(
          (const __attribute__((address_space(1))) void*)gL,
          (__attribute__((address_space(3))) void*)&Klo_s[(wave * 32 + ii * 16) * 32],
          16, 0, 0);
    }
    if (wave < 4) {
      int row = wave * 16 + (lane >> 2);
      const u16* gH = qhbase + (size_t)row * DIMC + d0 + (lane & 3) * 8;
      __builtin_amdgcn_global_load_lds(
          (const __attribute__((address_space(1))) void*)gH,
          (__attribute__((address_space(3))) void*)&Qhi_s[(wave * 16) * 32],
          16, 0, 0);
    } else {
      int row = (wave - 4) * 16 + (lane >> 2);
      const u16* gL = qlbase + (size_t)row * DIMC + d0 + (lane & 3) * 8;
      __builtin_amdgcn_global_load_lds(
          (const __attribute__((address_space(1))) void*)gL,
          (__attribute__((address_space(3))) void*)&Qlo_s[((wave - 4) * 16) * 32],
          16, 0, 0);
    }
    __syncthreads();

    int fr = lane & 15;
    int kf = (lane >> 4) * 8;
    bf16x8 bqh = *reinterpret_cast<const bf16x8*>(&Qhi_s[(qt * 16 + fr) * 32 + kf]);
    bf16x8 bql = *reinterpret_cast<const bf16x8*>(&Qlo_s[(qt * 16 + fr) * 32 + kf]);
    __builtin_amdgcn_s_setprio(1);
#pragma unroll
    for (int kt = 0; kt < 8; ++kt) {
      bf16x8 akh = *reinterpret_cast<const bf16x8*>(&Khi_s[((ktb + kt) * 16 + fr) * 32 + kf]);
      bf16x8 akl = *reinterpret_cast<const bf16x8*>(&Klo_s[((ktb + kt) * 16 + fr) * 32 + kf]);
      acc[kt] = __builtin_amdgcn_mfma_f32_16x16x32_bf16(akh, bqh, acc[kt], 0, 0, 0);
      acc[kt] = __builtin_amdgcn_mfma_f32_16x16x32_bf16(akh, bql, acc[kt], 0, 0, 0);
      acc[kt] = __builtin_amdgcn_mfma_f32_16x16x32_bf16(akl, bqh, acc[kt], 0, 0, 0);
    }
    __builtin_amdgcn_s_setprio(0);
  }
  __syncthreads();   // staging LDS dead; S_lds may overwrite

  int kp = keepArr[b * ng + g];
  float beta = 0.f, wgt = 0.f;
  int plo_ = 0, phi_ = 0;
  if (lvl > 0) {
    beta = 1.f / (1.f + expf(-betaL[lvl]));
    float pos = ((float)g + 0.5f) * ((float)prev_ng / (float)ng) - 0.5f;
    float fl = floorf(pos);
    plo_ = (int)fl;
    if (plo_ < 0) plo_ = 0;
    if (plo_ > prev_ng - 1) plo_ = prev_ng - 1;
    phi_ = plo_ + 1; if (phi_ > prev_ng - 1) phi_ = prev_ng - 1;
    wgt = fminf(fmaxf(pos - fl, 0.f), 1.f);
  }
  u64 lmask = (1ull << lane) - 1ull;

  // ---- S halves -> dual-row ballot top-k -> softmax -> prior ----
  unsigned atp[8][2];
#pragma unroll
  for (int half = 0; half < 2; ++half) {
    if ((wave >> 2) == half) {
      int ql = ((wave >> 1) & 1) * 16 + (lane & 15);   // q-local within half
#pragma unroll
      for (int kt = 0; kt < 8; ++kt) {
        int key = (ktb + kt) * 16 + (lane >> 4) * 4;
        *reinterpret_cast<f32x4*>(&S_lds[ql * 264 + key]) = acc[kt];
      }
    }
    __syncthreads();
#pragma unroll
    for (int j2 = 0; j2 < 2; ++j2) {
      int jA = j2 * 2, jB = j2 * 2 + 1;
      int lrowA = wave * 4 + jA, lrowB = wave * 4 + jB;
      int iA = p * 64 + half * 32 + lrowA;
      int iB = p * 64 + half * 32 + lrowB;
      f32x4 s4A = *reinterpret_cast<const f32x4*>(&S_lds[lrowA * 264 + lane * 4]);
      f32x4 s4B = *reinterpret_cast<const f32x4*>(&S_lds[lrowB * 264 + lane * 4]);
      float svA[4], svB[4];
      unsigned umA[4], umB[4];
#pragma unroll
      for (int e = 0; e < 4; ++e) {
        svA[e] = s4A[e] * 0.125f;
        svB[e] = s4B[e] * 0.125f;
        unsigned uA = __float_as_uint(svA[e]);
        unsigned uB = __float_as_uint(svB[e]);
        umA[e] = (uA & 0x80000000u) ? ~uA : (uA | 0x80000000u);
        umB[e] = (uB & 0x80000000u) ? ~uB : (uB | 0x80000000u);
      }
      // unmasked row max == masked max; computed early so shuffle latency
      // overlaps the ballot chains (two independent reductions).
      float mA = wave_max64(fmaxf(fmaxf(svA[0], svA[1]), fmaxf(svA[2], svA[3])));
      float mB = wave_max64(fmaxf(fmaxf(svB[0], svB[1]), fmaxf(svB[2], svB[3])));
      // dual-chain bit build: two independent T's share one loop
      unsigned Ta = 0u, Tb = 0u;
      bool dA = false, dB = false;
      for (int bit = 31; bit >= 0; --bit) {
        if (!dA) {
          unsigned T2 = Ta | (1u << bit);
          int c = __popcll(__ballot(umA[0] >= T2)) + __popcll(__ballot(umA[1] >= T2))
                + __popcll(__ballot(umA[2] >= T2)) + __popcll(__ballot(umA[3] >= T2));
          if (c >= kp) { Ta = T2; if (c == kp) dA = true; }
        }
        if (!dB) {
          unsigned T2 = Tb | (1u << bit);
          int c = __popcll(__ballot(umB[0] >= T2)) + __popcll(__ballot(umB[1] >= T2))
                + __popcll(__ballot(umB[2] >= T2)) + __popcll(__ballot(umB[3] >= T2));
          if (c >= kp) { Tb = T2; if (c == kp) dB = true; }
        }
        if (dA && dB) break;
      }
      int cgA = __popcll(__ballot(umA[0] > Ta)) + __popcll(__ballot(umA[1] > Ta))
              + __popcll(__ballot(umA[2] > Ta)) + __popcll(__ballot(umA[3] > Ta));
      int cgB = __popcll(__ballot(umB[0] > Tb)) + __popcll(__ballot(umB[1] > Tb))
              + __popcll(__ballot(umB[2] > Tb)) + __popcll(__ballot(umB[3] > Tb));
      u64 beqA[4], beqB[4];
#pragma unroll
      for (int e = 0; e < 4; ++e) {
        beqA[e] = __ballot(umA[e] == Ta);
        beqB[e] = __ballot(umB[e] == Tb);
      }
      int trA = __popcll(beqA[0] & lmask) + __popcll(beqA[1] & lmask)
              + __popcll(beqA[2] & lmask) + __popcll(beqA[3] & lmask);
      int trB = __popcll(beqB[0] & lmask) + __popcll(beqB[1] & lmask)
              + __popcll(beqB[2] & lmask) + __popcll(beqB[3] & lmask);
      int needA = kp - cgA, needB = kp - cgB;
      bool mskA[4], mskB[4];
      int ownA = 0, ownB = 0;
#pragma unroll
      for (int e = 0; e < 4; ++e) {
        bool eqA = (umA[e] == Ta);
        bool eqB = (umB[e] == Tb);
        mskA[e] = (umA[e] > Ta) || (eqA && (trA + ownA) < needA);
        mskB[e] = (umB[e] > Tb) || (eqB && (trB + ownB) < needB);
        ownA += eqA ? 1 : 0;
        ownB += eqB ? 1 : 0;
      }
      float ezA[4], ezB[4], zsA = 0.f, zsB = 0.f;
#pragma unroll
      for (int e = 0; e < 4; ++e) {
        ezA[e] = mskA[e] ? __expf(svA[e] - mA) : 0.f;
        ezB[e] = mskB[e] ? __expf(svB[e] - mB) : 0.f;
        zsA += ezA[e]; zsB += ezB[e];
      }
      zsA = wave_sum64(zsA);
      zsB = wave_sum64(zsB);
      float atA[4], atB[4];
#pragma unroll
      for (int e = 0; e < 4; ++e) { atA[e] = ezA[e] / zsA; atB[e] = ezB[e] / zsB; }
      if (lvl > 0) {
        size_t bLoA = ((((size_t)b * prev_ng + plo_) * 8 + h) * GS + iA) * WIN + lane * 4;
        size_t bHiA = ((((size_t)b * prev_ng + phi_) * 8 + h) * GS + iA) * WIN + lane * 4;
        size_t bLoB = ((((size_t)b * prev_ng + plo_) * 8 + h) * GS + iB) * WIN + lane * 4;
        size_t bHiB = ((((size_t)b * prev_ng + phi_) * 8 + h) * GS + iB) * WIN + lane * 4;
        uint2 rloA = *reinterpret_cast<const uint2*>(prevA + bLoA);
        uint2 rhiA = *reinterpret_cast<const uint2*>(prevA + bHiA);
        uint2 rloB = *reinterpret_cast<const uint2*>(prevA + bLoB);
        uint2 rhiB = *reinterpret_cast<const uint2*>(prevA + bHiB);
        float plA[4] = { b2f_lo(rloA.x), b2f_hi(rloA.x), b2f_lo(rloA.y), b2f_hi(rloA.y) };
        float phA[4] = { b2f_lo(rhiA.x), b2f_hi(rhiA.x), b2f_lo(rhiA.y), b2f_hi(rhiA.y) };
        float plB[4] = { b2f_lo(rloB.x), b2f_hi(rloB.x), b2f_lo(rloB.y), b2f_hi(rloB.y) };
        float phB[4] = { b2f_lo(rhiB.x), b2f_hi(rhiB.x), b2f_lo(rhiB.y), b2f_hi(rhiB.y) };
#pragma unroll
        for (int e = 0; e < 4; ++e) {
          float prA = fmaxf((1.f - wgt) * plA[e] + wgt * phA[e], 0.f);
          float prB = fmaxf((1.f - wgt) * plB[e] + wgt * phB[e], 0.f);
          atA[e] = (1.f - beta) * atA[e] + beta * prA;
          atB[e] = (1.f - beta) * atB[e] + beta * prB;
        }
      }
      atp[half * 4 + jA][0] = (unsigned)f2b(atA[0]) | ((unsigned)f2b(atA[1]) << 16);
      atp[half * 4 + jA][1] = (unsigned)f2b(atA[2]) | ((unsigned)f2b(atA[3]) << 16);
      atp[half * 4 + jB][0] = (unsigned)f2b(atB[0]) | ((unsigned)f2b(atB[1]) << 16);
      atp[half * 4 + jB][1] = (unsigned)f2b(atB[2]) | ((unsigned)f2b(atB[3]) << 16);
      if (curA != nullptr) {
        uint2 oA = { atp[half * 4 + jA][0], atp[half * 4 + jA][1] };
        uint2 oB = { atp[half * 4 + jB][0], atp[half * 4 + jB][1] };
        *reinterpret_cast<uint2*>(curA + ((size_t)bgh * GS + iA) * WIN + lane * 4) = oA;
        *reinterpret_cast<uint2*>(curA + ((size_t)bgh * GS + iB) * WIN + lane * 4) = oB;
      }
    }
    __syncthreads();   // S half consumed before next half's write / P_half
  }

  // ---- PV via MFMA: O(64x64) = P(64x256) @ V(256x64), per-j-half P ----
  const u16* vbase = vbf + (size_t)b * n_l * DIMC + h * DV;
  int rf   = wave >> 1;                  // q-row frag 0..3
  int cf0  = (wave & 1) * 2;             // dv col frag base {0,2}
  int frow = lane & 15;
  int fk   = (lane >> 4) * 8;
  f32x4 oacc0 = { 0.f, 0.f, 0.f, 0.f };
  f32x4 oacc1 = { 0.f, 0.f, 0.f, 0.f };
  int jlo = t & 15, vd4 = (t >> 4) & 15, jh2 = t >> 8;

#pragma unroll
  for (int jp = 0; jp < 2; ++jp) {
    // stage Vt half (transposed V)
#pragma unroll
    for (int it = 0; it < 4; ++it) {
      int j = (jh2 * 4 + it) * 16 + jlo;           // 0..127
      int pp = g * GS + jp * 128 + j;
      int src = (pp < n_l) ? pp : (2 * n_l - 1 - pp);
      ushort4 vv = *reinterpret_cast<const ushort4*>(vbase + (size_t)src * DIMC + vd4 * 4);
      Vt[(vd4 * 4 + 0) * 136 + j] = vv.x;
      Vt[(vd4 * 4 + 1) * 136 + j] = vv.y;
      Vt[(vd4 * 4 + 2) * 136 + j] = vv.z;
      Vt[(vd4 * 4 + 3) * 136 + j] = vv.w;
    }
    // write this half's P from retained regs (lanes owning these keys)
    if ((lane >> 5) == jp) {
      int kl = (lane & 31) * 4;          // local key base within half
#pragma unroll
      for (int j = 0; j < 4; ++j) {
        uint2 oA = { atp[j][0], atp[j][1] };
        uint2 oB = { atp[4 + j][0], atp[4 + j][1] };
        *reinterpret_cast<uint2*>(&P_half[(wave * 4 + j) * 136 + kl]) = oA;
        *reinterpret_cast<uint2*>(&P_half[(32 + wave * 4 + j) * 136 + kl]) = oB;
      }
    }
    __syncthreads();
    __builtin_amdgcn_s_setprio(1);
#pragma unroll
    for (int ks = 0; ks < 4; ++ks) {
      bf16x8 a  = *reinterpret_cast<const bf16x8*>(&P_half[(rf * 16 + frow) * 136 + ks * 32 + fk]);
      bf16x8 b0 = *reinterpret_cast<const bf16x8*>(&Vt[(cf0 * 16 + frow) * 136 + ks * 32 + fk]);
      bf16x8 b1 = *reinterpret_cast<const bf16x8*>(&Vt[((cf0 + 1) * 16 + frow) * 136 + ks * 32 + fk]);
      oacc0 = __builtin_amdgcn_mfma_f32_16x16x32_bf16(a, b0, oacc0, 0, 0, 0);
      oacc1 = __builtin_amdgcn_mfma_f32_16x16x32_bf16(a, b1, oacc1, 0, 0, 0);
    }
    __builtin_amdgcn_s_setprio(0);
    __syncthreads();
  }

  u16* obase = outp + ((size_t)b * n_l + (size_t)g * GS + p * 64 + rf * 16) * DIMC + h * DV;
#pragma unroll
  for (int rr = 0; rr < 4; ++rr) {
    int qrow = (lane >> 4) * 4 + rr;
    obase[(size_t)qrow * DIMC + cf0 * 16 + frow]       = f2b(oacc0[rr]);
    obase[(size_t)qrow * DIMC + (cf0 + 1) * 16 + frow] = f2b(oacc1[rr]);
  }
}

// ---------------------------------------------------------------------------
extern "C" void kernel_launch(void* const* d_in, const int* in_sizes, int n_in,
                              void* d_out, int out_size, void* d_ws, size_t ws_size,
                              hipStream_t stream) {
  (void)in_sizes; (void)n_in; (void)out_size; (void)ws_size;
  const float* x        = (const float*)d_in[0];
  const int*   labels   = (const int*)d_in[1];
  const float* scores   = (const float*)d_in[2];
  const int*   idx_last = (const int*)d_in[3];
  const float* Wq       = (const float*)d_in[4];
  const float* Wk       = (const float*)d_in[5];
  const float* Wv       = (const float*)d_in[6];
  const float* Wp       = (const float*)d_in[7];
  const float* betaL    = (const float*)d_in[8];
  float* out = (float*)d_out;

  char* w = (char*)d_ws;
  size_t off = 0;
  auto take = [&](size_t bytes) -> char* {
    char* p = w + off;
    off += (bytes + 255) & ~(size_t)255;
    return p;
  };
  u16*   qhib   = (u16*)  take(16777216);   // q hi bf16 (max 16384x512)
  u16*   qlob   = (u16*)  take(16777216);   // q lo
  u16*   khib   = (u16*)  take(16777216);   // k hi
  u16*   klob   = (u16*)  take(16777216);   // k lo
  u16*   vbf    = (u16*)  take(16777216);   // v bf16
  u16*   xhi    = (u16*)  take(16777216);   // A hi / attn-out (disjoint lifetimes)
  u16*   xlo    = (u16*)  take(16777216);   // A lo
  u16*   attnA  = (u16*)  take(16777216);   // lvl0 attn bf16
  u16*   attnB  = (u16*)  take(33554432);   // lvl1 attn bf16
  u16*   whiAll = (u16*)  take(6291456);    // 12 x [512][512] bf16 hi
  u16*   wloAll = (u16*)  take(3145728);    // 6  x [512][512] bf16 lo (q,k)
  float* sl     = (float*)take(32768);
  int*   ll     = (int*)  take(32768);
  int*   keepb  = (int*)  take(1024);
  // total ~178 MB

  // all 12 weight transposes+splits, once
  wprep_kernel<<<3072, 256, 0, stream>>>(Wq, Wk, Wv, Wp, whiAll, wloAll);

  for (int lvl = 0; lvl < 3; ++lvl) {
    int scale = (lvl == 0) ? 4 : (lvl == 1) ? 2 : 1;
    int n_l = NTOK / scale;
    int ng  = n_l / GS;
    int M   = 2 * n_l;
    const int* lin; const float* sin_;
    if (scale > 1) {
      int tfeat = 2 * n_l * (DIMC / 4);
      pool_split_kernel<<<(tfeat + 255) / 256, 256, 0, stream>>>(x, scores, xhi, xlo, sl, NTOK, scale);
      pool_label_kernel<<<(2 * n_l + 255) / 256, 256, 0, stream>>>(labels, scores, ll, NTOK, scale);
      lin = ll; sin_ = sl;
    } else {
      asplit_kernel<<<(2 * NTOK * 128) / 256, 256, 0, stream>>>(x, xhi, xlo);
      lin = labels; sin_ = scores;
    }
    keep_kernel<<<(2 * ng + 127) / 128, 128, 0, stream>>>(lin, sin_, keepb, 2 * ng);

    dim3 gq(12, M / 128);
    qkv_gemm_kernel<<<gq, 256, 0, stream>>>(xhi, xlo, whiAll, wloAll,
                                            qhib, qlob, khib, klob, vbf, M, lvl);

    const u16* prev = (lvl == 0) ? nullptr : ((lvl == 1) ? attnA : attnB);
    u16* cur = (lvl == 0) ? attnA : ((lvl == 1) ? attnB : nullptr);
    // attn output reuses xhi (A-side dead after qkv gemm)
    attn_fused_kernel<<<2 * ng * 8 * 2, 512, 0, stream>>>(qhib, qlob, khib, klob,
                                                          vbf, keepb, prev, cur,
                                                          betaL, xhi, lvl, n_l, ng, ng / 2);

    dim3 gp(4, M / 128);
    const u16* wphi = whiAll + (size_t)(9 + lvl) * WSZ;
    if (lvl == 0)
      wp_gemm_kernel<2><<<gp, 256, 0, stream>>>(xhi, wphi, out, idx_last, M, scale, n_l);
    else
      wp_gemm_kernel<3><<<gp, 256, 0, stream>>>(xhi, wphi, out, idx_last, M, scale, n_l);
  }
}

// Round 14
// 517.854 us; speedup vs baseline: 1.1018x; 1.1018x over previous
//
#include <hip/hip_runtime.h>
#include <math.h>

// ---------------------------------------------------------------------------
// LowToHighMultiLevelReconstruction — round 14.
// Changes vs round 13:
//  1. REVERT dual-row ballot (regression: SALU-branch-bound). Attn = round-12
//     single-chain ballot with early exit; setprio kept (guide T5, attn +).
//  2. lvl0+lvl1 batched: pooled x at row offsets {0, 4096} in shared buffers
//     (12288 rows <= 16384-row buffers, zero extra ws). ONE qkv launch for
//     both levels (grid (12,96) = 1152 blocks), ONE pool_split / pool_label /
//     keep launch (keep covers all 3 levels). Launches 17 -> 13.
// ---------------------------------------------------------------------------

#define GS   128
#define WIN  256        // 2*GS
#define DQK  64
#define DV   64
#define DIMC 512
#define NTOK 8192
#define WSZ  262144     // 512*512 elements per weight matrix

typedef unsigned long long u64;
typedef unsigned short u16;
typedef __attribute__((ext_vector_type(8))) short bf16x8;
typedef __attribute__((ext_vector_type(4))) float f32x4;

__device__ __forceinline__ u16 f2b(float f) {     // f32 -> bf16 RNE
  unsigned u = __float_as_uint(f);
  u = (u + 0x7fffu + ((u >> 16) & 1u)) >> 16;
  return (u16)u;
}
__device__ __forceinline__ float b2f(u16 h) { return __uint_as_float(((unsigned)h) << 16); }
__device__ __forceinline__ float b2f_lo(unsigned u) { return __uint_as_float(u << 16); }
__device__ __forceinline__ float b2f_hi(unsigned u) { return __uint_as_float(u & 0xffff0000u); }

__device__ __forceinline__ float wave_max64(float v) {
#pragma unroll
  for (int m = 1; m < 64; m <<= 1) v = fmaxf(v, __shfl_xor(v, m, 64));
  return v;
}
__device__ __forceinline__ float wave_sum64(float v) {
#pragma unroll
  for (int m = 1; m < 64; m <<= 1) v += __shfl_xor(v, m, 64);
  return v;
}

// ------------------------------ pooling lvl0+lvl1 (writes split bf16) -------
// lvl0: scale 4, npool 2048, rows [0,4096). lvl1: scale 2, npool 4096,
// rows [4096,12288). sl/ll same offsets.
__global__ void pool_split01_kernel(const float* __restrict__ x,
                                    const float* __restrict__ scores,
                                    u16* __restrict__ xhi, u16* __restrict__ xlo,
                                    float* __restrict__ sl) {
  int tid = blockIdx.x * 256 + threadIdx.x;     // 0..1572863
  int scale, npool, rowoff, rest;
  if (tid < 524288) { scale = 4; npool = 2048; rowoff = 0;    rest = tid >> 7; }
  else { tid -= 524288; scale = 2; npool = 4096; rowoff = 4096; rest = tid >> 7; }
  int c4 = tid & 127;
  int g  = rest % npool;
  int b  = rest / npool;
  const float* xp = x + ((size_t)b * NTOK + (size_t)g * scale) * DIMC + c4 * 4;
  float ax = 0.f, ay = 0.f, az = 0.f, aw = 0.f, wsum = 0.f, ssum = 0.f;
  for (int s = 0; s < scale; ++s) {
    float sc = scores[(size_t)b * NTOK + (size_t)g * scale + s];
    float w  = fmaxf(sc, 1e-6f);
    float4 xv = *reinterpret_cast<const float4*>(xp + (size_t)s * DIMC);
    ax += xv.x * w; ay += xv.y * w; az += xv.z * w; aw += xv.w * w;
    wsum += w; ssum += sc;
  }
  float o[4] = { ax / wsum, ay / wsum, az / wsum, aw / wsum };
  ushort4 h, l;
  h.x = f2b(o[0]); h.y = f2b(o[1]); h.z = f2b(o[2]); h.w = f2b(o[3]);
  l.x = f2b(o[0] - b2f(h.x)); l.y = f2b(o[1] - b2f(h.y));
  l.z = f2b(o[2] - b2f(h.z)); l.w = f2b(o[3] - b2f(h.w));
  size_t row = (size_t)rowoff + (size_t)b * npool + g;
  size_t off = row * DIMC + c4 * 4;
  *reinterpret_cast<ushort4*>(xhi + off) = h;
  *reinterpret_cast<ushort4*>(xlo + off) = l;
  if (c4 == 0) sl[row] = ssum / (float)scale;
}

__global__ void pool_label01_kernel(const int* __restrict__ labels,
                                    const float* __restrict__ scores,
                                    int* __restrict__ ll) {
  int tid = blockIdx.x * 256 + threadIdx.x;     // 0..12287
  int scale, npool, rowoff;
  if (tid < 4096) { scale = 4; npool = 2048; rowoff = 0; }
  else { tid -= 4096; scale = 2; npool = 4096; rowoff = 4096; }
  int b = tid / npool, g = tid % npool;
  float counts[4] = {0.f, 0.f, 0.f, 0.f};
  float ssum[4]   = {0.f, 0.f, 0.f, 0.f};
  int firstp[4];
  for (int c = 0; c < 4; ++c) firstp[c] = scale;
  for (int s = 0; s < scale; ++s) {
    int   L = labels[(size_t)b * NTOK + (size_t)g * scale + s];
    float S = scores[(size_t)b * NTOK + (size_t)g * scale + s];
    counts[L] += 1.0f;
    ssum[L]   += S;
    if (s < firstp[L]) firstp[L] = s;
  }
  float cmax = fmaxf(fmaxf(counts[0], counts[1]), fmaxf(counts[2], counts[3]));
  float s2[4];
  for (int c = 0; c < 4; ++c) s2[c] = (counts[c] == cmax) ? ssum[c] : -1e9f;
  float smax = fmaxf(fmaxf(s2[0], s2[1]), fmaxf(s2[2], s2[3]));
  int fp[4];
  for (int c = 0; c < 4; ++c) fp[c] = (s2[c] == smax) ? firstp[c] : scale;
  int best = 0, bv = fp[0];
  for (int c = 1; c < 4; ++c) if (fp[c] < bv) { bv = fp[c]; best = c; }
  ll[rowoff + b * npool + g] = best;
}

// --------------------------------------------------- raw x split (lvl 2) ----
__global__ void asplit_kernel(const float* __restrict__ x,
                              u16* __restrict__ xhi, u16* __restrict__ xlo) {
  int tid = blockIdx.x * 256 + threadIdx.x;     // over 2*NTOK*128 float4s
  float4 v = *reinterpret_cast<const float4*>(x + (size_t)tid * 4);
  ushort4 h, l;
  h.x = f2b(v.x); h.y = f2b(v.y); h.z = f2b(v.z); h.w = f2b(v.w);
  l.x = f2b(v.x - b2f(h.x)); l.y = f2b(v.y - b2f(h.y));
  l.z = f2b(v.z - b2f(h.z)); l.w = f2b(v.w - b2f(h.w));
  *reinterpret_cast<ushort4*>(xhi + (size_t)tid * 4) = h;
  *reinterpret_cast<ushort4*>(xlo + (size_t)tid * 4) = l;
}

// -------------------------- keep for ALL levels in one launch ---------------
// entries: [0,32) lvl0 (pooled), [32,96) lvl1 (pooled), [96,224) lvl2 (raw).
__global__ void keep_all_kernel(const int* __restrict__ ll, const float* __restrict__ sl,
                                const int* __restrict__ labels,
                                const float* __restrict__ scores,
                                int* __restrict__ keep) {
  int tid = blockIdx.x * 128 + threadIdx.x;
  if (tid >= 224) return;
  const int* lp; const float* sp;
  if (tid < 32) {
    int b = tid >> 4, g = tid & 15;
    lp = ll + (b * 2048 + g * GS);
    sp = sl + (b * 2048 + g * GS);
  } else if (tid < 96) {
    int e = tid - 32;
    int b = e >> 5, g = e & 31;
    lp = ll + 4096 + (b * 4096 + g * GS);
    sp = sl + 4096 + (b * 4096 + g * GS);
  } else {
    int e = tid - 96;
    int b = e >> 6, g = e & 63;
    lp = labels + ((size_t)b * NTOK + g * GS);
    sp = scores + ((size_t)b * NTOK + g * GS);
  }
  float counts[4] = {0.f, 0.f, 0.f, 0.f};
  for (int i = 0; i < GS; ++i) counts[lp[i]] += 1.f;
  int mode = 0; float bv = counts[0];
  for (int c = 1; c < 4; ++c) if (counts[c] > bv) { bv = counts[c]; mode = c; }
  float pm = 0.f, mean = 0.f;
  for (int i = 0; i < GS; ++i) { pm += (lp[i] == mode) ? 1.f : 0.f; mean += sp[i]; }
  float purity = pm / (float)GS;
  mean /= (float)GS;
  float var = 0.f;
  for (int i = 0; i < GS; ++i) { float d = sp[i] - mean; var += d * d; }
  var /= (float)GS;
  float focus = 0.5f + 0.25f * purity - 0.25f * var;
  focus = fminf(fmaxf(focus, 0.25f), 0.75f);
  keep[tid] = (int)ceilf(focus * (float)WIN);
}

// --------------------- ALL weight transpose+split in one launch (12 mats) ---
__global__ __launch_bounds__(256) void wprep_kernel(
    const float* __restrict__ Wq, const float* __restrict__ Wk,
    const float* __restrict__ Wv, const float* __restrict__ Wp,
    u16* __restrict__ whiAll, u16* __restrict__ wloAll) {
  __shared__ float tile[32][33];
  int blk = blockIdx.x;            // 0..3071
  int mat = blk >> 8;              // 0..11
  int sub = blk & 255;
  int kind = mat / 3, lvl = mat % 3;
  const float* W = (kind == 0 ? Wq : kind == 1 ? Wk : kind == 2 ? Wv : Wp)
                   + (size_t)lvl * WSZ;
  u16* bthi = whiAll + (size_t)mat * WSZ;
  u16* btlo = (mat < 6) ? (wloAll + (size_t)mat * WSZ) : nullptr;

  int bx = sub & 15;               // n block
  int by = sub >> 4;               // k block
  int tx = threadIdx.x & 31;
  int ty = threadIdx.x >> 5;       // 0..7
#pragma unroll
  for (int i = 0; i < 4; ++i) {
    int kk = ty + i * 8;
    tile[kk][tx] = W[(size_t)(by * 32 + kk) * 512 + bx * 32 + tx];
  }
  __syncthreads();
#pragma unroll
  for (int i = 0; i < 4; ++i) {
    int nn = ty + i * 8;
    float v = tile[tx][nn];        // = W[by*32+tx][bx*32+nn]
    u16 h = f2b(v);
    size_t o = (size_t)(bx * 32 + nn) * 512 + by * 32 + tx;
    bthi[o] = h;
    if (btlo) btlo[o] = f2b(v - b2f(h));
  }
}

// ---------------------------------------------------- fused q/k/v GEMM ------
// grid (12, Y): sel=blockIdx.x>>2 (0=q split, 1=k split, 2=v hi-only).
// blockIdx.y < ysplit -> level lvlA rows y*128; else lvlB rows rowB+(y-ys)*128.
__global__ __launch_bounds__(256) void qkv_gemm_kernel(
    const u16* __restrict__ Ahi, const u16* __restrict__ Alo,
    const u16* __restrict__ whiAll, const u16* __restrict__ wloAll,
    u16* __restrict__ qhi, u16* __restrict__ qlo,
    u16* __restrict__ khi, u16* __restrict__ klo, u16* __restrict__ vbf,
    int lvlA, int lvlB, int ysplit, int rowB) {
  __shared__ u16 smem[4 * 4096];
  u16* sAhi = smem;
  u16* sBhi = smem + 4096;
  u16* sAlo = smem + 2 * 4096;
  u16* sBlo = smem + 3 * 4096;

  int sel = blockIdx.x >> 2;       // 0=q, 1=k, 2=v
  int cx  = blockIdx.x & 3;
  bool split = (sel < 2);
  int ry  = blockIdx.y;
  int lvl   = (ry < ysplit) ? lvlA : lvlB;
  int row0  = (ry < ysplit) ? ry * 128 : rowB + (ry - ysplit) * 128;
  const u16* Bh = whiAll + (size_t)(sel * 3 + lvl) * WSZ;
  const u16* Bl = wloAll + (size_t)(sel * 3 + lvl) * WSZ;   // valid only sel<2

  int t = threadIdx.x, lane = t & 63, wave = t >> 6;
  int wr = wave >> 1, wc = wave & 1;
  int col0 = cx * 128;

  int srow = (lane >> 2);
  int schk = (lane & 3) * 8;

  const f32x4 zero = { 0.f, 0.f, 0.f, 0.f };
  f32x4 acc[4][4];
#pragma unroll
  for (int i = 0; i < 4; ++i)
#pragma unroll
    for (int j = 0; j < 4; ++j) acc[i][j] = zero;

  for (int k0 = 0; k0 < 512; k0 += 32) {
#pragma unroll
    for (int j = 0; j < 2; ++j) {
      int r = wave * 32 + j * 16 + srow;
      const u16* gA = Ahi + (size_t)(row0 + r) * 512 + k0 + schk;
      const u16* gB = Bh + (size_t)(col0 + r) * 512 + k0 + schk;
      __builtin_amdgcn_global_load_lds(
          (const __attribute__((address_space(1))) void*)gA,
          (__attribute__((address_space(3))) void*)&sAhi[(wave * 32 + j * 16) * 32],
          16, 0, 0);
      __builtin_amdgcn_global_load_lds(
          (const __attribute__((address_space(1))) void*)gB,
          (__attribute__((address_space(3))) void*)&sBhi[(wave * 32 + j * 16) * 32],
          16, 0, 0);
      if (split) {
        const u16* gAl = Alo + (size_t)(row0 + r) * 512 + k0 + schk;
        const u16* gBl = Bl + (size_t)(col0 + r) * 512 + k0 + schk;
        __builtin_amdgcn_global_load_lds(
            (const __attribute__((address_space(1))) void*)gAl,
            (__attribute__((address_space(3))) void*)&sAlo[(wave * 32 + j * 16) * 32],
            16, 0, 0);
        __builtin_amdgcn_global_load_lds(
            (const __attribute__((address_space(1))) void*)gBl,
            (__attribute__((address_space(3))) void*)&sBlo[(wave * 32 + j * 16) * 32],
            16, 0, 0);
      }
    }
    __syncthreads();

    int fr = lane & 15;
    int kf = (lane >> 4) * 8;
    bf16x8 ah[4], bh[4], al[4], bl[4];
#pragma unroll
    for (int i = 0; i < 4; ++i) {
      ah[i] = *reinterpret_cast<const bf16x8*>(&sAhi[(wr * 64 + i * 16 + fr) * 32 + kf]);
      bh[i] = *reinterpret_cast<const bf16x8*>(&sBhi[(wc * 64 + i * 16 + fr) * 32 + kf]);
      if (split) {
        al[i] = *reinterpret_cast<const bf16x8*>(&sAlo[(wr * 64 + i * 16 + fr) * 32 + kf]);
        bl[i] = *reinterpret_cast<const bf16x8*>(&sBlo[(wc * 64 + i * 16 + fr) * 32 + kf]);
      }
    }
#pragma unroll
    for (int i = 0; i < 4; ++i)
#pragma unroll
      for (int j = 0; j < 4; ++j) {
        acc[i][j] = __builtin_amdgcn_mfma_f32_16x16x32_bf16(ah[i], bh[j], acc[i][j], 0, 0, 0);
        if (split) {
          acc[i][j] = __builtin_amdgcn_mfma_f32_16x16x32_bf16(ah[i], bl[j], acc[i][j], 0, 0, 0);
          acc[i][j] = __builtin_amdgcn_mfma_f32_16x16x32_bf16(al[i], bh[j], acc[i][j], 0, 0, 0);
        }
      }
    __syncthreads();
  }

  int ccol = col0 + wc * 64 + (lane & 15);
  int crow = row0 + wr * 64 + (lane >> 4) * 4;
  if (sel == 2) {
#pragma unroll
    for (int i = 0; i < 4; ++i)
#pragma unroll
      for (int r = 0; r < 4; ++r) {
        int gr = crow + i * 16 + r;
#pragma unroll
        for (int j = 0; j < 4; ++j)
          vbf[(size_t)gr * 512 + ccol + j * 16] = f2b(acc[i][j][r]);
      }
  } else {
    u16* Ch = (sel == 0) ? qhi : khi;
    u16* Cl = (sel == 0) ? qlo : klo;
#pragma unroll
    for (int i = 0; i < 4; ++i)
#pragma unroll
      for (int r = 0; r < 4; ++r) {
        int gr = crow + i * 16 + r;
#pragma unroll
        for (int j = 0; j < 4; ++j) {
          float v = acc[i][j][r];
          u16 hh = f2b(v);
          Ch[(size_t)gr * 512 + ccol + j * 16] = hh;
          Cl[(size_t)gr * 512 + ccol + j * 16] = f2b(v - b2f(hh));
        }
      }
  }
}

// --------------------------------------------------- Wp GEMM (scatter) ------
template<int EMODE>
__global__ __launch_bounds__(256) void wp_gemm_kernel(
    const u16* __restrict__ Ahi, const u16* __restrict__ Bthi,
    float* __restrict__ C, const int* __restrict__ idx,
    int M, int scale, int n_l) {
  __shared__ u16 smem[2 * 4096];
  u16* sAhi = smem;
  u16* sBhi = smem + 4096;

  int t = threadIdx.x, lane = t & 63, wave = t >> 6;
  int wr = wave >> 1, wc = wave & 1;
  int row0 = blockIdx.y * 128, col0 = blockIdx.x * 128;

  int srow = (lane >> 2);
  int schk = (lane & 3) * 8;

  const f32x4 zero = { 0.f, 0.f, 0.f, 0.f };
  f32x4 acc[4][4];
#pragma unroll
  for (int i = 0; i < 4; ++i)
#pragma unroll
    for (int j = 0; j < 4; ++j) acc[i][j] = zero;

  for (int k0 = 0; k0 < 512; k0 += 32) {
#pragma unroll
    for (int j = 0; j < 2; ++j) {
      int r = wave * 32 + j * 16 + srow;
      const u16* gA = Ahi + (size_t)(row0 + r) * 512 + k0 + schk;
      const u16* gB = Bthi + (size_t)(col0 + r) * 512 + k0 + schk;
      __builtin_amdgcn_global_load_lds(
          (const __attribute__((address_space(1))) void*)gA,
          (__attribute__((address_space(3))) void*)&sAhi[(wave * 32 + j * 16) * 32],
          16, 0, 0);
      __builtin_amdgcn_global_load_lds(
          (const __attribute__((address_space(1))) void*)gB,
          (__attribute__((address_space(3))) void*)&sBhi[(wave * 32 + j * 16) * 32],
          16, 0, 0);
    }
    __syncthreads();

    int fr = lane & 15;
    int kf = (lane >> 4) * 8;
    bf16x8 ah[4], bh[4];
#pragma unroll
    for (int i = 0; i < 4; ++i) {
      ah[i] = *reinterpret_cast<const bf16x8*>(&sAhi[(wr * 64 + i * 16 + fr) * 32 + kf]);
      bh[i] = *reinterpret_cast<const bf16x8*>(&sBhi[(wc * 64 + i * 16 + fr) * 32 + kf]);
    }
#pragma unroll
    for (int i = 0; i < 4; ++i)
#pragma unroll
      for (int j = 0; j < 4; ++j)
        acc[i][j] = __builtin_amdgcn_mfma_f32_16x16x32_bf16(ah[i], bh[j], acc[i][j], 0, 0, 0);
    __syncthreads();
  }

  int ccol = col0 + wc * 64 + (lane & 15);
  int crow = row0 + wr * 64 + (lane >> 4) * 4;
#pragma unroll
  for (int i = 0; i < 4; ++i) {
#pragma unroll
    for (int r = 0; r < 4; ++r) {
      int gr = crow + i * 16 + r;
      int bb = gr / n_l, rr = gr - bb * n_l;
      for (int s = 0; s < scale; ++s) {
        int dst = idx[(size_t)bb * NTOK + (size_t)rr * scale + s];
        float* p = C + ((size_t)bb * NTOK + dst) * 512 + ccol;
        if (EMODE == 3) {
#pragma unroll
          for (int j = 0; j < 4; ++j) p[j * 16] += acc[i][j][r];
        } else {
#pragma unroll
          for (int j = 0; j < 4; ++j) p[j * 16] = acc[i][j][r];
        }
      }
    }
  }
}

// ----------------------------------------------- fused windowed attention ---
// (round-12 structure + setprio) TWO blocks per (b,g,h), 64 q-rows each.
__global__ __launch_bounds__(512) void attn_fused_kernel(
    const u16* __restrict__ qhi, const u16* __restrict__ qlo,
    const u16* __restrict__ khi, const u16* __restrict__ klo,
    const u16* __restrict__ vbf, const int* __restrict__ keepArr,
    const u16* __restrict__ prevA, u16* __restrict__ curA,
    const float* __restrict__ betaL, u16* __restrict__ outp,
    int lvl, int n_l, int ng, int prev_ng) {
  __shared__ u64 smem8[5120];             // 40960 B
  u16*   Khi_s  = (u16*)smem8;            // [256][32] @0     (phase A stage)
  u16*   Klo_s  = Khi_s + 256 * 32;       // @16384
  u16*   Qhi_s  = Klo_s + 256 * 32;       // [64][32] @32768
  u16*   Qlo_s  = Qhi_s + 64 * 32;        // @36864 (..40960)
  float* S_lds  = (float*)smem8;          // [32][264] f32 @0..33792
  u16*   P_half = (u16*)smem8;            // [64][136] @0..17408   (phase B)
  u16*   Vt     = P_half + 64 * 136;      // [64][136] @17408..34816

  int t = threadIdx.x;
  int lane = t & 63, wave = t >> 6;
  int bid = blockIdx.x;
  int p   = bid & 1;
  int h   = (bid >> 1) & 7;
  int gl  = bid >> 4;
  int g   = gl % ng;
  int b   = gl / ng;
  int bgh = bid >> 1;                     // (b,g,h) index for attn state

  const u16* qhbase = qhi + ((size_t)b * n_l + (size_t)g * GS + p * 64) * DIMC + h * DQK;
  const u16* qlbase = qlo + ((size_t)b * n_l + (size_t)g * GS + p * 64) * DIMC + h * DQK;
  const u16* khbase = khi + (size_t)b * n_l * DIMC + h * DQK;
  const u16* klbase = klo + (size_t)b * n_l * DIMC + h * DQK;

  // ---- phase A: sim via MFMA (3-product split), acc over 2 d-halves ----
  int qt  = wave >> 1;                    // q-tile 0..3
  int ktb = (wave & 1) * 8;               // key-tile base 0 or 8
  f32x4 acc[8];
#pragma unroll
  for (int i = 0; i < 8; ++i) acc[i] = (f32x4){0.f, 0.f, 0.f, 0.f};

#pragma unroll
  for (int dp = 0; dp < 2; ++dp) {
    if (dp) __syncthreads();              // previous half's frags consumed
    int d0 = dp * 32;
#pragma unroll
    for (int ii = 0; ii < 2; ++ii) {
      int row = wave * 32 + ii * 16 + (lane >> 2);
      int pp = g * GS + row;
      int src = (pp < n_l) ? pp : (2 * n_l - 1 - pp);
      const u16* gH = khbase + (size_t)src * DIMC + d0 + (lane & 3) * 8;
      const u16* gL = klbase + (size_t)src * DIMC + d0 + (lane & 3) * 8;
      __builtin_amdgcn_global_load_lds(
          (const __attribute__((address_space(1))) void*)gH,
          (__attribute__((address_space(3))) void*)&Khi_s[(wave * 32 + ii * 16) * 32],
          16, 0, 0);
      __builtin_amdgcn_global_load_lds(
          (const __attribute__((address_space(1))) void*)gL,
          (__attribute__((address_space(3))) void*)&Klo_s[(wave * 32 + ii * 16) * 32],
          16, 0, 0);
    }
    if (wave < 4) {
      int row = wave * 16 + (lane >> 2);
      const u16* gH = qhbase + (size_t)row * DIMC + d0 + (lane & 3) * 8;
      __builtin_amdgcn_global_load_lds(
          (const __attribute__((address_space(1))) void*)gH,
          (__attribute__((address_space(3))) void*)&Qhi_s[(wave * 16) * 32],
          16, 0, 0);
    } else {
      int row = (wave - 4) * 16 + (lane >> 2);
      const u16* gL = qlbase + (size_t)row * DIMC + d0 + (lane & 3) * 8;
      __builtin_amdgcn_global_load_lds(
          (const __attribute__((address_space(1))) void*)gL,
          (__attribute__((address_space(3))) void*)&Qlo_s[((wave - 4) * 16) * 32],
          16, 0, 0);
    }
    __syncthreads();

    int fr = lane & 15;
    int kf = (lane >> 4) * 8;
    bf16x8 bqh = *reinterpret_cast<const bf16x8*>(&Qhi_s[(qt * 16 + fr) * 32 + kf]);
    bf16x8 bql = *reinterpret_cast<const bf16x8*>(&Qlo_s[(qt * 16 + fr) * 32 + kf]);
    __builtin_amdgcn_s_setprio(1);
#pragma unroll
    for (int kt = 0; kt < 8; ++kt) {
      bf16x8 akh = *reinterpret_cast<const bf16x8*>(&Khi_s[((ktb + kt) * 16 + fr) * 32 + kf]);
      bf16x8 akl = *reinterpret_cast<const bf16x8*>(&Klo_s[((ktb + kt) * 16 + fr) * 32 + kf]);
      acc[kt] = __builtin_amdgcn_mfma_f32_16x16x32_bf16(akh, bqh, acc[kt], 0, 0, 0);
      acc[kt] = __builtin_amdgcn_mfma_f32_16x16x32_bf16(akh, bql, acc[kt], 0, 0, 0);
      acc[kt] = __builtin_amdgcn_mfma_f32_16x16x32_bf16(akl, bqh, acc[kt], 0, 0, 0);
    }
    __builtin_amdgcn_s_setprio(0);
  }
  __syncthreads();   // staging LDS dead; S_lds may overwrite

  int kp = keepArr[b * ng + g];
  float beta = 0.f, wgt = 0.f;
  int plo_ = 0, phi_ = 0;
  if (lvl > 0) {
    beta = 1.f / (1.f + expf(-betaL[lvl]));
    float pos = ((float)g + 0.5f) * ((float)prev_ng / (float)ng) - 0.5f;
    float fl = floorf(pos);
    plo_ = (int)fl;
    if (plo_ < 0) plo_ = 0;
    if (plo_ > prev_ng - 1) plo_ = prev_ng - 1;
    phi_ = plo_ + 1; if (phi_ > prev_ng - 1) phi_ = prev_ng - 1;
    wgt = fminf(fmaxf(pos - fl, 0.f), 1.f);
  }
  u64 lmask = (1ull << lane) - 1ull;

  // ---- S halves -> ballot top-k -> softmax -> prior; retain packed bf16 ----
  unsigned atp[8][2];
#pragma unroll
  for (int half = 0; half < 2; ++half) {
    if ((wave >> 2) == half) {
      int ql = ((wave >> 1) & 1) * 16 + (lane & 15);   // q-local within half
#pragma unroll
      for (int kt = 0; kt < 8; ++kt) {
        int key = (ktb + kt) * 16 + (lane >> 4) * 4;
        *reinterpret_cast<f32x4*>(&S_lds[ql * 264 + key]) = acc[kt];
      }
    }
    __syncthreads();
#pragma unroll
    for (int j = 0; j < 4; ++j) {
      int lrow = wave * 4 + j;            // 0..31 within half
      int i = p * 64 + half * 32 + lrow;  // row within 128-row group
      f32x4 s4 = *reinterpret_cast<const f32x4*>(&S_lds[lrow * 264 + lane * 4]);
      float sv[4];
      unsigned um[4];
#pragma unroll
      for (int e = 0; e < 4; ++e) {
        sv[e] = s4[e] * 0.125f;
        unsigned u = __float_as_uint(sv[e]);
        um[e] = (u & 0x80000000u) ? ~u : (u | 0x80000000u);
      }
      // unmasked row max == masked max (top element always kept, kp>=128)
      float m = wave_max64(fmaxf(fmaxf(sv[0], sv[1]), fmaxf(sv[2], sv[3])));
      unsigned T = 0u;
      for (int bit = 31; bit >= 0; --bit) {
        unsigned T2 = T | (1u << bit);
        int c = __popcll(__ballot(um[0] >= T2)) + __popcll(__ballot(um[1] >= T2))
              + __popcll(__ballot(um[2] >= T2)) + __popcll(__ballot(um[3] >= T2));
        if (c >= kp) { T = T2; if (c == kp) break; }
      }
      int c_gt = __popcll(__ballot(um[0] > T)) + __popcll(__ballot(um[1] > T))
               + __popcll(__ballot(um[2] > T)) + __popcll(__ballot(um[3] > T));
      u64 beq[4];
#pragma unroll
      for (int e = 0; e < 4; ++e) beq[e] = __ballot(um[e] == T);
      int trbase = __popcll(beq[0] & lmask) + __popcll(beq[1] & lmask)
                 + __popcll(beq[2] & lmask) + __popcll(beq[3] & lmask);
      int need = kp - c_gt;
      bool msk[4];
      int own = 0;
#pragma unroll
      for (int e = 0; e < 4; ++e) {
        bool eq = (um[e] == T);
        msk[e] = (um[e] > T) || (eq && (trbase + own) < need);
        own += eq ? 1 : 0;
      }
      float ez[4], zs = 0.f;
#pragma unroll
      for (int e = 0; e < 4; ++e) { ez[e] = msk[e] ? __expf(sv[e] - m) : 0.f; zs += ez[e]; }
      zs = wave_sum64(zs);
      float at[4];
#pragma unroll
      for (int e = 0; e < 4; ++e) at[e] = ez[e] / zs;
      if (lvl > 0) {
        size_t baseLo = ((((size_t)b * prev_ng + plo_) * 8 + h) * GS + i) * WIN + lane * 4;
        size_t baseHi = ((((size_t)b * prev_ng + phi_) * 8 + h) * GS + i) * WIN + lane * 4;
        uint2 rlo = *reinterpret_cast<const uint2*>(prevA + baseLo);
        uint2 rhi = *reinterpret_cast<const uint2*>(prevA + baseHi);
        float pl[4] = { b2f_lo(rlo.x), b2f_hi(rlo.x), b2f_lo(rlo.y), b2f_hi(rlo.y) };
        float ph[4] = { b2f_lo(rhi.x), b2f_hi(rhi.x), b2f_lo(rhi.y), b2f_hi(rhi.y) };
        // prior rows are stored normalized; skip re-normalizing reduction
#pragma unroll
        for (int e = 0; e < 4; ++e) {
          float pr = fmaxf((1.f - wgt) * pl[e] + wgt * ph[e], 0.f);
          at[e] = (1.f - beta) * at[e] + beta * pr;
        }
      }
      atp[half * 4 + j][0] = (unsigned)f2b(at[0]) | ((unsigned)f2b(at[1]) << 16);
      atp[half * 4 + j][1] = (unsigned)f2b(at[2]) | ((unsigned)f2b(at[3]) << 16);
      if (curA != nullptr) {
        uint2 o = { atp[half * 4 + j][0], atp[half * 4 + j][1] };
        *reinterpret_cast<uint2*>(curA + ((size_t)bgh * GS + i) * WIN + lane * 4) = o;
      }
    }
    __syncthreads();   // S half consumed before next half's write / P_half
  }

  // ---- PV via MFMA: O(64x64) = P(64x256) @ V(256x64), per-j-half P ----
  const u16* vbase = vbf + (size_t)b * n_l * DIMC + h * DV;
  int rf   = wave >> 1;                  // q-row frag 0..3
  int cf0  = (wave & 1) * 2;             // dv col frag base {0,2}
  int frow = lane & 15;
  int fk   = (lane >> 4) * 8;
  f32x4 oacc0 = { 0.f, 0.f, 0.f, 0.f };
  f32x4 oacc1 = { 0.f, 0.f, 0.f, 0.f };
  int jlo = t & 15, vd4 = (t >> 4) & 15, jh2 = t >> 8;

#pragma unroll
  for (int jp = 0; jp < 2; ++jp) {
    // stage Vt half (transposed V)
#pragma unroll
    for (int it = 0; it < 4; ++it) {
      int j = (jh2 * 4 + it) * 16 + jlo;           // 0..127
      int pp = g * GS + jp * 128 + j;
      int src = (pp < n_l) ? pp : (2 * n_l - 1 - pp);
      ushort4 vv = *reinterpret_cast<const ushort4*>(vbase + (size_t)src * DIMC + vd4 * 4);
      Vt[(vd4 * 4 + 0) * 136 + j] = vv.x;
      Vt[(vd4 * 4 + 1) * 136 + j] = vv.y;
      Vt[(vd4 * 4 + 2) * 136 + j] = vv.z;
      Vt[(vd4 * 4 + 3) * 136 + j] = vv.w;
    }
    // write this half's P from retained regs (lanes owning these keys)
    if ((lane >> 5) == jp) {
      int kl = (lane & 31) * 4;          // local key base within half
#pragma unroll
      for (int j = 0; j < 4; ++j) {
        uint2 oA = { atp[j][0], atp[j][1] };
        uint2 oB = { atp[4 + j][0], atp[4 + j][1] };
        *reinterpret_cast<uint2*>(&P_half[(wave * 4 + j) * 136 + kl]) = oA;
        *reinterpret_cast<uint2*>(&P_half[(32 + wave * 4 + j) * 136 + kl]) = oB;
      }
    }
    __syncthreads();
    __builtin_amdgcn_s_setprio(1);
#pragma unroll
    for (int ks = 0; ks < 4; ++ks) {
      bf16x8 a  = *reinterpret_cast<const bf16x8*>(&P_half[(rf * 16 + frow) * 136 + ks * 32 + fk]);
      bf16x8 b0 = *reinterpret_cast<const bf16x8*>(&Vt[(cf0 * 16 + frow) * 136 + ks * 32 + fk]);
      bf16x8 b1 = *reinterpret_cast<const bf16x8*>(&Vt[((cf0 + 1) * 16 + frow) * 136 + ks * 32 + fk]);
      oacc0 = __builtin_amdgcn_mfma_f32_16x16x32_bf16(a, b0, oacc0, 0, 0, 0);
      oacc1 = __builtin_amdgcn_mfma_f32_16x16x32_bf16(a, b1, oacc1, 0, 0, 0);
    }
    __builtin_amdgcn_s_setprio(0);
    __syncthreads();
  }

  u16* obase = outp + ((size_t)b * n_l + (size_t)g * GS + p * 64 + rf * 16) * DIMC + h * DV;
#pragma unroll
  for (int rr = 0; rr < 4; ++rr) {
    int qrow = (lane >> 4) * 4 + rr;
    obase[(size_t)qrow * DIMC + cf0 * 16 + frow]       = f2b(oacc0[rr]);
    obase[(size_t)qrow * DIMC + (cf0 + 1) * 16 + frow] = f2b(oacc1[rr]);
  }
}

// ---------------------------------------------------------------------------
extern "C" void kernel_launch(void* const* d_in, const int* in_sizes, int n_in,
                              void* d_out, int out_size, void* d_ws, size_t ws_size,
                              hipStream_t stream) {
  (void)in_sizes; (void)n_in; (void)out_size; (void)ws_size;
  const float* x        = (const float*)d_in[0];
  const int*   labels   = (const int*)d_in[1];
  const float* scores   = (const float*)d_in[2];
  const int*   idx_last = (const int*)d_in[3];
  const float* Wq       = (const float*)d_in[4];
  const float* Wk       = (const float*)d_in[5];
  const float* Wv       = (const float*)d_in[6];
  const float* Wp       = (const float*)d_in[7];
  const float* betaL    = (const float*)d_in[8];
  float* out = (float*)d_out;

  char* w = (char*)d_ws;
  size_t off = 0;
  auto take = [&](size_t bytes) -> char* {
    char* p = w + off;
    off += (bytes + 255) & ~(size_t)255;
    return p;
  };
  u16*   qhib   = (u16*)  take(16777216);   // q hi bf16 (16384 rows x 512)
  u16*   qlob   = (u16*)  take(16777216);   // q lo
  u16*   khib   = (u16*)  take(16777216);   // k hi
  u16*   klob   = (u16*)  take(16777216);   // k lo
  u16*   vbf    = (u16*)  take(16777216);   // v bf16
  u16*   xhi    = (u16*)  take(16777216);   // A hi / attn-out (disjoint lifetimes)
  u16*   xlo    = (u16*)  take(16777216);   // A lo
  u16*   attnA  = (u16*)  take(16777216);   // lvl0 attn bf16
  u16*   attnB  = (u16*)  take(33554432);   // lvl1 attn bf16
  u16*   whiAll = (u16*)  take(6291456);    // 12 x [512][512] bf16 hi
  u16*   wloAll = (u16*)  take(3145728);    // 6  x [512][512] bf16 lo (q,k)
  float* sl     = (float*)take(65536);      // pooled scores lvl0 [0,4096) lvl1 [4096,12288)
  int*   ll     = (int*)  take(65536);      // pooled labels, same offsets
  int*   keepb  = (int*)  take(1024);       // keep: lvl0 @0, lvl1 @32, lvl2 @96
  // total ~178 MB

  const size_t ROW1 = 4096;                 // lvl1 row offset in shared buffers

  // all 12 weight transposes+splits, once
  wprep_kernel<<<3072, 256, 0, stream>>>(Wq, Wk, Wv, Wp, whiAll, wloAll);
  // pooled features + labels for lvl0+lvl1, one launch each
  pool_split01_kernel<<<6144, 256, 0, stream>>>(x, scores, xhi, xlo, sl);
  pool_label01_kernel<<<48, 256, 0, stream>>>(labels, scores, ll);
  // keep for all 3 levels (lvl2 from raw inputs)
  keep_all_kernel<<<2, 128, 0, stream>>>(ll, sl, labels, scores, keepb);

  // qkv for lvl0+lvl1 in one launch: rows [0,4096) lvl0, [4096,12288) lvl1
  {
    dim3 gq(12, 96);
    qkv_gemm_kernel<<<gq, 256, 0, stream>>>(xhi, xlo, whiAll, wloAll,
                                            qhib, qlob, khib, klob, vbf,
                                            0, 1, 32, (int)ROW1);
  }

  // ---- level 0 ----
  attn_fused_kernel<<<2 * 16 * 8 * 2, 512, 0, stream>>>(
      qhib, qlob, khib, klob, vbf, keepb, nullptr, attnA,
      betaL, xhi, 0, 2048, 16, 8);
  {
    dim3 gp(4, 32);
    wp_gemm_kernel<2><<<gp, 256, 0, stream>>>(xhi, whiAll + (size_t)9 * WSZ,
                                              out, idx_last, 4096, 4, 2048);
  }

  // ---- level 1 (buffers at row offset 4096) ----
  attn_fused_kernel<<<2 * 32 * 8 * 2, 512, 0, stream>>>(
      qhib + ROW1 * DIMC, qlob + ROW1 * DIMC, khib + ROW1 * DIMC, klob + ROW1 * DIMC,
      vbf + ROW1 * DIMC, keepb + 32, attnA, attnB,
      betaL, xhi + ROW1 * DIMC, 1, 4096, 32, 16);
  {
    dim3 gp(4, 64);
    wp_gemm_kernel<3><<<gp, 256, 0, stream>>>(xhi + ROW1 * DIMC, whiAll + (size_t)10 * WSZ,
                                              out, idx_last, 8192, 2, 4096);
  }

  // ---- level 2 (reuses all buffers from row 0) ----
  asplit_kernel<<<(2 * NTOK * 128) / 256, 256, 0, stream>>>(x, xhi, xlo);
  {
    dim3 gq(12, 128);
    qkv_gemm_kernel<<<gq, 256, 0, stream>>>(xhi, xlo, whiAll, wloAll,
                                            qhib, qlob, khib, klob, vbf,
                                            2, 2, 1 << 20, 0);
  }
  attn_fused_kernel<<<2 * 64 * 8 * 2, 512, 0, stream>>>(
      qhib, qlob, khib, klob, vbf, keepb + 96, attnB, nullptr,
      betaL, xhi, 2, 8192, 64, 32);
  {
    dim3 gp(4, 128);
    wp_gemm_kernel<3><<<gp, 256, 0, stream>>>(xhi, whiAll + (size_t)11 * WSZ,
                                              out, idx_last, 16384, 1, 8192);
  }
}

// Round 15
// 516.656 us; speedup vs baseline: 1.1043x; 1.0023x over previous
//
#include <hip/hip_runtime.h>
#include <math.h>

// ---------------------------------------------------------------------------
// LowToHighMultiLevelReconstruction — round 15.
// Changes vs round 14 (attention ballot only):
//  1. Ranking keys truncated to top 20 bits (count-preserving selection;
//     boundary class ~ adjacent-sim gap -> output perturbation ~1e-4).
//  2. Fixed 20-step BRANCHLESS bit-build (no early-exit break; cselect only).
//  3. Prior (prevA) loads hoisted above the ballot chain (latency hiding).
// ---------------------------------------------------------------------------

#define GS   128
#define WIN  256        // 2*GS
#define DQK  64
#define DV   64
#define DIMC 512
#define NTOK 8192
#define WSZ  262144     // 512*512 elements per weight matrix

typedef unsigned long long u64;
typedef unsigned short u16;
typedef __attribute__((ext_vector_type(8))) short bf16x8;
typedef __attribute__((ext_vector_type(4))) float f32x4;

__device__ __forceinline__ u16 f2b(float f) {     // f32 -> bf16 RNE
  unsigned u = __float_as_uint(f);
  u = (u + 0x7fffu + ((u >> 16) & 1u)) >> 16;
  return (u16)u;
}
__device__ __forceinline__ float b2f(u16 h) { return __uint_as_float(((unsigned)h) << 16); }
__device__ __forceinline__ float b2f_lo(unsigned u) { return __uint_as_float(u << 16); }
__device__ __forceinline__ float b2f_hi(unsigned u) { return __uint_as_float(u & 0xffff0000u); }

__device__ __forceinline__ float wave_max64(float v) {
#pragma unroll
  for (int m = 1; m < 64; m <<= 1) v = fmaxf(v, __shfl_xor(v, m, 64));
  return v;
}
__device__ __forceinline__ float wave_sum64(float v) {
#pragma unroll
  for (int m = 1; m < 64; m <<= 1) v += __shfl_xor(v, m, 64);
  return v;
}

// ------------------------------ pooling lvl0+lvl1 (writes split bf16) -------
__global__ void pool_split01_kernel(const float* __restrict__ x,
                                    const float* __restrict__ scores,
                                    u16* __restrict__ xhi, u16* __restrict__ xlo,
                                    float* __restrict__ sl) {
  int tid = blockIdx.x * 256 + threadIdx.x;     // 0..1572863
  int scale, npool, rowoff, rest;
  if (tid < 524288) { scale = 4; npool = 2048; rowoff = 0;    rest = tid >> 7; }
  else { tid -= 524288; scale = 2; npool = 4096; rowoff = 4096; rest = tid >> 7; }
  int c4 = tid & 127;
  int g  = rest % npool;
  int b  = rest / npool;
  const float* xp = x + ((size_t)b * NTOK + (size_t)g * scale) * DIMC + c4 * 4;
  float ax = 0.f, ay = 0.f, az = 0.f, aw = 0.f, wsum = 0.f, ssum = 0.f;
  for (int s = 0; s < scale; ++s) {
    float sc = scores[(size_t)b * NTOK + (size_t)g * scale + s];
    float w  = fmaxf(sc, 1e-6f);
    float4 xv = *reinterpret_cast<const float4*>(xp + (size_t)s * DIMC);
    ax += xv.x * w; ay += xv.y * w; az += xv.z * w; aw += xv.w * w;
    wsum += w; ssum += sc;
  }
  float o[4] = { ax / wsum, ay / wsum, az / wsum, aw / wsum };
  ushort4 h, l;
  h.x = f2b(o[0]); h.y = f2b(o[1]); h.z = f2b(o[2]); h.w = f2b(o[3]);
  l.x = f2b(o[0] - b2f(h.x)); l.y = f2b(o[1] - b2f(h.y));
  l.z = f2b(o[2] - b2f(h.z)); l.w = f2b(o[3] - b2f(h.w));
  size_t row = (size_t)rowoff + (size_t)b * npool + g;
  size_t off = row * DIMC + c4 * 4;
  *reinterpret_cast<ushort4*>(xhi + off) = h;
  *reinterpret_cast<ushort4*>(xlo + off) = l;
  if (c4 == 0) sl[row] = ssum / (float)scale;
}

__global__ void pool_label01_kernel(const int* __restrict__ labels,
                                    const float* __restrict__ scores,
                                    int* __restrict__ ll) {
  int tid = blockIdx.x * 256 + threadIdx.x;     // 0..12287
  int scale, npool, rowoff;
  if (tid < 4096) { scale = 4; npool = 2048; rowoff = 0; }
  else { tid -= 4096; scale = 2; npool = 4096; rowoff = 4096; }
  int b = tid / npool, g = tid % npool;
  float counts[4] = {0.f, 0.f, 0.f, 0.f};
  float ssum[4]   = {0.f, 0.f, 0.f, 0.f};
  int firstp[4];
  for (int c = 0; c < 4; ++c) firstp[c] = scale;
  for (int s = 0; s < scale; ++s) {
    int   L = labels[(size_t)b * NTOK + (size_t)g * scale + s];
    float S = scores[(size_t)b * NTOK + (size_t)g * scale + s];
    counts[L] += 1.0f;
    ssum[L]   += S;
    if (s < firstp[L]) firstp[L] = s;
  }
  float cmax = fmaxf(fmaxf(counts[0], counts[1]), fmaxf(counts[2], counts[3]));
  float s2[4];
  for (int c = 0; c < 4; ++c) s2[c] = (counts[c] == cmax) ? ssum[c] : -1e9f;
  float smax = fmaxf(fmaxf(s2[0], s2[1]), fmaxf(s2[2], s2[3]));
  int fp[4];
  for (int c = 0; c < 4; ++c) fp[c] = (s2[c] == smax) ? firstp[c] : scale;
  int best = 0, bv = fp[0];
  for (int c = 1; c < 4; ++c) if (fp[c] < bv) { bv = fp[c]; best = c; }
  ll[rowoff + b * npool + g] = best;
}

// --------------------------------------------------- raw x split (lvl 2) ----
__global__ void asplit_kernel(const float* __restrict__ x,
                              u16* __restrict__ xhi, u16* __restrict__ xlo) {
  int tid = blockIdx.x * 256 + threadIdx.x;     // over 2*NTOK*128 float4s
  float4 v = *reinterpret_cast<const float4*>(x + (size_t)tid * 4);
  ushort4 h, l;
  h.x = f2b(v.x); h.y = f2b(v.y); h.z = f2b(v.z); h.w = f2b(v.w);
  l.x = f2b(v.x - b2f(h.x)); l.y = f2b(v.y - b2f(h.y));
  l.z = f2b(v.z - b2f(h.z)); l.w = f2b(v.w - b2f(h.w));
  *reinterpret_cast<ushort4*>(xhi + (size_t)tid * 4) = h;
  *reinterpret_cast<ushort4*>(xlo + (size_t)tid * 4) = l;
}

// -------------------------- keep for ALL levels in one launch ---------------
__global__ void keep_all_kernel(const int* __restrict__ ll, const float* __restrict__ sl,
                                const int* __restrict__ labels,
                                const float* __restrict__ scores,
                                int* __restrict__ keep) {
  int tid = blockIdx.x * 128 + threadIdx.x;
  if (tid >= 224) return;
  const int* lp; const float* sp;
  if (tid < 32) {
    int b = tid >> 4, g = tid & 15;
    lp = ll + (b * 2048 + g * GS);
    sp = sl + (b * 2048 + g * GS);
  } else if (tid < 96) {
    int e = tid - 32;
    int b = e >> 5, g = e & 31;
    lp = ll + 4096 + (b * 4096 + g * GS);
    sp = sl + 4096 + (b * 4096 + g * GS);
  } else {
    int e = tid - 96;
    int b = e >> 6, g = e & 63;
    lp = labels + ((size_t)b * NTOK + g * GS);
    sp = scores + ((size_t)b * NTOK + g * GS);
  }
  float counts[4] = {0.f, 0.f, 0.f, 0.f};
  for (int i = 0; i < GS; ++i) counts[lp[i]] += 1.f;
  int mode = 0; float bv = counts[0];
  for (int c = 1; c < 4; ++c) if (counts[c] > bv) { bv = counts[c]; mode = c; }
  float pm = 0.f, mean = 0.f;
  for (int i = 0; i < GS; ++i) { pm += (lp[i] == mode) ? 1.f : 0.f; mean += sp[i]; }
  float purity = pm / (float)GS;
  mean /= (float)GS;
  float var = 0.f;
  for (int i = 0; i < GS; ++i) { float d = sp[i] - mean; var += d * d; }
  var /= (float)GS;
  float focus = 0.5f + 0.25f * purity - 0.25f * var;
  focus = fminf(fmaxf(focus, 0.25f), 0.75f);
  keep[tid] = (int)ceilf(focus * (float)WIN);
}

// --------------------- ALL weight transpose+split in one launch (12 mats) ---
__global__ __launch_bounds__(256) void wprep_kernel(
    const float* __restrict__ Wq, const float* __restrict__ Wk,
    const float* __restrict__ Wv, const float* __restrict__ Wp,
    u16* __restrict__ whiAll, u16* __restrict__ wloAll) {
  __shared__ float tile[32][33];
  int blk = blockIdx.x;            // 0..3071
  int mat = blk >> 8;              // 0..11
  int sub = blk & 255;
  int kind = mat / 3, lvl = mat % 3;
  const float* W = (kind == 0 ? Wq : kind == 1 ? Wk : kind == 2 ? Wv : Wp)
                   + (size_t)lvl * WSZ;
  u16* bthi = whiAll + (size_t)mat * WSZ;
  u16* btlo = (mat < 6) ? (wloAll + (size_t)mat * WSZ) : nullptr;

  int bx = sub & 15;               // n block
  int by = sub >> 4;               // k block
  int tx = threadIdx.x & 31;
  int ty = threadIdx.x >> 5;       // 0..7
#pragma unroll
  for (int i = 0; i < 4; ++i) {
    int kk = ty + i * 8;
    tile[kk][tx] = W[(size_t)(by * 32 + kk) * 512 + bx * 32 + tx];
  }
  __syncthreads();
#pragma unroll
  for (int i = 0; i < 4; ++i) {
    int nn = ty + i * 8;
    float v = tile[tx][nn];        // = W[by*32+tx][bx*32+nn]
    u16 h = f2b(v);
    size_t o = (size_t)(bx * 32 + nn) * 512 + by * 32 + tx;
    bthi[o] = h;
    if (btlo) btlo[o] = f2b(v - b2f(h));
  }
}

// ---------------------------------------------------- fused q/k/v GEMM ------
__global__ __launch_bounds__(256) void qkv_gemm_kernel(
    const u16* __restrict__ Ahi, const u16* __restrict__ Alo,
    const u16* __restrict__ whiAll, const u16* __restrict__ wloAll,
    u16* __restrict__ qhi, u16* __restrict__ qlo,
    u16* __restrict__ khi, u16* __restrict__ klo, u16* __restrict__ vbf,
    int lvlA, int lvlB, int ysplit, int rowB) {
  __shared__ u16 smem[4 * 4096];
  u16* sAhi = smem;
  u16* sBhi = smem + 4096;
  u16* sAlo = smem + 2 * 4096;
  u16* sBlo = smem + 3 * 4096;

  int sel = blockIdx.x >> 2;       // 0=q, 1=k, 2=v
  int cx  = blockIdx.x & 3;
  bool split = (sel < 2);
  int ry  = blockIdx.y;
  int lvl   = (ry < ysplit) ? lvlA : lvlB;
  int row0  = (ry < ysplit) ? ry * 128 : rowB + (ry - ysplit) * 128;
  const u16* Bh = whiAll + (size_t)(sel * 3 + lvl) * WSZ;
  const u16* Bl = wloAll + (size_t)(sel * 3 + lvl) * WSZ;   // valid only sel<2

  int t = threadIdx.x, lane = t & 63, wave = t >> 6;
  int wr = wave >> 1, wc = wave & 1;
  int col0 = cx * 128;

  int srow = (lane >> 2);
  int schk = (lane & 3) * 8;

  const f32x4 zero = { 0.f, 0.f, 0.f, 0.f };
  f32x4 acc[4][4];
#pragma unroll
  for (int i = 0; i < 4; ++i)
#pragma unroll
    for (int j = 0; j < 4; ++j) acc[i][j] = zero;

  for (int k0 = 0; k0 < 512; k0 += 32) {
#pragma unroll
    for (int j = 0; j < 2; ++j) {
      int r = wave * 32 + j * 16 + srow;
      const u16* gA = Ahi + (size_t)(row0 + r) * 512 + k0 + schk;
      const u16* gB = Bh + (size_t)(col0 + r) * 512 + k0 + schk;
      __builtin_amdgcn_global_load_lds(
          (const __attribute__((address_space(1))) void*)gA,
          (__attribute__((address_space(3))) void*)&sAhi[(wave * 32 + j * 16) * 32],
          16, 0, 0);
      __builtin_amdgcn_global_load_lds(
          (const __attribute__((address_space(1))) void*)gB,
          (__attribute__((address_space(3))) void*)&sBhi[(wave * 32 + j * 16) * 32],
          16, 0, 0);
      if (split) {
        const u16* gAl = Alo + (size_t)(row0 + r) * 512 + k0 + schk;
        const u16* gBl = Bl + (size_t)(col0 + r) * 512 + k0 + schk;
        __builtin_amdgcn_global_load_lds(
            (const __attribute__((address_space(1))) void*)gAl,
            (__attribute__((address_space(3))) void*)&sAlo[(wave * 32 + j * 16) * 32],
            16, 0, 0);
        __builtin_amdgcn_global_load_lds(
            (const __attribute__((address_space(1))) void*)gBl,
            (__attribute__((address_space(3))) void*)&sBlo[(wave * 32 + j * 16) * 32],
            16, 0, 0);
      }
    }
    __syncthreads();

    int fr = lane & 15;
    int kf = (lane >> 4) * 8;
    bf16x8 ah[4], bh[4], al[4], bl[4];
#pragma unroll
    for (int i = 0; i < 4; ++i) {
      ah[i] = *reinterpret_cast<const bf16x8*>(&sAhi[(wr * 64 + i * 16 + fr) * 32 + kf]);
      bh[i] = *reinterpret_cast<const bf16x8*>(&sBhi[(wc * 64 + i * 16 + fr) * 32 + kf]);
      if (split) {
        al[i] = *reinterpret_cast<const bf16x8*>(&sAlo[(wr * 64 + i * 16 + fr) * 32 + kf]);
        bl[i] = *reinterpret_cast<const bf16x8*>(&sBlo[(wc * 64 + i * 16 + fr) * 32 + kf]);
      }
    }
#pragma unroll
    for (int i = 0; i < 4; ++i)
#pragma unroll
      for (int j = 0; j < 4; ++j) {
        acc[i][j] = __builtin_amdgcn_mfma_f32_16x16x32_bf16(ah[i], bh[j], acc[i][j], 0, 0, 0);
        if (split) {
          acc[i][j] = __builtin_amdgcn_mfma_f32_16x16x32_bf16(ah[i], bl[j], acc[i][j], 0, 0, 0);
          acc[i][j] = __builtin_amdgcn_mfma_f32_16x16x32_bf16(al[i], bh[j], acc[i][j], 0, 0, 0);
        }
      }
    __syncthreads();
  }

  int ccol = col0 + wc * 64 + (lane & 15);
  int crow = row0 + wr * 64 + (lane >> 4) * 4;
  if (sel == 2) {
#pragma unroll
    for (int i = 0; i < 4; ++i)
#pragma unroll
      for (int r = 0; r < 4; ++r) {
        int gr = crow + i * 16 + r;
#pragma unroll
        for (int j = 0; j < 4; ++j)
          vbf[(size_t)gr * 512 + ccol + j * 16] = f2b(acc[i][j][r]);
      }
  } else {
    u16* Ch = (sel == 0) ? qhi : khi;
    u16* Cl = (sel == 0) ? qlo : klo;
#pragma unroll
    for (int i = 0; i < 4; ++i)
#pragma unroll
      for (int r = 0; r < 4; ++r) {
        int gr = crow + i * 16 + r;
#pragma unroll
        for (int j = 0; j < 4; ++j) {
          float v = acc[i][j][r];
          u16 hh = f2b(v);
          Ch[(size_t)gr * 512 + ccol + j * 16] = hh;
          Cl[(size_t)gr * 512 + ccol + j * 16] = f2b(v - b2f(hh));
        }
      }
  }
}

// --------------------------------------------------- Wp GEMM (scatter) ------
template<int EMODE>
__global__ __launch_bounds__(256) void wp_gemm_kernel(
    const u16* __restrict__ Ahi, const u16* __restrict__ Bthi,
    float* __restrict__ C, const int* __restrict__ idx,
    int M, int scale, int n_l) {
  __shared__ u16 smem[2 * 4096];
  u16* sAhi = smem;
  u16* sBhi = smem + 4096;

  int t = threadIdx.x, lane = t & 63, wave = t >> 6;
  int wr = wave >> 1, wc = wave & 1;
  int row0 = blockIdx.y * 128, col0 = blockIdx.x * 128;

  int srow = (lane >> 2);
  int schk = (lane & 3) * 8;

  const f32x4 zero = { 0.f, 0.f, 0.f, 0.f };
  f32x4 acc[4][4];
#pragma unroll
  for (int i = 0; i < 4; ++i)
#pragma unroll
    for (int j = 0; j < 4; ++j) acc[i][j] = zero;

  for (int k0 = 0; k0 < 512; k0 += 32) {
#pragma unroll
    for (int j = 0; j < 2; ++j) {
      int r = wave * 32 + j * 16 + srow;
      const u16* gA = Ahi + (size_t)(row0 + r) * 512 + k0 + schk;
      const u16* gB = Bthi + (size_t)(col0 + r) * 512 + k0 + schk;
      __builtin_amdgcn_global_load_lds(
          (const __attribute__((address_space(1))) void*)gA,
          (__attribute__((address_space(3))) void*)&sAhi[(wave * 32 + j * 16) * 32],
          16, 0, 0);
      __builtin_amdgcn_global_load_lds(
          (const __attribute__((address_space(1))) void*)gB,
          (__attribute__((address_space(3))) void*)&sBhi[(wave * 32 + j * 16) * 32],
          16, 0, 0);
    }
    __syncthreads();

    int fr = lane & 15;
    int kf = (lane >> 4) * 8;
    bf16x8 ah[4], bh[4];
#pragma unroll
    for (int i = 0; i < 4; ++i) {
      ah[i] = *reinterpret_cast<const bf16x8*>(&sAhi[(wr * 64 + i * 16 + fr) * 32 + kf]);
      bh[i] = *reinterpret_cast<const bf16x8*>(&sBhi[(wc * 64 + i * 16 + fr) * 32 + kf]);
    }
#pragma unroll
    for (int i = 0; i < 4; ++i)
#pragma unroll
      for (int j = 0; j < 4; ++j)
        acc[i][j] = __builtin_amdgcn_mfma_f32_16x16x32_bf16(ah[i], bh[j], acc[i][j], 0, 0, 0);
    __syncthreads();
  }

  int ccol = col0 + wc * 64 + (lane & 15);
  int crow = row0 + wr * 64 + (lane >> 4) * 4;
#pragma unroll
  for (int i = 0; i < 4; ++i) {
#pragma unroll
    for (int r = 0; r < 4; ++r) {
      int gr = crow + i * 16 + r;
      int bb = gr / n_l, rr = gr - bb * n_l;
      for (int s = 0; s < scale; ++s) {
        int dst = idx[(size_t)bb * NTOK + (size_t)rr * scale + s];
        float* p = C + ((size_t)bb * NTOK + dst) * 512 + ccol;
        if (EMODE == 3) {
#pragma unroll
          for (int j = 0; j < 4; ++j) p[j * 16] += acc[i][j][r];
        } else {
#pragma unroll
          for (int j = 0; j < 4; ++j) p[j * 16] = acc[i][j][r];
        }
      }
    }
  }
}

// ----------------------------------------------- fused windowed attention ---
// TWO blocks per (b,g,h), 64 q-rows each. Ballot keys truncated to top-20
// bits; fixed branchless 20-step bit-build; prior loads hoisted.
__global__ __launch_bounds__(512) void attn_fused_kernel(
    const u16* __restrict__ qhi, const u16* __restrict__ qlo,
    const u16* __restrict__ khi, const u16* __restrict__ klo,
    const u16* __restrict__ vbf, const int* __restrict__ keepArr,
    const u16* __restrict__ prevA, u16* __restrict__ curA,
    const float* __restrict__ betaL, u16* __restrict__ outp,
    int lvl, int n_l, int ng, int prev_ng) {
  __shared__ u64 smem8[5120];             // 40960 B
  u16*   Khi_s  = (u16*)smem8;            // [256][32] @0     (phase A stage)
  u16*   Klo_s  = Khi_s + 256 * 32;       // @16384
  u16*   Qhi_s  = Klo_s + 256 * 32;       // [64][32] @32768
  u16*   Qlo_s  = Qhi_s + 64 * 32;        // @36864 (..40960)
  float* S_lds  = (float*)smem8;          // [32][264] f32 @0..33792
  u16*   P_half = (u16*)smem8;            // [64][136] @0..17408   (phase B)
  u16*   Vt     = P_half + 64 * 136;      // [64][136] @17408..34816

  int t = threadIdx.x;
  int lane = t & 63, wave = t >> 6;
  int bid = blockIdx.x;
  int p   = bid & 1;
  int h   = (bid >> 1) & 7;
  int gl  = bid >> 4;
  int g   = gl % ng;
  int b   = gl / ng;
  int bgh = bid >> 1;                     // (b,g,h) index for attn state

  const u16* qhbase = qhi + ((size_t)b * n_l + (size_t)g * GS + p * 64) * DIMC + h * DQK;
  const u16* qlbase = qlo + ((size_t)b * n_l + (size_t)g * GS + p * 64) * DIMC + h * DQK;
  const u16* khbase = khi + (size_t)b * n_l * DIMC + h * DQK;
  const u16* klbase = klo + (size_t)b * n_l * DIMC + h * DQK;

  // ---- phase A: sim via MFMA (3-product split), acc over 2 d-halves ----
  int qt  = wave >> 1;                    // q-tile 0..3
  int ktb = (wave & 1) * 8;               // key-tile base 0 or 8
  f32x4 acc[8];
#pragma unroll
  for (int i = 0; i < 8; ++i) acc[i] = (f32x4){0.f, 0.f, 0.f, 0.f};

#pragma unroll
  for (int dp = 0; dp < 2; ++dp) {
    if (dp) __syncthreads();              // previous half's frags consumed
    int d0 = dp * 32;
#pragma unroll
    for (int ii = 0; ii < 2; ++ii) {
      int row = wave * 32 + ii * 16 + (lane >> 2);
      int pp = g * GS + row;
      int src = (pp < n_l) ? pp : (2 * n_l - 1 - pp);
      const u16* gH = khbase + (size_t)src * DIMC + d0 + (lane & 3) * 8;
      const u16* gL = klbase + (size_t)src * DIMC + d0 + (lane & 3) * 8;
      __builtin_amdgcn_global_load_lds(
          (const __attribute__((address_space(1))) void*)gH,
          (__attribute__((address_space(3))) void*)&Khi_s[(wave * 32 + ii * 16) * 32],
          16, 0, 0);
      __builtin_amdgcn_global_load_lds(
          (const __attribute__((address_space(1))) void*)gL,
          (__attribute__((address_space(3))) void*)&Klo_s[(wave * 32 + ii * 16) * 32],
          16, 0, 0);
    }
    if (wave < 4) {
      int row = wave * 16 + (lane >> 2);
      const u16* gH = qhbase + (size_t)row * DIMC + d0 + (lane & 3) * 8;
      __builtin_amdgcn_global_load_lds(
          (const __attribute__((address_space(1))) void*)gH,
          (__attribute__((address_space(3))) void*)&Qhi_s[(wave * 16) * 32],
          16, 0, 0);
    } else {
      int row = (wave - 4) * 16 + (lane >> 2);
      const u16* gL = qlbase + (size_t)row * DIMC + d0 + (lane & 3) * 8;
      __builtin_amdgcn_global_load_lds(
          (const __attribute__((address_space(1))) void*)gL,
          (__attribute__((address_space(3))) void*)&Qlo_s[((wave - 4) * 16) * 32],
          16, 0, 0);
    }
    __syncthreads();

    int fr = lane & 15;
    int kf = (lane >> 4) * 8;
    bf16x8 bqh = *reinterpret_cast<const bf16x8*>(&Qhi_s[(qt * 16 + fr) * 32 + kf]);
    bf16x8 bql = *reinterpret_cast<const bf16x8*>(&Qlo_s[(qt * 16 + fr) * 32 + kf]);
    __builtin_amdgcn_s_setprio(1);
#pragma unroll
    for (int kt = 0; kt < 8; ++kt) {
      bf16x8 akh = *reinterpret_cast<const bf16x8*>(&Khi_s[((ktb + kt) * 16 + fr) * 32 + kf]);
      bf16x8 akl = *reinterpret_cast<const bf16x8*>(&Klo_s[((ktb + kt) * 16 + fr) * 32 + kf]);
      acc[kt] = __builtin_amdgcn_mfma_f32_16x16x32_bf16(akh, bqh, acc[kt], 0, 0, 0);
      acc[kt] = __builtin_amdgcn_mfma_f32_16x16x32_bf16(akh, bql, acc[kt], 0, 0, 0);
      acc[kt] = __builtin_amdgcn_mfma_f32_16x16x32_bf16(akl, bqh, acc[kt], 0, 0, 0);
    }
    __builtin_amdgcn_s_setprio(0);
  }
  __syncthreads();   // staging LDS dead; S_lds may overwrite

  int kp = keepArr[b * ng + g];
  float beta = 0.f, wgt = 0.f;
  int plo_ = 0, phi_ = 0;
  if (lvl > 0) {
    beta = 1.f / (1.f + expf(-betaL[lvl]));
    float pos = ((float)g + 0.5f) * ((float)prev_ng / (float)ng) - 0.5f;
    float fl = floorf(pos);
    plo_ = (int)fl;
    if (plo_ < 0) plo_ = 0;
    if (plo_ > prev_ng - 1) plo_ = prev_ng - 1;
    phi_ = plo_ + 1; if (phi_ > prev_ng - 1) phi_ = prev_ng - 1;
    wgt = fminf(fmaxf(pos - fl, 0.f), 1.f);
  }
  u64 lmask = (1ull << lane) - 1ull;

  // ---- S halves -> ballot top-k -> softmax -> prior; retain packed bf16 ----
  unsigned atp[8][2];
#pragma unroll
  for (int half = 0; half < 2; ++half) {
    if ((wave >> 2) == half) {
      int ql = ((wave >> 1) & 1) * 16 + (lane & 15);   // q-local within half
#pragma unroll
      for (int kt = 0; kt < 8; ++kt) {
        int key = (ktb + kt) * 16 + (lane >> 4) * 4;
        *reinterpret_cast<f32x4*>(&S_lds[ql * 264 + key]) = acc[kt];
      }
    }
    __syncthreads();
#pragma unroll
    for (int j = 0; j < 4; ++j) {
      int lrow = wave * 4 + j;            // 0..31 within half
      int i = p * 64 + half * 32 + lrow;  // row within 128-row group
      f32x4 s4 = *reinterpret_cast<const f32x4*>(&S_lds[lrow * 264 + lane * 4]);
      float sv[4];
      unsigned um[4];
#pragma unroll
      for (int e = 0; e < 4; ++e) {
        sv[e] = s4[e] * 0.125f;
        unsigned u = __float_as_uint(sv[e]);
        // truncate ranking key to top 20 bits: count-preserving selection,
        // boundary tie-class ~ adjacent-sim gap -> output perturbation ~1e-4
        um[e] = ((u & 0x80000000u) ? ~u : (u | 0x80000000u)) & 0xFFFFF000u;
      }
      // prior loads hoisted above the ballot chain (latency hiding)
      float pl[4], ph[4];
      if (lvl > 0) {
        size_t baseLo = ((((size_t)b * prev_ng + plo_) * 8 + h) * GS + i) * WIN + lane * 4;
        size_t baseHi = ((((size_t)b * prev_ng + phi_) * 8 + h) * GS + i) * WIN + lane * 4;
        uint2 rlo = *reinterpret_cast<const uint2*>(prevA + baseLo);
        uint2 rhi = *reinterpret_cast<const uint2*>(prevA + baseHi);
        pl[0] = b2f_lo(rlo.x); pl[1] = b2f_hi(rlo.x);
        pl[2] = b2f_lo(rlo.y); pl[3] = b2f_hi(rlo.y);
        ph[0] = b2f_lo(rhi.x); ph[1] = b2f_hi(rhi.x);
        ph[2] = b2f_lo(rhi.y); ph[3] = b2f_hi(rhi.y);
      }
      // unmasked row max == masked max (top element always kept, kp>=128)
      float m = wave_max64(fmaxf(fmaxf(sv[0], sv[1]), fmaxf(sv[2], sv[3])));
      // fixed 20-step branchless bit-build over truncated keys
      unsigned T = 0u;
#pragma unroll
      for (int bit = 31; bit >= 12; --bit) {
        unsigned T2 = T | (1u << bit);
        int c = __popcll(__ballot(um[0] >= T2)) + __popcll(__ballot(um[1] >= T2))
              + __popcll(__ballot(um[2] >= T2)) + __popcll(__ballot(um[3] >= T2));
        T = (c >= kp) ? T2 : T;
      }
      int c_gt = __popcll(__ballot(um[0] > T)) + __popcll(__ballot(um[1] > T))
               + __popcll(__ballot(um[2] > T)) + __popcll(__ballot(um[3] > T));
      u64 beq[4];
#pragma unroll
      for (int e = 0; e < 4; ++e) beq[e] = __ballot(um[e] == T);
      int trbase = __popcll(beq[0] & lmask) + __popcll(beq[1] & lmask)
                 + __popcll(beq[2] & lmask) + __popcll(beq[3] & lmask);
      int need = kp - c_gt;
      bool msk[4];
      int own = 0;
#pragma unroll
      for (int e = 0; e < 4; ++e) {
        bool eq = (um[e] == T);
        msk[e] = (um[e] > T) || (eq && (trbase + own) < need);
        own += eq ? 1 : 0;
      }
      float ez[4], zs = 0.f;
#pragma unroll
      for (int e = 0; e < 4; ++e) { ez[e] = msk[e] ? __expf(sv[e] - m) : 0.f; zs += ez[e]; }
      zs = wave_sum64(zs);
      float at[4];
#pragma unroll
      for (int e = 0; e < 4; ++e) at[e] = ez[e] / zs;
      if (lvl > 0) {
#pragma unroll
        for (int e = 0; e < 4; ++e) {
          float pr = fmaxf((1.f - wgt) * pl[e] + wgt * ph[e], 0.f);
          at[e] = (1.f - beta) * at[e] + beta * pr;
        }
      }
      atp[half * 4 + j][0] = (unsigned)f2b(at[0]) | ((unsigned)f2b(at[1]) << 16);
      atp[half * 4 + j][1] = (unsigned)f2b(at[2]) | ((unsigned)f2b(at[3]) << 16);
      if (curA != nullptr) {
        uint2 o = { atp[half * 4 + j][0], atp[half * 4 + j][1] };
        *reinterpret_cast<uint2*>(curA + ((size_t)bgh * GS + i) * WIN + lane * 4) = o;
      }
    }
    __syncthreads();   // S half consumed before next half's write / P_half
  }

  // ---- PV via MFMA: O(64x64) = P(64x256) @ V(256x64), per-j-half P ----
  const u16* vbase = vbf + (size_t)b * n_l * DIMC + h * DV;
  int rf   = wave >> 1;                  // q-row frag 0..3
  int cf0  = (wave & 1) * 2;             // dv col frag base {0,2}
  int frow = lane & 15;
  int fk   = (lane >> 4) * 8;
  f32x4 oacc0 = { 0.f, 0.f, 0.f, 0.f };
  f32x4 oacc1 = { 0.f, 0.f, 0.f, 0.f };
  int jlo = t & 15, vd4 = (t >> 4) & 15, jh2 = t >> 8;

#pragma unroll
  for (int jp = 0; jp < 2; ++jp) {
    // stage Vt half (transposed V)
#pragma unroll
    for (int it = 0; it < 4; ++it) {
      int j = (jh2 * 4 + it) * 16 + jlo;           // 0..127
      int pp = g * GS + jp * 128 + j;
      int src = (pp < n_l) ? pp : (2 * n_l - 1 - pp);
      ushort4 vv = *reinterpret_cast<const ushort4*>(vbase + (size_t)src * DIMC + vd4 * 4);
      Vt[(vd4 * 4 + 0) * 136 + j] = vv.x;
      Vt[(vd4 * 4 + 1) * 136 + j] = vv.y;
      Vt[(vd4 * 4 + 2) * 136 + j] = vv.z;
      Vt[(vd4 * 4 + 3) * 136 + j] = vv.w;
    }
    // write this half's P from retained regs (lanes owning these keys)
    if ((lane >> 5) == jp) {
      int kl = (lane & 31) * 4;          // local key base within half
#pragma unroll
      for (int j = 0; j < 4; ++j) {
        uint2 oA = { atp[j][0], atp[j][1] };
        uint2 oB = { atp[4 + j][0], atp[4 + j][1] };
        *reinterpret_cast<uint2*>(&P_half[(wave * 4 + j) * 136 + kl]) = oA;
        *reinterpret_cast<uint2*>(&P_half[(32 + wave * 4 + j) * 136 + kl]) = oB;
      }
    }
    __syncthreads();
    __builtin_amdgcn_s_setprio(1);
#pragma unroll
    for (int ks = 0; ks < 4; ++ks) {
      bf16x8 a  = *reinterpret_cast<const bf16x8*>(&P_half[(rf * 16 + frow) * 136 + ks * 32 + fk]);
      bf16x8 b0 = *reinterpret_cast<const bf16x8*>(&Vt[(cf0 * 16 + frow) * 136 + ks * 32 + fk]);
      bf16x8 b1 = *reinterpret_cast<const bf16x8*>(&Vt[((cf0 + 1) * 16 + frow) * 136 + ks * 32 + fk]);
      oacc0 = __builtin_amdgcn_mfma_f32_16x16x32_bf16(a, b0, oacc0, 0, 0, 0);
      oacc1 = __builtin_amdgcn_mfma_f32_16x16x32_bf16(a, b1, oacc1, 0, 0, 0);
    }
    __builtin_amdgcn_s_setprio(0);
    __syncthreads();
  }

  u16* obase = outp + ((size_t)b * n_l + (size_t)g * GS + p * 64 + rf * 16) * DIMC + h * DV;
#pragma unroll
  for (int rr = 0; rr < 4; ++rr) {
    int qrow = (lane >> 4) * 4 + rr;
    obase[(size_t)qrow * DIMC + cf0 * 16 + frow]       = f2b(oacc0[rr]);
    obase[(size_t)qrow * DIMC + (cf0 + 1) * 16 + frow] = f2b(oacc1[rr]);
  }
}

// ---------------------------------------------------------------------------
extern "C" void kernel_launch(void* const* d_in, const int* in_sizes, int n_in,
                              void* d_out, int out_size, void* d_ws, size_t ws_size,
                              hipStream_t stream) {
  (void)in_sizes; (void)n_in; (void)out_size; (void)ws_size;
  const float* x        = (const float*)d_in[0];
  const int*   labels   = (const int*)d_in[1];
  const float* scores   = (const float*)d_in[2];
  const int*   idx_last = (const int*)d_in[3];
  const float* Wq       = (const float*)d_in[4];
  const float* Wk       = (const float*)d_in[5];
  const float* Wv       = (const float*)d_in[6];
  const float* Wp       = (const float*)d_in[7];
  const float* betaL    = (const float*)d_in[8];
  float* out = (float*)d_out;

  char* w = (char*)d_ws;
  size_t off = 0;
  auto take = [&](size_t bytes) -> char* {
    char* p = w + off;
    off += (bytes + 255) & ~(size_t)255;
    return p;
  };
  u16*   qhib   = (u16*)  take(16777216);   // q hi bf16 (16384 rows x 512)
  u16*   qlob   = (u16*)  take(16777216);   // q lo
  u16*   khib   = (u16*)  take(16777216);   // k hi
  u16*   klob   = (u16*)  take(16777216);   // k lo
  u16*   vbf    = (u16*)  take(16777216);   // v bf16
  u16*   xhi    = (u16*)  take(16777216);   // A hi / attn-out (disjoint lifetimes)
  u16*   xlo    = (u16*)  take(16777216);   // A lo
  u16*   attnA  = (u16*)  take(16777216);   // lvl0 attn bf16
  u16*   attnB  = (u16*)  take(33554432);   // lvl1 attn bf16
  u16*   whiAll = (u16*)  take(6291456);    // 12 x [512][512] bf16 hi
  u16*   wloAll = (u16*)  take(3145728);    // 6  x [512][512] bf16 lo (q,k)
  float* sl     = (float*)take(65536);      // pooled scores lvl0 [0,4096) lvl1 [4096,12288)
  int*   ll     = (int*)  take(65536);      // pooled labels, same offsets
  int*   keepb  = (int*)  take(1024);       // keep: lvl0 @0, lvl1 @32, lvl2 @96
  // total ~178 MB

  const size_t ROW1 = 4096;                 // lvl1 row offset in shared buffers

  wprep_kernel<<<3072, 256, 0, stream>>>(Wq, Wk, Wv, Wp, whiAll, wloAll);
  pool_split01_kernel<<<6144, 256, 0, stream>>>(x, scores, xhi, xlo, sl);
  pool_label01_kernel<<<48, 256, 0, stream>>>(labels, scores, ll);
  keep_all_kernel<<<2, 128, 0, stream>>>(ll, sl, labels, scores, keepb);

  {
    dim3 gq(12, 96);
    qkv_gemm_kernel<<<gq, 256, 0, stream>>>(xhi, xlo, whiAll, wloAll,
                                            qhib, qlob, khib, klob, vbf,
                                            0, 1, 32, (int)ROW1);
  }

  // ---- level 0 ----
  attn_fused_kernel<<<2 * 16 * 8 * 2, 512, 0, stream>>>(
      qhib, qlob, khib, klob, vbf, keepb, nullptr, attnA,
      betaL, xhi, 0, 2048, 16, 8);
  {
    dim3 gp(4, 32);
    wp_gemm_kernel<2><<<gp, 256, 0, stream>>>(xhi, whiAll + (size_t)9 * WSZ,
                                              out, idx_last, 4096, 4, 2048);
  }

  // ---- level 1 (buffers at row offset 4096) ----
  attn_fused_kernel<<<2 * 32 * 8 * 2, 512, 0, stream>>>(
      qhib + ROW1 * DIMC, qlob + ROW1 * DIMC, khib + ROW1 * DIMC, klob + ROW1 * DIMC,
      vbf + ROW1 * DIMC, keepb + 32, attnA, attnB,
      betaL, xhi + ROW1 * DIMC, 1, 4096, 32, 16);
  {
    dim3 gp(4, 64);
    wp_gemm_kernel<3><<<gp, 256, 0, stream>>>(xhi + ROW1 * DIMC, whiAll + (size_t)10 * WSZ,
                                              out, idx_last, 8192, 2, 4096);
  }

  // ---- level 2 (reuses all buffers from row 0) ----
  asplit_kernel<<<(2 * NTOK * 128) / 256, 256, 0, stream>>>(x, xhi, xlo);
  {
    dim3 gq(12, 128);
    qkv_gemm_kernel<<<gq, 256, 0, stream>>>(xhi, xlo, whiAll, wloAll,
                                            qhib, qlob, khib, klob, vbf,
                                            2, 2, 1 << 20, 0);
  }
  attn_fused_kernel<<<2 * 64 * 8 * 2, 512, 0, stream>>>(
      qhib, qlob, khib, klob, vbf, keepb + 96, attnB, nullptr,
      betaL, xhi, 2, 8192, 64, 32);
  {
    dim3 gp(4, 128);
    wp_gemm_kernel<3><<<gp, 256, 0, stream>>>(xhi, whiAll + (size_t)11 * WSZ,
                                              out, idx_last, 16384, 1, 8192);
  }
}

// Round 16
// 498.908 us; speedup vs baseline: 1.1436x; 1.0356x over previous
//
#include <hip/hip_runtime.h>
#include <math.h>

// ---------------------------------------------------------------------------
// LowToHighMultiLevelReconstruction — round 16.
// Changes vs round 15:
//  1. REVERT ballot to round-14 (32-bit keys + wave-uniform early exit;
//     round-15's fixed 20-step loop was LONGER than the avg early-exit path).
//  2. XCD-aware chunked block swizzle (T1) on attn / qkv / wp grids:
//     swz = (bid&7)*(n/8) + (bid>>3), all grid sizes %8==0 (bijective).
//     Co-locates K/V-window-sharing attn blocks and A-panel-sharing GEMM
//     blocks on one XCD's L2 (cuts cross-XCD re-fetch).
// ---------------------------------------------------------------------------

#define GS   128
#define WIN  256        // 2*GS
#define DQK  64
#define DV   64
#define DIMC 512
#define NTOK 8192
#define WSZ  262144     // 512*512 elements per weight matrix

typedef unsigned long long u64;
typedef unsigned short u16;
typedef __attribute__((ext_vector_type(8))) short bf16x8;
typedef __attribute__((ext_vector_type(4))) float f32x4;

__device__ __forceinline__ u16 f2b(float f) {     // f32 -> bf16 RNE
  unsigned u = __float_as_uint(f);
  u = (u + 0x7fffu + ((u >> 16) & 1u)) >> 16;
  return (u16)u;
}
__device__ __forceinline__ float b2f(u16 h) { return __uint_as_float(((unsigned)h) << 16); }
__device__ __forceinline__ float b2f_lo(unsigned u) { return __uint_as_float(u << 16); }
__device__ __forceinline__ float b2f_hi(unsigned u) { return __uint_as_float(u & 0xffff0000u); }

__device__ __forceinline__ float wave_max64(float v) {
#pragma unroll
  for (int m = 1; m < 64; m <<= 1) v = fmaxf(v, __shfl_xor(v, m, 64));
  return v;
}
__device__ __forceinline__ float wave_sum64(float v) {
#pragma unroll
  for (int m = 1; m < 64; m <<= 1) v += __shfl_xor(v, m, 64);
  return v;
}

// ------------------------------ pooling lvl0+lvl1 (writes split bf16) -------
__global__ void pool_split01_kernel(const float* __restrict__ x,
                                    const float* __restrict__ scores,
                                    u16* __restrict__ xhi, u16* __restrict__ xlo,
                                    float* __restrict__ sl) {
  int tid = blockIdx.x * 256 + threadIdx.x;     // 0..1572863
  int scale, npool, rowoff, rest;
  if (tid < 524288) { scale = 4; npool = 2048; rowoff = 0;    rest = tid >> 7; }
  else { tid -= 524288; scale = 2; npool = 4096; rowoff = 4096; rest = tid >> 7; }
  int c4 = tid & 127;
  int g  = rest % npool;
  int b  = rest / npool;
  const float* xp = x + ((size_t)b * NTOK + (size_t)g * scale) * DIMC + c4 * 4;
  float ax = 0.f, ay = 0.f, az = 0.f, aw = 0.f, wsum = 0.f, ssum = 0.f;
  for (int s = 0; s < scale; ++s) {
    float sc = scores[(size_t)b * NTOK + (size_t)g * scale + s];
    float w  = fmaxf(sc, 1e-6f);
    float4 xv = *reinterpret_cast<const float4*>(xp + (size_t)s * DIMC);
    ax += xv.x * w; ay += xv.y * w; az += xv.z * w; aw += xv.w * w;
    wsum += w; ssum += sc;
  }
  float o[4] = { ax / wsum, ay / wsum, az / wsum, aw / wsum };
  ushort4 h, l;
  h.x = f2b(o[0]); h.y = f2b(o[1]); h.z = f2b(o[2]); h.w = f2b(o[3]);
  l.x = f2b(o[0] - b2f(h.x)); l.y = f2b(o[1] - b2f(h.y));
  l.z = f2b(o[2] - b2f(h.z)); l.w = f2b(o[3] - b2f(h.w));
  size_t row = (size_t)rowoff + (size_t)b * npool + g;
  size_t off = row * DIMC + c4 * 4;
  *reinterpret_cast<ushort4*>(xhi + off) = h;
  *reinterpret_cast<ushort4*>(xlo + off) = l;
  if (c4 == 0) sl[row] = ssum / (float)scale;
}

__global__ void pool_label01_kernel(const int* __restrict__ labels,
                                    const float* __restrict__ scores,
                                    int* __restrict__ ll) {
  int tid = blockIdx.x * 256 + threadIdx.x;     // 0..12287
  int scale, npool, rowoff;
  if (tid < 4096) { scale = 4; npool = 2048; rowoff = 0; }
  else { tid -= 4096; scale = 2; npool = 4096; rowoff = 4096; }
  int b = tid / npool, g = tid % npool;
  float counts[4] = {0.f, 0.f, 0.f, 0.f};
  float ssum[4]   = {0.f, 0.f, 0.f, 0.f};
  int firstp[4];
  for (int c = 0; c < 4; ++c) firstp[c] = scale;
  for (int s = 0; s < scale; ++s) {
    int   L = labels[(size_t)b * NTOK + (size_t)g * scale + s];
    float S = scores[(size_t)b * NTOK + (size_t)g * scale + s];
    counts[L] += 1.0f;
    ssum[L]   += S;
    if (s < firstp[L]) firstp[L] = s;
  }
  float cmax = fmaxf(fmaxf(counts[0], counts[1]), fmaxf(counts[2], counts[3]));
  float s2[4];
  for (int c = 0; c < 4; ++c) s2[c] = (counts[c] == cmax) ? ssum[c] : -1e9f;
  float smax = fmaxf(fmaxf(s2[0], s2[1]), fmaxf(s2[2], s2[3]));
  int fp[4];
  for (int c = 0; c < 4; ++c) fp[c] = (s2[c] == smax) ? firstp[c] : scale;
  int best = 0, bv = fp[0];
  for (int c = 1; c < 4; ++c) if (fp[c] < bv) { bv = fp[c]; best = c; }
  ll[rowoff + b * npool + g] = best;
}

// --------------------------------------------------- raw x split (lvl 2) ----
__global__ void asplit_kernel(const float* __restrict__ x,
                              u16* __restrict__ xhi, u16* __restrict__ xlo) {
  int tid = blockIdx.x * 256 + threadIdx.x;     // over 2*NTOK*128 float4s
  float4 v = *reinterpret_cast<const float4*>(x + (size_t)tid * 4);
  ushort4 h, l;
  h.x = f2b(v.x); h.y = f2b(v.y); h.z = f2b(v.z); h.w = f2b(v.w);
  l.x = f2b(v.x - b2f(h.x)); l.y = f2b(v.y - b2f(h.y));
  l.z = f2b(v.z - b2f(h.z)); l.w = f2b(v.w - b2f(h.w));
  *reinterpret_cast<ushort4*>(xhi + (size_t)tid * 4) = h;
  *reinterpret_cast<ushort4*>(xlo + (size_t)tid * 4) = l;
}

// -------------------------- keep for ALL levels in one launch ---------------
__global__ void keep_all_kernel(const int* __restrict__ ll, const float* __restrict__ sl,
                                const int* __restrict__ labels,
                                const float* __restrict__ scores,
                                int* __restrict__ keep) {
  int tid = blockIdx.x * 128 + threadIdx.x;
  if (tid >= 224) return;
  const int* lp; const float* sp;
  if (tid < 32) {
    int b = tid >> 4, g = tid & 15;
    lp = ll + (b * 2048 + g * GS);
    sp = sl + (b * 2048 + g * GS);
  } else if (tid < 96) {
    int e = tid - 32;
    int b = e >> 5, g = e & 31;
    lp = ll + 4096 + (b * 4096 + g * GS);
    sp = sl + 4096 + (b * 4096 + g * GS);
  } else {
    int e = tid - 96;
    int b = e >> 6, g = e & 63;
    lp = labels + ((size_t)b * NTOK + g * GS);
    sp = scores + ((size_t)b * NTOK + g * GS);
  }
  float counts[4] = {0.f, 0.f, 0.f, 0.f};
  for (int i = 0; i < GS; ++i) counts[lp[i]] += 1.f;
  int mode = 0; float bv = counts[0];
  for (int c = 1; c < 4; ++c) if (counts[c] > bv) { bv = counts[c]; mode = c; }
  float pm = 0.f, mean = 0.f;
  for (int i = 0; i < GS; ++i) { pm += (lp[i] == mode) ? 1.f : 0.f; mean += sp[i]; }
  float purity = pm / (float)GS;
  mean /= (float)GS;
  float var = 0.f;
  for (int i = 0; i < GS; ++i) { float d = sp[i] - mean; var += d * d; }
  var /= (float)GS;
  float focus = 0.5f + 0.25f * purity - 0.25f * var;
  focus = fminf(fmaxf(focus, 0.25f), 0.75f);
  keep[tid] = (int)ceilf(focus * (float)WIN);
}

// --------------------- ALL weight transpose+split in one launch (12 mats) ---
__global__ __launch_bounds__(256) void wprep_kernel(
    const float* __restrict__ Wq, const float* __restrict__ Wk,
    const float* __restrict__ Wv, const float* __restrict__ Wp,
    u16* __restrict__ whiAll, u16* __restrict__ wloAll) {
  __shared__ float tile[32][33];
  int blk = blockIdx.x;            // 0..3071
  int mat = blk >> 8;              // 0..11
  int sub = blk & 255;
  int kind = mat / 3, lvl = mat % 3;
  const float* W = (kind == 0 ? Wq : kind == 1 ? Wk : kind == 2 ? Wv : Wp)
                   + (size_t)lvl * WSZ;
  u16* bthi = whiAll + (size_t)mat * WSZ;
  u16* btlo = (mat < 6) ? (wloAll + (size_t)mat * WSZ) : nullptr;

  int bx = sub & 15;               // n block
  int by = sub >> 4;               // k block
  int tx = threadIdx.x & 31;
  int ty = threadIdx.x >> 5;       // 0..7
#pragma unroll
  for (int i = 0; i < 4; ++i) {
    int kk = ty + i * 8;
    tile[kk][tx] = W[(size_t)(by * 32 + kk) * 512 + bx * 32 + tx];
  }
  __syncthreads();
#pragma unroll
  for (int i = 0; i < 4; ++i) {
    int nn = ty + i * 8;
    float v = tile[tx][nn];        // = W[by*32+tx][bx*32+nn]
    u16 h = f2b(v);
    size_t o = (size_t)(bx * 32 + nn) * 512 + by * 32 + tx;
    bthi[o] = h;
    if (btlo) btlo[o] = f2b(v - b2f(h));
  }
}

// ---------------------------------------------------- fused q/k/v GEMM ------
// Logical work decoded from XCD-chunk-swizzled linear block id.
__global__ __launch_bounds__(256) void qkv_gemm_kernel(
    const u16* __restrict__ Ahi, const u16* __restrict__ Alo,
    const u16* __restrict__ whiAll, const u16* __restrict__ wloAll,
    u16* __restrict__ qhi, u16* __restrict__ qlo,
    u16* __restrict__ khi, u16* __restrict__ klo, u16* __restrict__ vbf,
    int lvlA, int lvlB, int ysplit, int rowB) {
  __shared__ u16 smem[4 * 4096];
  u16* sAhi = smem;
  u16* sBhi = smem + 4096;
  u16* sAlo = smem + 2 * 4096;
  u16* sBlo = smem + 3 * 4096;

  // XCD chunked swizzle (n % 8 == 0): hw block lin -> logical swz
  int lin = blockIdx.y * 12 + blockIdx.x;
  int n = gridDim.y * 12;
  int swz = (lin & 7) * (n >> 3) + (lin >> 3);
  int xx = swz % 12;
  int ry = swz / 12;
  int sel = xx >> 2;               // 0=q, 1=k, 2=v
  int cx  = xx & 3;
  bool split = (sel < 2);
  int lvl   = (ry < ysplit) ? lvlA : lvlB;
  int row0  = (ry < ysplit) ? ry * 128 : rowB + (ry - ysplit) * 128;
  const u16* Bh = whiAll + (size_t)(sel * 3 + lvl) * WSZ;
  const u16* Bl = wloAll + (size_t)(sel * 3 + lvl) * WSZ;   // valid only sel<2

  int t = threadIdx.x, lane = t & 63, wave = t >> 6;
  int wr = wave >> 1, wc = wave & 1;
  int col0 = cx * 128;

  int srow = (lane >> 2);
  int schk = (lane & 3) * 8;

  const f32x4 zero = { 0.f, 0.f, 0.f, 0.f };
  f32x4 acc[4][4];
#pragma unroll
  for (int i = 0; i < 4; ++i)
#pragma unroll
    for (int j = 0; j < 4; ++j) acc[i][j] = zero;

  for (int k0 = 0; k0 < 512; k0 += 32) {
#pragma unroll
    for (int j = 0; j < 2; ++j) {
      int r = wave * 32 + j * 16 + srow;
      const u16* gA = Ahi + (size_t)(row0 + r) * 512 + k0 + schk;
      const u16* gB = Bh + (size_t)(col0 + r) * 512 + k0 + schk;
      __builtin_amdgcn_global_load_lds(
          (const __attribute__((address_space(1))) void*)gA,
          (__attribute__((address_space(3))) void*)&sAhi[(wave * 32 + j * 16) * 32],
          16, 0, 0);
      __builtin_amdgcn_global_load_lds(
          (const __attribute__((address_space(1))) void*)gB,
          (__attribute__((address_space(3))) void*)&sBhi[(wave * 32 + j * 16) * 32],
          16, 0, 0);
      if (split) {
        const u16* gAl = Alo + (size_t)(row0 + r) * 512 + k0 + schk;
        const u16* gBl = Bl + (size_t)(col0 + r) * 512 + k0 + schk;
        __builtin_amdgcn_global_load_lds(
            (const __attribute__((address_space(1))) void*)gAl,
            (__attribute__((address_space(3))) void*)&sAlo[(wave * 32 + j * 16) * 32],
            16, 0, 0);
        __builtin_amdgcn_global_load_lds(
            (const __attribute__((address_space(1))) void*)gBl,
            (__attribute__((address_space(3))) void*)&sBlo[(wave * 32 + j * 16) * 32],
            16, 0, 0);
      }
    }
    __syncthreads();

    int fr = lane & 15;
    int kf = (lane >> 4) * 8;
    bf16x8 ah[4], bh[4], al[4], bl[4];
#pragma unroll
    for (int i = 0; i < 4; ++i) {
      ah[i] = *reinterpret_cast<const bf16x8*>(&sAhi[(wr * 64 + i * 16 + fr) * 32 + kf]);
      bh[i] = *reinterpret_cast<const bf16x8*>(&sBhi[(wc * 64 + i * 16 + fr) * 32 + kf]);
      if (split) {
        al[i] = *reinterpret_cast<const bf16x8*>(&sAlo[(wr * 64 + i * 16 + fr) * 32 + kf]);
        bl[i] = *reinterpret_cast<const bf16x8*>(&sBlo[(wc * 64 + i * 16 + fr) * 32 + kf]);
      }
    }
#pragma unroll
    for (int i = 0; i < 4; ++i)
#pragma unroll
      for (int j = 0; j < 4; ++j) {
        acc[i][j] = __builtin_amdgcn_mfma_f32_16x16x32_bf16(ah[i], bh[j], acc[i][j], 0, 0, 0);
        if (split) {
          acc[i][j] = __builtin_amdgcn_mfma_f32_16x16x32_bf16(ah[i], bl[j], acc[i][j], 0, 0, 0);
          acc[i][j] = __builtin_amdgcn_mfma_f32_16x16x32_bf16(al[i], bh[j], acc[i][j], 0, 0, 0);
        }
      }
    __syncthreads();
  }

  int ccol = col0 + wc * 64 + (lane & 15);
  int crow = row0 + wr * 64 + (lane >> 4) * 4;
  if (sel == 2) {
#pragma unroll
    for (int i = 0; i < 4; ++i)
#pragma unroll
      for (int r = 0; r < 4; ++r) {
        int gr = crow + i * 16 + r;
#pragma unroll
        for (int j = 0; j < 4; ++j)
          vbf[(size_t)gr * 512 + ccol + j * 16] = f2b(acc[i][j][r]);
      }
  } else {
    u16* Ch = (sel == 0) ? qhi : khi;
    u16* Cl = (sel == 0) ? qlo : klo;
#pragma unroll
    for (int i = 0; i < 4; ++i)
#pragma unroll
      for (int r = 0; r < 4; ++r) {
        int gr = crow + i * 16 + r;
#pragma unroll
        for (int j = 0; j < 4; ++j) {
          float v = acc[i][j][r];
          u16 hh = f2b(v);
          Ch[(size_t)gr * 512 + ccol + j * 16] = hh;
          Cl[(size_t)gr * 512 + ccol + j * 16] = f2b(v - b2f(hh));
        }
      }
  }
}

// --------------------------------------------------- Wp GEMM (scatter) ------
template<int EMODE>
__global__ __launch_bounds__(256) void wp_gemm_kernel(
    const u16* __restrict__ Ahi, const u16* __restrict__ Bthi,
    float* __restrict__ C, const int* __restrict__ idx,
    int M, int scale, int n_l) {
  __shared__ u16 smem[2 * 4096];
  u16* sAhi = smem;
  u16* sBhi = smem + 4096;

  // XCD chunked swizzle (grid (4,Y), n % 8 == 0)
  int lin = blockIdx.y * 4 + blockIdx.x;
  int n = gridDim.y * 4;
  int swz = (lin & 7) * (n >> 3) + (lin >> 3);
  int row0 = (swz >> 2) * 128, col0 = (swz & 3) * 128;

  int t = threadIdx.x, lane = t & 63, wave = t >> 6;
  int wr = wave >> 1, wc = wave & 1;

  int srow = (lane >> 2);
  int schk = (lane & 3) * 8;

  const f32x4 zero = { 0.f, 0.f, 0.f, 0.f };
  f32x4 acc[4][4];
#pragma unroll
  for (int i = 0; i < 4; ++i)
#pragma unroll
    for (int j = 0; j < 4; ++j) acc[i][j] = zero;

  for (int k0 = 0; k0 < 512; k0 += 32) {
#pragma unroll
    for (int j = 0; j < 2; ++j) {
      int r = wave * 32 + j * 16 + srow;
      const u16* gA = Ahi + (size_t)(row0 + r) * 512 + k0 + schk;
      const u16* gB = Bthi + (size_t)(col0 + r) * 512 + k0 + schk;
      __builtin_amdgcn_global_load_lds(
          (const __attribute__((address_space(1))) void*)gA,
          (__attribute__((address_space(3))) void*)&sAhi[(wave * 32 + j * 16) * 32],
          16, 0, 0);
      __builtin_amdgcn_global_load_lds(
          (const __attribute__((address_space(1))) void*)gB,
          (__attribute__((address_space(3))) void*)&sBhi[(wave * 32 + j * 16) * 32],
          16, 0, 0);
    }
    __syncthreads();

    int fr = lane & 15;
    int kf = (lane >> 4) * 8;
    bf16x8 ah[4], bh[4];
#pragma unroll
    for (int i = 0; i < 4; ++i) {
      ah[i] = *reinterpret_cast<const bf16x8*>(&sAhi[(wr * 64 + i * 16 + fr) * 32 + kf]);
      bh[i] = *reinterpret_cast<const bf16x8*>(&sBhi[(wc * 64 + i * 16 + fr) * 32 + kf]);
    }
#pragma unroll
    for (int i = 0; i < 4; ++i)
#pragma unroll
      for (int j = 0; j < 4; ++j)
        acc[i][j] = __builtin_amdgcn_mfma_f32_16x16x32_bf16(ah[i], bh[j], acc[i][j], 0, 0, 0);
    __syncthreads();
  }

  int ccol = col0 + wc * 64 + (lane & 15);
  int crow = row0 + wr * 64 + (lane >> 4) * 4;
#pragma unroll
  for (int i = 0; i < 4; ++i) {
#pragma unroll
    for (int r = 0; r < 4; ++r) {
      int gr = crow + i * 16 + r;
      int bb = gr / n_l, rr = gr - bb * n_l;
      for (int s = 0; s < scale; ++s) {
        int dst = idx[(size_t)bb * NTOK + (size_t)rr * scale + s];
        float* p = C + ((size_t)bb * NTOK + dst) * 512 + ccol;
        if (EMODE == 3) {
#pragma unroll
          for (int j = 0; j < 4; ++j) p[j * 16] += acc[i][j][r];
        } else {
#pragma unroll
          for (int j = 0; j < 4; ++j) p[j * 16] = acc[i][j][r];
        }
      }
    }
  }
}

// ----------------------------------------------- fused windowed attention ---
// (round-14 structure; logical block id decoded from XCD-chunk swizzle so
// the 16 blocks sharing a K/V window co-locate on one XCD's L2)
__global__ __launch_bounds__(512) void attn_fused_kernel(
    const u16* __restrict__ qhi, const u16* __restrict__ qlo,
    const u16* __restrict__ khi, const u16* __restrict__ klo,
    const u16* __restrict__ vbf, const int* __restrict__ keepArr,
    const u16* __restrict__ prevA, u16* __restrict__ curA,
    const float* __restrict__ betaL, u16* __restrict__ outp,
    int lvl, int n_l, int ng, int prev_ng) {
  __shared__ u64 smem8[5120];             // 40960 B
  u16*   Khi_s  = (u16*)smem8;            // [256][32] @0     (phase A stage)
  u16*   Klo_s  = Khi_s + 256 * 32;       // @16384
  u16*   Qhi_s  = Klo_s + 256 * 32;       // [64][32] @32768
  u16*   Qlo_s  = Qhi_s + 64 * 32;        // @36864 (..40960)
  float* S_lds  = (float*)smem8;          // [32][264] f32 @0..33792
  u16*   P_half = (u16*)smem8;            // [64][136] @0..17408   (phase B)
  u16*   Vt     = P_half + 64 * 136;      // [64][136] @17408..34816

  int t = threadIdx.x;
  int lane = t & 63, wave = t >> 6;
  // XCD chunked swizzle (gridDim.x % 8 == 0)
  int nwg = gridDim.x;
  int bid = (blockIdx.x & 7) * (nwg >> 3) + (blockIdx.x >> 3);
  int p   = bid & 1;
  int h   = (bid >> 1) & 7;
  int gl  = bid >> 4;
  int g   = gl % ng;
  int b   = gl / ng;
  int bgh = bid >> 1;                     // (b,g,h) index for attn state

  const u16* qhbase = qhi + ((size_t)b * n_l + (size_t)g * GS + p * 64) * DIMC + h * DQK;
  const u16* qlbase = qlo + ((size_t)b * n_l + (size_t)g * GS + p * 64) * DIMC + h * DQK;
  const u16* khbase = khi + (size_t)b * n_l * DIMC + h * DQK;
  const u16* klbase = klo + (size_t)b * n_l * DIMC + h * DQK;

  // ---- phase A: sim via MFMA (3-product split), acc over 2 d-halves ----
  int qt  = wave >> 1;                    // q-tile 0..3
  int ktb = (wave & 1) * 8;               // key-tile base 0 or 8
  f32x4 acc[8];
#pragma unroll
  for (int i = 0; i < 8; ++i) acc[i] = (f32x4){0.f, 0.f, 0.f, 0.f};

#pragma unroll
  for (int dp = 0; dp < 2; ++dp) {
    if (dp) __syncthreads();              // previous half's frags consumed
    int d0 = dp * 32;
#pragma unroll
    for (int ii = 0; ii < 2; ++ii) {
      int row = wave * 32 + ii * 16 + (lane >> 2);
      int pp = g * GS + row;
      int src = (pp < n_l) ? pp : (2 * n_l - 1 - pp);
      const u16* gH = khbase + (size_t)src * DIMC + d0 + (lane & 3) * 8;
      const u16* gL = klbase + (size_t)src * DIMC + d0 + (lane & 3) * 8;
      __builtin_amdgcn_global_load_lds(
          (const __attribute__((address_space(1))) void*)gH,
          (__attribute__((address_space(3))) void*)&Khi_s[(wave * 32 + ii * 16) * 32],
          16, 0, 0);
      __builtin_amdgcn_global_load_lds(
          (const __attribute__((address_space(1))) void*)gL,
          (__attribute__((address_space(3))) void*)&Klo_s[(wave * 32 + ii * 16) * 32],
          16, 0, 0);
    }
    if (wave < 4) {
      int row = wave * 16 + (lane >> 2);
      const u16* gH = qhbase + (size_t)row * DIMC + d0 + (lane & 3) * 8;
      __builtin_amdgcn_global_load_lds(
          (const __attribute__((address_space(1))) void*)gH,
          (__attribute__((address_space(3))) void*)&Qhi_s[(wave * 16) * 32],
          16, 0, 0);
    } else {
      int row = (wave - 4) * 16 + (lane >> 2);
      const u16* gL = qlbase + (size_t)row * DIMC + d0 + (lane & 3) * 8;
      __builtin_amdgcn_global_load_lds(
          (const __attribute__((address_space(1))) void*)gL,
          (__attribute__((address_space(3))) void*)&Qlo_s[((wave - 4) * 16) * 32],
          16, 0, 0);
    }
    __syncthreads();

    int fr = lane & 15;
    int kf = (lane >> 4) * 8;
    bf16x8 bqh = *reinterpret_cast<const bf16x8*>(&Qhi_s[(qt * 16 + fr) * 32 + kf]);
    bf16x8 bql = *reinterpret_cast<const bf16x8*>(&Qlo_s[(qt * 16 + fr) * 32 + kf]);
    __builtin_amdgcn_s_setprio(1);
#pragma unroll
    for (int kt = 0; kt < 8; ++kt) {
      bf16x8 akh = *reinterpret_cast<const bf16x8*>(&Khi_s[((ktb + kt) * 16 + fr) * 32 + kf]);
      bf16x8 akl = *reinterpret_cast<const bf16x8*>(&Klo_s[((ktb + kt) * 16 + fr) * 32 + kf]);
      acc[kt] = __builtin_amdgcn_mfma_f32_16x16x32_bf16(akh, bqh, acc[kt], 0, 0, 0);
      acc[kt] = __builtin_amdgcn_mfma_f32_16x16x32_bf16(akh, bql, acc[kt], 0, 0, 0);
      acc[kt] = __builtin_amdgcn_mfma_f32_16x16x32_bf16(akl, bqh, acc[kt], 0, 0, 0);
    }
    __builtin_amdgcn_s_setprio(0);
  }
  __syncthreads();   // staging LDS dead; S_lds may overwrite

  int kp = keepArr[b * ng + g];
  float beta = 0.f, wgt = 0.f;
  int plo_ = 0, phi_ = 0;
  if (lvl > 0) {
    beta = 1.f / (1.f + expf(-betaL[lvl]));
    float pos = ((float)g + 0.5f) * ((float)prev_ng / (float)ng) - 0.5f;
    float fl = floorf(pos);
    plo_ = (int)fl;
    if (plo_ < 0) plo_ = 0;
    if (plo_ > prev_ng - 1) plo_ = prev_ng - 1;
    phi_ = plo_ + 1; if (phi_ > prev_ng - 1) phi_ = prev_ng - 1;
    wgt = fminf(fmaxf(pos - fl, 0.f), 1.f);
  }
  u64 lmask = (1ull << lane) - 1ull;

  // ---- S halves -> ballot top-k -> softmax -> prior; retain packed bf16 ----
  unsigned atp[8][2];
#pragma unroll
  for (int half = 0; half < 2; ++half) {
    if ((wave >> 2) == half) {
      int ql = ((wave >> 1) & 1) * 16 + (lane & 15);   // q-local within half
#pragma unroll
      for (int kt = 0; kt < 8; ++kt) {
        int key = (ktb + kt) * 16 + (lane >> 4) * 4;
        *reinterpret_cast<f32x4*>(&S_lds[ql * 264 + key]) = acc[kt];
      }
    }
    __syncthreads();
#pragma unroll
    for (int j = 0; j < 4; ++j) {
      int lrow = wave * 4 + j;            // 0..31 within half
      int i = p * 64 + half * 32 + lrow;  // row within 128-row group
      f32x4 s4 = *reinterpret_cast<const f32x4*>(&S_lds[lrow * 264 + lane * 4]);
      float sv[4];
      unsigned um[4];
#pragma unroll
      for (int e = 0; e < 4; ++e) {
        sv[e] = s4[e] * 0.125f;
        unsigned u = __float_as_uint(sv[e]);
        um[e] = (u & 0x80000000u) ? ~u : (u | 0x80000000u);
      }
      // unmasked row max == masked max (top element always kept, kp>=128)
      float m = wave_max64(fmaxf(fmaxf(sv[0], sv[1]), fmaxf(sv[2], sv[3])));
      unsigned T = 0u;
      for (int bit = 31; bit >= 0; --bit) {
        unsigned T2 = T | (1u << bit);
        int c = __popcll(__ballot(um[0] >= T2)) + __popcll(__ballot(um[1] >= T2))
              + __popcll(__ballot(um[2] >= T2)) + __popcll(__ballot(um[3] >= T2));
        if (c >= kp) { T = T2; if (c == kp) break; }
      }
      int c_gt = __popcll(__ballot(um[0] > T)) + __popcll(__ballot(um[1] > T))
               + __popcll(__ballot(um[2] > T)) + __popcll(__ballot(um[3] > T));
      u64 beq[4];
#pragma unroll
      for (int e = 0; e < 4; ++e) beq[e] = __ballot(um[e] == T);
      int trbase = __popcll(beq[0] & lmask) + __popcll(beq[1] & lmask)
                 + __popcll(beq[2] & lmask) + __popcll(beq[3] & lmask);
      int need = kp - c_gt;
      bool msk[4];
      int own = 0;
#pragma unroll
      for (int e = 0; e < 4; ++e) {
        bool eq = (um[e] == T);
        msk[e] = (um[e] > T) || (eq && (trbase + own) < need);
        own += eq ? 1 : 0;
      }
      float ez[4], zs = 0.f;
#pragma unroll
      for (int e = 0; e < 4; ++e) { ez[e] = msk[e] ? __expf(sv[e] - m) : 0.f; zs += ez[e]; }
      zs = wave_sum64(zs);
      float at[4];
#pragma unroll
      for (int e = 0; e < 4; ++e) at[e] = ez[e] / zs;
      if (lvl > 0) {
        size_t baseLo = ((((size_t)b * prev_ng + plo_) * 8 + h) * GS + i) * WIN + lane * 4;
        size_t baseHi = ((((size_t)b * prev_ng + phi_) * 8 + h) * GS + i) * WIN + lane * 4;
        uint2 rlo = *reinterpret_cast<const uint2*>(prevA + baseLo);
        uint2 rhi = *reinterpret_cast<const uint2*>(prevA + baseHi);
        float pl[4] = { b2f_lo(rlo.x), b2f_hi(rlo.x), b2f_lo(rlo.y), b2f_hi(rlo.y) };
        float ph[4] = { b2f_lo(rhi.x), b2f_hi(rhi.x), b2f_lo(rhi.y), b2f_hi(rhi.y) };
        // prior rows are stored normalized; skip re-normalizing reduction
#pragma unroll
        for (int e = 0; e < 4; ++e) {
          float pr = fmaxf((1.f - wgt) * pl[e] + wgt * ph[e], 0.f);
          at[e] = (1.f - beta) * at[e] + beta * pr;
        }
      }
      atp[half * 4 + j][0] = (unsigned)f2b(at[0]) | ((unsigned)f2b(at[1]) << 16);
      atp[half * 4 + j][1] = (unsigned)f2b(at[2]) | ((unsigned)f2b(at[3]) << 16);
      if (curA != nullptr) {
        uint2 o = { atp[half * 4 + j][0], atp[half * 4 + j][1] };
        *reinterpret_cast<uint2*>(curA + ((size_t)bgh * GS + i) * WIN + lane * 4) = o;
      }
    }
    __syncthreads();   // S half consumed before next half's write / P_half
  }

  // ---- PV via MFMA: O(64x64) = P(64x256) @ V(256x64), per-j-half P ----
  const u16* vbase = vbf + (size_t)b * n_l * DIMC + h * DV;
  int rf   = wave >> 1;                  // q-row frag 0..3
  int cf0  = (wave & 1) * 2;             // dv col frag base {0,2}
  int frow = lane & 15;
  int fk   = (lane >> 4) * 8;
  f32x4 oacc0 = { 0.f, 0.f, 0.f, 0.f };
  f32x4 oacc1 = { 0.f, 0.f, 0.f, 0.f };
  int jlo = t & 15, vd4 = (t >> 4) & 15, jh2 = t >> 8;

#pragma unroll
  for (int jp = 0; jp < 2; ++jp) {
    // stage Vt half (transposed V)
#pragma unroll
    for (int it = 0; it < 4; ++it) {
      int j = (jh2 * 4 + it) * 16 + jlo;           // 0..127
      int pp = g * GS + jp * 128 + j;
      int src = (pp < n_l) ? pp : (2 * n_l - 1 - pp);
      ushort4 vv = *reinterpret_cast<const ushort4*>(vbase + (size_t)src * DIMC + vd4 * 4);
      Vt[(vd4 * 4 + 0) * 136 + j] = vv.x;
      Vt[(vd4 * 4 + 1) * 136 + j] = vv.y;
      Vt[(vd4 * 4 + 2) * 136 + j] = vv.z;
      Vt[(vd4 * 4 + 3) * 136 + j] = vv.w;
    }
    // write this half's P from retained regs (lanes owning these keys)
    if ((lane >> 5) == jp) {
      int kl = (lane & 31) * 4;          // local key base within half
#pragma unroll
      for (int j = 0; j < 4; ++j) {
        uint2 oA = { atp[j][0], atp[j][1] };
        uint2 oB = { atp[4 + j][0], atp[4 + j][1] };
        *reinterpret_cast<uint2*>(&P_half[(wave * 4 + j) * 136 + kl]) = oA;
        *reinterpret_cast<uint2*>(&P_half[(32 + wave * 4 + j) * 136 + kl]) = oB;
      }
    }
    __syncthreads();
    __builtin_amdgcn_s_setprio(1);
#pragma unroll
    for (int ks = 0; ks < 4; ++ks) {
      bf16x8 a  = *reinterpret_cast<const bf16x8*>(&P_half[(rf * 16 + frow) * 136 + ks * 32 + fk]);
      bf16x8 b0 = *reinterpret_cast<const bf16x8*>(&Vt[(cf0 * 16 + frow) * 136 + ks * 32 + fk]);
      bf16x8 b1 = *reinterpret_cast<const bf16x8*>(&Vt[((cf0 + 1) * 16 + frow) * 136 + ks * 32 + fk]);
      oacc0 = __builtin_amdgcn_mfma_f32_16x16x32_bf16(a, b0, oacc0, 0, 0, 0);
      oacc1 = __builtin_amdgcn_mfma_f32_16x16x32_bf16(a, b1, oacc1, 0, 0, 0);
    }
    __builtin_amdgcn_s_setprio(0);
    __syncthreads();
  }

  u16* obase = outp + ((size_t)b * n_l + (size_t)g * GS + p * 64 + rf * 16) * DIMC + h * DV;
#pragma unroll
  for (int rr = 0; rr < 4; ++rr) {
    int qrow = (lane >> 4) * 4 + rr;
    obase[(size_t)qrow * DIMC + cf0 * 16 + frow]       = f2b(oacc0[rr]);
    obase[(size_t)qrow * DIMC + (cf0 + 1) * 16 + frow] = f2b(oacc1[rr]);
  }
}

// ---------------------------------------------------------------------------
extern "C" void kernel_launch(void* const* d_in, const int* in_sizes, int n_in,
                              void* d_out, int out_size, void* d_ws, size_t ws_size,
                              hipStream_t stream) {
  (void)in_sizes; (void)n_in; (void)out_size; (void)ws_size;
  const float* x        = (const float*)d_in[0];
  const int*   labels   = (const int*)d_in[1];
  const float* scores   = (const float*)d_in[2];
  const int*   idx_last = (const int*)d_in[3];
  const float* Wq       = (const float*)d_in[4];
  const float* Wk       = (const float*)d_in[5];
  const float* Wv       = (const float*)d_in[6];
  const float* Wp       = (const float*)d_in[7];
  const float* betaL    = (const float*)d_in[8];
  float* out = (float*)d_out;

  char* w = (char*)d_ws;
  size_t off = 0;
  auto take = [&](size_t bytes) -> char* {
    char* p = w + off;
    off += (bytes + 255) & ~(size_t)255;
    return p;
  };
  u16*   qhib   = (u16*)  take(16777216);   // q hi bf16 (16384 rows x 512)
  u16*   qlob   = (u16*)  take(16777216);   // q lo
  u16*   khib   = (u16*)  take(16777216);   // k hi
  u16*   klob   = (u16*)  take(16777216);   // k lo
  u16*   vbf    = (u16*)  take(16777216);   // v bf16
  u16*   xhi    = (u16*)  take(16777216);   // A hi / attn-out (disjoint lifetimes)
  u16*   xlo    = (u16*)  take(16777216);   // A lo
  u16*   attnA  = (u16*)  take(16777216);   // lvl0 attn bf16
  u16*   attnB  = (u16*)  take(33554432);   // lvl1 attn bf16
  u16*   whiAll = (u16*)  take(6291456);    // 12 x [512][512] bf16 hi
  u16*   wloAll = (u16*)  take(3145728);    // 6  x [512][512] bf16 lo (q,k)
  float* sl     = (float*)take(65536);      // pooled scores lvl0 [0,4096) lvl1 [4096,12288)
  int*   ll     = (int*)  take(65536);      // pooled labels, same offsets
  int*   keepb  = (int*)  take(1024);       // keep: lvl0 @0, lvl1 @32, lvl2 @96
  // total ~178 MB

  const size_t ROW1 = 4096;                 // lvl1 row offset in shared buffers

  wprep_kernel<<<3072, 256, 0, stream>>>(Wq, Wk, Wv, Wp, whiAll, wloAll);
  pool_split01_kernel<<<6144, 256, 0, stream>>>(x, scores, xhi, xlo, sl);
  pool_label01_kernel<<<48, 256, 0, stream>>>(labels, scores, ll);
  keep_all_kernel<<<2, 128, 0, stream>>>(ll, sl, labels, scores, keepb);

  {
    dim3 gq(12, 96);
    qkv_gemm_kernel<<<gq, 256, 0, stream>>>(xhi, xlo, whiAll, wloAll,
                                            qhib, qlob, khib, klob, vbf,
                                            0, 1, 32, (int)ROW1);
  }

  // ---- level 0 ----
  attn_fused_kernel<<<2 * 16 * 8 * 2, 512, 0, stream>>>(
      qhib, qlob, khib, klob, vbf, keepb, nullptr, attnA,
      betaL, xhi, 0, 2048, 16, 8);
  {
    dim3 gp(4, 32);
    wp_gemm_kernel<2><<<gp, 256, 0, stream>>>(xhi, whiAll + (size_t)9 * WSZ,
                                              out, idx_last, 4096, 4, 2048);
  }

  // ---- level 1 (buffers at row offset 4096) ----
  attn_fused_kernel<<<2 * 32 * 8 * 2, 512, 0, stream>>>(
      qhib + ROW1 * DIMC, qlob + ROW1 * DIMC, khib + ROW1 * DIMC, klob + ROW1 * DIMC,
      vbf + ROW1 * DIMC, keepb + 32, attnA, attnB,
      betaL, xhi + ROW1 * DIMC, 1, 4096, 32, 16);
  {
    dim3 gp(4, 64);
    wp_gemm_kernel<3><<<gp, 256, 0, stream>>>(xhi + ROW1 * DIMC, whiAll + (size_t)10 * WSZ,
                                              out, idx_last, 8192, 2, 4096);
  }

  // ---- level 2 (reuses all buffers from row 0) ----
  asplit_kernel<<<(2 * NTOK * 128) / 256, 256, 0, stream>>>(x, xhi, xlo);
  {
    dim3 gq(12, 128);
    qkv_gemm_kernel<<<gq, 256, 0, stream>>>(xhi, xlo, whiAll, wloAll,
                                            qhib, qlob, khib, klob, vbf,
                                            2, 2, 1 << 20, 0);
  }
  attn_fused_kernel<<<2 * 64 * 8 * 2, 512, 0, stream>>>(
      qhib, qlob, khib, klob, vbf, keepb + 96, attnB, nullptr,
      betaL, xhi, 2, 8192, 64, 32);
  {
    dim3 gp(4, 128);
    wp_gemm_kernel<3><<<gp, 256, 0, stream>>>(xhi, whiAll + (size_t)11 * WSZ,
                                              out, idx_last, 16384, 1, 8192);
  }
}

// Round 17
// 444.656 us; speedup vs baseline: 1.2832x; 1.1220x over previous
//
#include <hip/hip_runtime.h>
#include <math.h>

// ---------------------------------------------------------------------------
// LowToHighMultiLevelReconstruction — round 17.
// Changes vs round 16:
//  1. The three Wp GEMMs merged into ONE wp_merged launch: each block owns
//     lvl2 rows [ry*128,+128) and also computes the lvl1 (64-row) and lvl0
//     (32-row) contributions feeding the same output rows (dst=idx[i] gets
//     lvl2 row i + lvl1 row i/2 + lvl0 row i/4). lvl1/lvl0 partials round-
//     trip via LDS f32; out written ONCE (pure stores, no RMW, no atomics).
//  2. Buffer re-plumbing so lvl0/1 attn outputs survive: asplit -> attnA
//     (dead after attn1) + new x2lo (ws 178->194MB); attn2 out -> attnA.
//  Attn / qkv kernels identical to round 16 (swizzle + round-14 ballot).
// ---------------------------------------------------------------------------

#define GS   128
#define WIN  256        // 2*GS
#define DQK  64
#define DV   64
#define DIMC 512
#define NTOK 8192
#define WSZ  262144     // 512*512 elements per weight matrix

typedef unsigned long long u64;
typedef unsigned short u16;
typedef __attribute__((ext_vector_type(8))) short bf16x8;
typedef __attribute__((ext_vector_type(4))) float f32x4;

__device__ __forceinline__ u16 f2b(float f) {     // f32 -> bf16 RNE
  unsigned u = __float_as_uint(f);
  u = (u + 0x7fffu + ((u >> 16) & 1u)) >> 16;
  return (u16)u;
}
__device__ __forceinline__ float b2f(u16 h) { return __uint_as_float(((unsigned)h) << 16); }
__device__ __forceinline__ float b2f_lo(unsigned u) { return __uint_as_float(u << 16); }
__device__ __forceinline__ float b2f_hi(unsigned u) { return __uint_as_float(u & 0xffff0000u); }

__device__ __forceinline__ float wave_max64(float v) {
#pragma unroll
  for (int m = 1; m < 64; m <<= 1) v = fmaxf(v, __shfl_xor(v, m, 64));
  return v;
}
__device__ __forceinline__ float wave_sum64(float v) {
#pragma unroll
  for (int m = 1; m < 64; m <<= 1) v += __shfl_xor(v, m, 64);
  return v;
}

// ------------------------------ pooling lvl0+lvl1 (writes split bf16) -------
__global__ void pool_split01_kernel(const float* __restrict__ x,
                                    const float* __restrict__ scores,
                                    u16* __restrict__ xhi, u16* __restrict__ xlo,
                                    float* __restrict__ sl) {
  int tid = blockIdx.x * 256 + threadIdx.x;     // 0..1572863
  int scale, npool, rowoff, rest;
  if (tid < 524288) { scale = 4; npool = 2048; rowoff = 0;    rest = tid >> 7; }
  else { tid -= 524288; scale = 2; npool = 4096; rowoff = 4096; rest = tid >> 7; }
  int c4 = tid & 127;
  int g  = rest % npool;
  int b  = rest / npool;
  const float* xp = x + ((size_t)b * NTOK + (size_t)g * scale) * DIMC + c4 * 4;
  float ax = 0.f, ay = 0.f, az = 0.f, aw = 0.f, wsum = 0.f, ssum = 0.f;
  for (int s = 0; s < scale; ++s) {
    float sc = scores[(size_t)b * NTOK + (size_t)g * scale + s];
    float w  = fmaxf(sc, 1e-6f);
    float4 xv = *reinterpret_cast<const float4*>(xp + (size_t)s * DIMC);
    ax += xv.x * w; ay += xv.y * w; az += xv.z * w; aw += xv.w * w;
    wsum += w; ssum += sc;
  }
  float o[4] = { ax / wsum, ay / wsum, az / wsum, aw / wsum };
  ushort4 h, l;
  h.x = f2b(o[0]); h.y = f2b(o[1]); h.z = f2b(o[2]); h.w = f2b(o[3]);
  l.x = f2b(o[0] - b2f(h.x)); l.y = f2b(o[1] - b2f(h.y));
  l.z = f2b(o[2] - b2f(h.z)); l.w = f2b(o[3] - b2f(h.w));
  size_t row = (size_t)rowoff + (size_t)b * npool + g;
  size_t off = row * DIMC + c4 * 4;
  *reinterpret_cast<ushort4*>(xhi + off) = h;
  *reinterpret_cast<ushort4*>(xlo + off) = l;
  if (c4 == 0) sl[row] = ssum / (float)scale;
}

__global__ void pool_label01_kernel(const int* __restrict__ labels,
                                    const float* __restrict__ scores,
                                    int* __restrict__ ll) {
  int tid = blockIdx.x * 256 + threadIdx.x;     // 0..12287
  int scale, npool, rowoff;
  if (tid < 4096) { scale = 4; npool = 2048; rowoff = 0; }
  else { tid -= 4096; scale = 2; npool = 4096; rowoff = 4096; }
  int b = tid / npool, g = tid % npool;
  float counts[4] = {0.f, 0.f, 0.f, 0.f};
  float ssum[4]   = {0.f, 0.f, 0.f, 0.f};
  int firstp[4];
  for (int c = 0; c < 4; ++c) firstp[c] = scale;
  for (int s = 0; s < scale; ++s) {
    int   L = labels[(size_t)b * NTOK + (size_t)g * scale + s];
    float S = scores[(size_t)b * NTOK + (size_t)g * scale + s];
    counts[L] += 1.0f;
    ssum[L]   += S;
    if (s < firstp[L]) firstp[L] = s;
  }
  float cmax = fmaxf(fmaxf(counts[0], counts[1]), fmaxf(counts[2], counts[3]));
  float s2[4];
  for (int c = 0; c < 4; ++c) s2[c] = (counts[c] == cmax) ? ssum[c] : -1e9f;
  float smax = fmaxf(fmaxf(s2[0], s2[1]), fmaxf(s2[2], s2[3]));
  int fp[4];
  for (int c = 0; c < 4; ++c) fp[c] = (s2[c] == smax) ? firstp[c] : scale;
  int best = 0, bv = fp[0];
  for (int c = 1; c < 4; ++c) if (fp[c] < bv) { bv = fp[c]; best = c; }
  ll[rowoff + b * npool + g] = best;
}

// --------------------------------------------------- raw x split (lvl 2) ----
__global__ void asplit_kernel(const float* __restrict__ x,
                              u16* __restrict__ xhi, u16* __restrict__ xlo) {
  int tid = blockIdx.x * 256 + threadIdx.x;     // over 2*NTOK*128 float4s
  float4 v = *reinterpret_cast<const float4*>(x + (size_t)tid * 4);
  ushort4 h, l;
  h.x = f2b(v.x); h.y = f2b(v.y); h.z = f2b(v.z); h.w = f2b(v.w);
  l.x = f2b(v.x - b2f(h.x)); l.y = f2b(v.y - b2f(h.y));
  l.z = f2b(v.z - b2f(h.z)); l.w = f2b(v.w - b2f(h.w));
  *reinterpret_cast<ushort4*>(xhi + (size_t)tid * 4) = h;
  *reinterpret_cast<ushort4*>(xlo + (size_t)tid * 4) = l;
}

// -------------------------- keep for ALL levels in one launch ---------------
__global__ void keep_all_kernel(const int* __restrict__ ll, const float* __restrict__ sl,
                                const int* __restrict__ labels,
                                const float* __restrict__ scores,
                                int* __restrict__ keep) {
  int tid = blockIdx.x * 128 + threadIdx.x;
  if (tid >= 224) return;
  const int* lp; const float* sp;
  if (tid < 32) {
    int b = tid >> 4, g = tid & 15;
    lp = ll + (b * 2048 + g * GS);
    sp = sl + (b * 2048 + g * GS);
  } else if (tid < 96) {
    int e = tid - 32;
    int b = e >> 5, g = e & 31;
    lp = ll + 4096 + (b * 4096 + g * GS);
    sp = sl + 4096 + (b * 4096 + g * GS);
  } else {
    int e = tid - 96;
    int b = e >> 6, g = e & 63;
    lp = labels + ((size_t)b * NTOK + g * GS);
    sp = scores + ((size_t)b * NTOK + g * GS);
  }
  float counts[4] = {0.f, 0.f, 0.f, 0.f};
  for (int i = 0; i < GS; ++i) counts[lp[i]] += 1.f;
  int mode = 0; float bv = counts[0];
  for (int c = 1; c < 4; ++c) if (counts[c] > bv) { bv = counts[c]; mode = c; }
  float pm = 0.f, mean = 0.f;
  for (int i = 0; i < GS; ++i) { pm += (lp[i] == mode) ? 1.f : 0.f; mean += sp[i]; }
  float purity = pm / (float)GS;
  mean /= (float)GS;
  float var = 0.f;
  for (int i = 0; i < GS; ++i) { float d = sp[i] - mean; var += d * d; }
  var /= (float)GS;
  float focus = 0.5f + 0.25f * purity - 0.25f * var;
  focus = fminf(fmaxf(focus, 0.25f), 0.75f);
  keep[tid] = (int)ceilf(focus * (float)WIN);
}

// --------------------- ALL weight transpose+split in one launch (12 mats) ---
__global__ __launch_bounds__(256) void wprep_kernel(
    const float* __restrict__ Wq, const float* __restrict__ Wk,
    const float* __restrict__ Wv, const float* __restrict__ Wp,
    u16* __restrict__ whiAll, u16* __restrict__ wloAll) {
  __shared__ float tile[32][33];
  int blk = blockIdx.x;            // 0..3071
  int mat = blk >> 8;              // 0..11
  int sub = blk & 255;
  int kind = mat / 3, lvl = mat % 3;
  const float* W = (kind == 0 ? Wq : kind == 1 ? Wk : kind == 2 ? Wv : Wp)
                   + (size_t)lvl * WSZ;
  u16* bthi = whiAll + (size_t)mat * WSZ;
  u16* btlo = (mat < 6) ? (wloAll + (size_t)mat * WSZ) : nullptr;

  int bx = sub & 15;               // n block
  int by = sub >> 4;               // k block
  int tx = threadIdx.x & 31;
  int ty = threadIdx.x >> 5;       // 0..7
#pragma unroll
  for (int i = 0; i < 4; ++i) {
    int kk = ty + i * 8;
    tile[kk][tx] = W[(size_t)(by * 32 + kk) * 512 + bx * 32 + tx];
  }
  __syncthreads();
#pragma unroll
  for (int i = 0; i < 4; ++i) {
    int nn = ty + i * 8;
    float v = tile[tx][nn];        // = W[by*32+tx][bx*32+nn]
    u16 h = f2b(v);
    size_t o = (size_t)(bx * 32 + nn) * 512 + by * 32 + tx;
    bthi[o] = h;
    if (btlo) btlo[o] = f2b(v - b2f(h));
  }
}

// ---------------------------------------------------- fused q/k/v GEMM ------
// Logical work decoded from XCD-chunk-swizzled linear block id.
__global__ __launch_bounds__(256) void qkv_gemm_kernel(
    const u16* __restrict__ Ahi, const u16* __restrict__ Alo,
    const u16* __restrict__ whiAll, const u16* __restrict__ wloAll,
    u16* __restrict__ qhi, u16* __restrict__ qlo,
    u16* __restrict__ khi, u16* __restrict__ klo, u16* __restrict__ vbf,
    int lvlA, int lvlB, int ysplit, int rowB) {
  __shared__ u16 smem[4 * 4096];
  u16* sAhi = smem;
  u16* sBhi = smem + 4096;
  u16* sAlo = smem + 2 * 4096;
  u16* sBlo = smem + 3 * 4096;

  // XCD chunked swizzle (n % 8 == 0): hw block lin -> logical swz
  int lin = blockIdx.y * 12 + blockIdx.x;
  int n = gridDim.y * 12;
  int swz = (lin & 7) * (n >> 3) + (lin >> 3);
  int xx = swz % 12;
  int ry = swz / 12;
  int sel = xx >> 2;               // 0=q, 1=k, 2=v
  int cx  = xx & 3;
  bool split = (sel < 2);
  int lvl   = (ry < ysplit) ? lvlA : lvlB;
  int row0  = (ry < ysplit) ? ry * 128 : rowB + (ry - ysplit) * 128;
  const u16* Bh = whiAll + (size_t)(sel * 3 + lvl) * WSZ;
  const u16* Bl = wloAll + (size_t)(sel * 3 + lvl) * WSZ;   // valid only sel<2

  int t = threadIdx.x, lane = t & 63, wave = t >> 6;
  int wr = wave >> 1, wc = wave & 1;
  int col0 = cx * 128;

  int srow = (lane >> 2);
  int schk = (lane & 3) * 8;

  const f32x4 zero = { 0.f, 0.f, 0.f, 0.f };
  f32x4 acc[4][4];
#pragma unroll
  for (int i = 0; i < 4; ++i)
#pragma unroll
    for (int j = 0; j < 4; ++j) acc[i][j] = zero;

  for (int k0 = 0; k0 < 512; k0 += 32) {
#pragma unroll
    for (int j = 0; j < 2; ++j) {
      int r = wave * 32 + j * 16 + srow;
      const u16* gA = Ahi + (size_t)(row0 + r) * 512 + k0 + schk;
      const u16* gB = Bh + (size_t)(col0 + r) * 512 + k0 + schk;
      __builtin_amdgcn_global_load_lds(
          (const __attribute__((address_space(1))) void*)gA,
          (__attribute__((address_space(3))) void*)&sAhi[(wave * 32 + j * 16) * 32],
          16, 0, 0);
      __builtin_amdgcn_global_load_lds(
          (const __attribute__((address_space(1))) void*)gB,
          (__attribute__((address_space(3))) void*)&sBhi[(wave * 32 + j * 16) * 32],
          16, 0, 0);
      if (split) {
        const u16* gAl = Alo + (size_t)(row0 + r) * 512 + k0 + schk;
        const u16* gBl = Bl + (size_t)(col0 + r) * 512 + k0 + schk;
        __builtin_amdgcn_global_load_lds(
            (const __attribute__((address_space(1))) void*)gAl,
            (__attribute__((address_space(3))) void*)&sAlo[(wave * 32 + j * 16) * 32],
            16, 0, 0);
        __builtin_amdgcn_global_load_lds(
            (const __attribute__((address_space(1))) void*)gBl,
            (__attribute__((address_space(3))) void*)&sBlo[(wave * 32 + j * 16) * 32],
            16, 0, 0);
      }
    }
    __syncthreads();

    int fr = lane & 15;
    int kf = (lane >> 4) * 8;
    bf16x8 ah[4], bh[4], al[4], bl[4];
#pragma unroll
    for (int i = 0; i < 4; ++i) {
      ah[i] = *reinterpret_cast<const bf16x8*>(&sAhi[(wr * 64 + i * 16 + fr) * 32 + kf]);
      bh[i] = *reinterpret_cast<const bf16x8*>(&sBhi[(wc * 64 + i * 16 + fr) * 32 + kf]);
      if (split) {
        al[i] = *reinterpret_cast<const bf16x8*>(&sAlo[(wr * 64 + i * 16 + fr) * 32 + kf]);
        bl[i] = *reinterpret_cast<const bf16x8*>(&sBlo[(wc * 64 + i * 16 + fr) * 32 + kf]);
      }
    }
#pragma unroll
    for (int i = 0; i < 4; ++i)
#pragma unroll
      for (int j = 0; j < 4; ++j) {
        acc[i][j] = __builtin_amdgcn_mfma_f32_16x16x32_bf16(ah[i], bh[j], acc[i][j], 0, 0, 0);
        if (split) {
          acc[i][j] = __builtin_amdgcn_mfma_f32_16x16x32_bf16(ah[i], bl[j], acc[i][j], 0, 0, 0);
          acc[i][j] = __builtin_amdgcn_mfma_f32_16x16x32_bf16(al[i], bh[j], acc[i][j], 0, 0, 0);
        }
      }
    __syncthreads();
  }

  int ccol = col0 + wc * 64 + (lane & 15);
  int crow = row0 + wr * 64 + (lane >> 4) * 4;
  if (sel == 2) {
#pragma unroll
    for (int i = 0; i < 4; ++i)
#pragma unroll
      for (int r = 0; r < 4; ++r) {
        int gr = crow + i * 16 + r;
#pragma unroll
        for (int j = 0; j < 4; ++j)
          vbf[(size_t)gr * 512 + ccol + j * 16] = f2b(acc[i][j][r]);
      }
  } else {
    u16* Ch = (sel == 0) ? qhi : khi;
    u16* Cl = (sel == 0) ? qlo : klo;
#pragma unroll
    for (int i = 0; i < 4; ++i)
#pragma unroll
      for (int r = 0; r < 4; ++r) {
        int gr = crow + i * 16 + r;
#pragma unroll
        for (int j = 0; j < 4; ++j) {
          float v = acc[i][j][r];
          u16 hh = f2b(v);
          Ch[(size_t)gr * 512 + ccol + j * 16] = hh;
          Cl[(size_t)gr * 512 + ccol + j * 16] = f2b(v - b2f(hh));
        }
      }
  }
}

// --------------------------- merged Wp GEMM (all 3 levels, gather-sum) ------
// grid (4,128), 256 thr. Block owns lvl2 rows [ry*128,+128) and computes the
// lvl1/lvl0 contributions feeding the same outputs. out written once (no RMW).
__global__ __launch_bounds__(256) void wp_merged_kernel(
    const u16* __restrict__ xOut01, const u16* __restrict__ xOut2,
    const u16* __restrict__ whiAll, float* __restrict__ out,
    const int* __restrict__ idx) {
  __shared__ u64 smem8[6144];            // 49152 B
  u16* sA2 = (u16*)smem8;                // [128][32] @0
  u16* sA1 = sA2 + 4096;                 // [64][32]  @8192B
  u16* sA0 = sA1 + 2048;                 // [32][32]  @12288B
  u16* sB2 = sA0 + 1024;                 // [128][32] @14336B
  u16* sB1 = sB2 + 4096;                 // [128][32] @22528B
  u16* sB0 = sB1 + 4096;                 // [128][32] @30720B (..38912B)
  float* acc1f = (float*)smem8;          // [64][128] @0..32768 (epilogue)
  float* acc0f = (float*)smem8 + 8192;   // [32][128] @32768..49152

  // XCD chunked swizzle over n = 512 blocks
  int lin = blockIdx.y * 4 + blockIdx.x;
  int swz = (lin & 7) * 64 + (lin >> 3);
  int ry = swz >> 2, cx = swz & 3;
  int col0 = cx * 128;
  int i0  = ry * 128;                    // lvl2 source row base
  int bb  = i0 >> 13;                    // batch (8192 rows each)
  int il0 = i0 & 8191;
  const u16* A2 = xOut2 + (size_t)i0 * 512;
  const u16* A1 = xOut01 + (size_t)(4096 + bb * 4096 + (il0 >> 1)) * 512;
  const u16* A0 = xOut01 + (size_t)(bb * 2048 + (il0 >> 2)) * 512;
  const u16* B2 = whiAll + (size_t)11 * WSZ;
  const u16* B1 = whiAll + (size_t)10 * WSZ;
  const u16* B0 = whiAll + (size_t)9  * WSZ;

  int t = threadIdx.x, lane = t & 63, wave = t >> 6;
  int wr = wave >> 1, wc = wave & 1;
  int srow = lane >> 2, schk = (lane & 3) * 8;

  const f32x4 zero = { 0.f, 0.f, 0.f, 0.f };
  f32x4 acc2[4][4], acc1[2][4], acc0[4];
#pragma unroll
  for (int i = 0; i < 4; ++i)
#pragma unroll
    for (int j = 0; j < 4; ++j) acc2[i][j] = zero;
#pragma unroll
  for (int i = 0; i < 2; ++i)
#pragma unroll
    for (int j = 0; j < 4; ++j) acc1[i][j] = zero;
#pragma unroll
  for (int j = 0; j < 4; ++j) acc0[j] = zero;

  for (int k0 = 0; k0 < 512; k0 += 32) {
#pragma unroll
    for (int j = 0; j < 2; ++j) {
      int r = wave * 32 + j * 16 + srow;
      __builtin_amdgcn_global_load_lds(
          (const __attribute__((address_space(1))) void*)(A2 + (size_t)r * 512 + k0 + schk),
          (__attribute__((address_space(3))) void*)&sA2[(wave * 32 + j * 16) * 32], 16, 0, 0);
      __builtin_amdgcn_global_load_lds(
          (const __attribute__((address_space(1))) void*)(B2 + (size_t)(col0 + r) * 512 + k0 + schk),
          (__attribute__((address_space(3))) void*)&sB2[(wave * 32 + j * 16) * 32], 16, 0, 0);
      __builtin_amdgcn_global_load_lds(
          (const __attribute__((address_space(1))) void*)(B1 + (size_t)(col0 + r) * 512 + k0 + schk),
          (__attribute__((address_space(3))) void*)&sB1[(wave * 32 + j * 16) * 32], 16, 0, 0);
      __builtin_amdgcn_global_load_lds(
          (const __attribute__((address_space(1))) void*)(B0 + (size_t)(col0 + r) * 512 + k0 + schk),
          (__attribute__((address_space(3))) void*)&sB0[(wave * 32 + j * 16) * 32], 16, 0, 0);
    }
    {
      int r = wave * 16 + srow;
      __builtin_amdgcn_global_load_lds(
          (const __attribute__((address_space(1))) void*)(A1 + (size_t)r * 512 + k0 + schk),
          (__attribute__((address_space(3))) void*)&sA1[(wave * 16) * 32], 16, 0, 0);
    }
    if (wave < 2) {
      int r = wave * 16 + srow;
      __builtin_amdgcn_global_load_lds(
          (const __attribute__((address_space(1))) void*)(A0 + (size_t)r * 512 + k0 + schk),
          (__attribute__((address_space(3))) void*)&sA0[(wave * 16) * 32], 16, 0, 0);
    }
    __syncthreads();

    int fr = lane & 15;
    int kf = (lane >> 4) * 8;
    // lvl2: 64x64 per wave
    {
      bf16x8 a[4], b[4];
#pragma unroll
      for (int i = 0; i < 4; ++i) {
        a[i] = *reinterpret_cast<const bf16x8*>(&sA2[(wr * 64 + i * 16 + fr) * 32 + kf]);
        b[i] = *reinterpret_cast<const bf16x8*>(&sB2[(wc * 64 + i * 16 + fr) * 32 + kf]);
      }
#pragma unroll
      for (int i = 0; i < 4; ++i)
#pragma unroll
        for (int j = 0; j < 4; ++j)
          acc2[i][j] = __builtin_amdgcn_mfma_f32_16x16x32_bf16(a[i], b[j], acc2[i][j], 0, 0, 0);
    }
    // lvl1: 32x64 per wave (rows wr*32.., cols wc*64..)
    {
      bf16x8 a[2], b[4];
#pragma unroll
      for (int i = 0; i < 2; ++i)
        a[i] = *reinterpret_cast<const bf16x8*>(&sA1[(wr * 32 + i * 16 + fr) * 32 + kf]);
#pragma unroll
      for (int j = 0; j < 4; ++j)
        b[j] = *reinterpret_cast<const bf16x8*>(&sB1[(wc * 64 + j * 16 + fr) * 32 + kf]);
#pragma unroll
      for (int i = 0; i < 2; ++i)
#pragma unroll
        for (int j = 0; j < 4; ++j)
          acc1[i][j] = __builtin_amdgcn_mfma_f32_16x16x32_bf16(a[i], b[j], acc1[i][j], 0, 0, 0);
    }
    // lvl0: 16x64 per wave (rows wr*16.., cols wc*64..)
    {
      bf16x8 a = *reinterpret_cast<const bf16x8*>(&sA0[(wr * 16 + fr) * 32 + kf]);
      bf16x8 b[4];
#pragma unroll
      for (int j = 0; j < 4; ++j)
        b[j] = *reinterpret_cast<const bf16x8*>(&sB0[(wc * 64 + j * 16 + fr) * 32 + kf]);
#pragma unroll
      for (int j = 0; j < 4; ++j)
        acc0[j] = __builtin_amdgcn_mfma_f32_16x16x32_bf16(a, b[j], acc0[j], 0, 0, 0);
    }
    __syncthreads();
  }

  // ---- epilogue: lvl1/lvl0 partials to LDS f32, then gather-sum stores ----
  int rbase = (lane >> 4) * 4;
  int lcb = wc * 64 + (lane & 15);
#pragma unroll
  for (int i = 0; i < 2; ++i)
#pragma unroll
    for (int j = 0; j < 4; ++j)
#pragma unroll
      for (int rr = 0; rr < 4; ++rr)
        acc1f[(wr * 32 + i * 16 + rbase + rr) * 128 + lcb + j * 16] = acc1[i][j][rr];
#pragma unroll
  for (int j = 0; j < 4; ++j)
#pragma unroll
    for (int rr = 0; rr < 4; ++rr)
      acc0f[(wr * 16 + rbase + rr) * 128 + lcb + j * 16] = acc0[j][rr];
  __syncthreads();

#pragma unroll
  for (int i = 0; i < 4; ++i) {
#pragma unroll
    for (int rr = 0; rr < 4; ++rr) {
      int grl = wr * 64 + i * 16 + rbase + rr;     // 0..127 local lvl2 row
      int dst = idx[(size_t)bb * NTOK + (il0 + grl)];
      float* p = out + ((size_t)bb * NTOK + dst) * 512 + col0;
#pragma unroll
      for (int j = 0; j < 4; ++j) {
        int lcol = lcb + j * 16;
        p[lcol] = acc2[i][j][rr] + acc1f[(grl >> 1) * 128 + lcol]
                                 + acc0f[(grl >> 2) * 128 + lcol];
      }
    }
  }
}

// ----------------------------------------------- fused windowed attention ---
// (round-16 structure: round-14 ballot + setprio + XCD chunk swizzle)
__global__ __launch_bounds__(512) void attn_fused_kernel(
    const u16* __restrict__ qhi, const u16* __restrict__ qlo,
    const u16* __restrict__ khi, const u16* __restrict__ klo,
    const u16* __restrict__ vbf, const int* __restrict__ keepArr,
    const u16* __restrict__ prevA, u16* __restrict__ curA,
    const float* __restrict__ betaL, u16* __restrict__ outp,
    int lvl, int n_l, int ng, int prev_ng) {
  __shared__ u64 smem8[5120];             // 40960 B
  u16*   Khi_s  = (u16*)smem8;            // [256][32] @0     (phase A stage)
  u16*   Klo_s  = Khi_s + 256 * 32;       // @16384
  u16*   Qhi_s  = Klo_s + 256 * 32;       // [64][32] @32768
  u16*   Qlo_s  = Qhi_s + 64 * 32;        // @36864 (..40960)
  float* S_lds  = (float*)smem8;          // [32][264] f32 @0..33792
  u16*   P_half = (u16*)smem8;            // [64][136] @0..17408   (phase B)
  u16*   Vt     = P_half + 64 * 136;      // [64][136] @17408..34816

  int t = threadIdx.x;
  int lane = t & 63, wave = t >> 6;
  // XCD chunked swizzle (gridDim.x % 8 == 0)
  int nwg = gridDim.x;
  int bid = (blockIdx.x & 7) * (nwg >> 3) + (blockIdx.x >> 3);
  int p   = bid & 1;
  int h   = (bid >> 1) & 7;
  int gl  = bid >> 4;
  int g   = gl % ng;
  int b   = gl / ng;
  int bgh = bid >> 1;                     // (b,g,h) index for attn state

  const u16* qhbase = qhi + ((size_t)b * n_l + (size_t)g * GS + p * 64) * DIMC + h * DQK;
  const u16* qlbase = qlo + ((size_t)b * n_l + (size_t)g * GS + p * 64) * DIMC + h * DQK;
  const u16* khbase = khi + (size_t)b * n_l * DIMC + h * DQK;
  const u16* klbase = klo + (size_t)b * n_l * DIMC + h * DQK;

  // ---- phase A: sim via MFMA (3-product split), acc over 2 d-halves ----
  int qt  = wave >> 1;                    // q-tile 0..3
  int ktb = (wave & 1) * 8;               // key-tile base 0 or 8
  f32x4 acc[8];
#pragma unroll
  for (int i = 0; i < 8; ++i) acc[i] = (f32x4){0.f, 0.f, 0.f, 0.f};

#pragma unroll
  for (int dp = 0; dp < 2; ++dp) {
    if (dp) __syncthreads();              // previous half's frags consumed
    int d0 = dp * 32;
#pragma unroll
    for (int ii = 0; ii < 2; ++ii) {
      int row = wave * 32 + ii * 16 + (lane >> 2);
      int pp = g * GS + row;
      int src = (pp < n_l) ? pp : (2 * n_l - 1 - pp);
      const u16* gH = khbase + (size_t)src * DIMC + d0 + (lane & 3) * 8;
      const u16* gL = klbase + (size_t)src * DIMC + d0 + (lane & 3) * 8;
      __builtin_amdgcn_global_load_lds(
          (const __attribute__((address_space(1))) void*)gH,
          (__attribute__((address_space(3))) void*)&Khi_s[(wave * 32 + ii * 16) * 32],
          16, 0, 0);
      __builtin_amdgcn_global_load_lds(
          (const __attribute__((address_space(1))) void*)gL,
          (__attribute__((address_space(3))) void*)&Klo_s[(wave * 32 + ii * 16) * 32],
          16, 0, 0);
    }
    if (wave < 4) {
      int row = wave * 16 + (lane >> 2);
      const u16* gH = qhbase + (size_t)row * DIMC + d0 + (lane & 3) * 8;
      __builtin_amdgcn_global_load_lds(
          (const __attribute__((address_space(1))) void*)gH,
          (__attribute__((address_space(3))) void*)&Qhi_s[(wave * 16) * 32],
          16, 0, 0);
    } else {
      int row = (wave - 4) * 16 + (lane >> 2);
      const u16* gL = qlbase + (size_t)row * DIMC + d0 + (lane & 3) * 8;
      __builtin_amdgcn_global_load_lds(
          (const __attribute__((address_space(1))) void*)gL,
          (__attribute__((address_space(3))) void*)&Qlo_s[((wave - 4) * 16) * 32],
          16, 0, 0);
    }
    __syncthreads();

    int fr = lane & 15;
    int kf = (lane >> 4) * 8;
    bf16x8 bqh = *reinterpret_cast<const bf16x8*>(&Qhi_s[(qt * 16 + fr) * 32 + kf]);
    bf16x8 bql = *reinterpret_cast<const bf16x8*>(&Qlo_s[(qt * 16 + fr) * 32 + kf]);
    __builtin_amdgcn_s_setprio(1);
#pragma unroll
    for (int kt = 0; kt < 8; ++kt) {
      bf16x8 akh = *reinterpret_cast<const bf16x8*>(&Khi_s[((ktb + kt) * 16 + fr) * 32 + kf]);
      bf16x8 akl = *reinterpret_cast<const bf16x8*>(&Klo_s[((ktb + kt) * 16 + fr) * 32 + kf]);
      acc[kt] = __builtin_amdgcn_mfma_f32_16x16x32_bf16(akh, bqh, acc[kt], 0, 0, 0);
      acc[kt] = __builtin_amdgcn_mfma_f32_16x16x32_bf16(akh, bql, acc[kt], 0, 0, 0);
      acc[kt] = __builtin_amdgcn_mfma_f32_16x16x32_bf16(akl, bqh, acc[kt], 0, 0, 0);
    }
    __builtin_amdgcn_s_setprio(0);
  }
  __syncthreads();   // staging LDS dead; S_lds may overwrite

  int kp = keepArr[b * ng + g];
  float beta = 0.f, wgt = 0.f;
  int plo_ = 0, phi_ = 0;
  if (lvl > 0) {
    beta = 1.f / (1.f + expf(-betaL[lvl]));
    float pos = ((float)g + 0.5f) * ((float)prev_ng / (float)ng) - 0.5f;
    float fl = floorf(pos);
    plo_ = (int)fl;
    if (plo_ < 0) plo_ = 0;
    if (plo_ > prev_ng - 1) plo_ = prev_ng - 1;
    phi_ = plo_ + 1; if (phi_ > prev_ng - 1) phi_ = prev_ng - 1;
    wgt = fminf(fmaxf(pos - fl, 0.f), 1.f);
  }
  u64 lmask = (1ull << lane) - 1ull;

  // ---- S halves -> ballot top-k -> softmax -> prior; retain packed bf16 ----
  unsigned atp[8][2];
#pragma unroll
  for (int half = 0; half < 2; ++half) {
    if ((wave >> 2) == half) {
      int ql = ((wave >> 1) & 1) * 16 + (lane & 15);   // q-local within half
#pragma unroll
      for (int kt = 0; kt < 8; ++kt) {
        int key = (ktb + kt) * 16 + (lane >> 4) * 4;
        *reinterpret_cast<f32x4*>(&S_lds[ql * 264 + key]) = acc[kt];
      }
    }
    __syncthreads();
#pragma unroll
    for (int j = 0; j < 4; ++j) {
      int lrow = wave * 4 + j;            // 0..31 within half
      int i = p * 64 + half * 32 + lrow;  // row within 128-row group
      f32x4 s4 = *reinterpret_cast<const f32x4*>(&S_lds[lrow * 264 + lane * 4]);
      float sv[4];
      unsigned um[4];
#pragma unroll
      for (int e = 0; e < 4; ++e) {
        sv[e] = s4[e] * 0.125f;
        unsigned u = __float_as_uint(sv[e]);
        um[e] = (u & 0x80000000u) ? ~u : (u | 0x80000000u);
      }
      // unmasked row max == masked max (top element always kept)
      float m = wave_max64(fmaxf(fmaxf(sv[0], sv[1]), fmaxf(sv[2], sv[3])));
      unsigned T = 0u;
      for (int bit = 31; bit >= 0; --bit) {
        unsigned T2 = T | (1u << bit);
        int c = __popcll(__ballot(um[0] >= T2)) + __popcll(__ballot(um[1] >= T2))
              + __popcll(__ballot(um[2] >= T2)) + __popcll(__ballot(um[3] >= T2));
        if (c >= kp) { T = T2; if (c == kp) break; }
      }
      int c_gt = __popcll(__ballot(um[0] > T)) + __popcll(__ballot(um[1] > T))
               + __popcll(__ballot(um[2] > T)) + __popcll(__ballot(um[3] > T));
      u64 beq[4];
#pragma unroll
      for (int e = 0; e < 4; ++e) beq[e] = __ballot(um[e] == T);
      int trbase = __popcll(beq[0] & lmask) + __popcll(beq[1] & lmask)
                 + __popcll(beq[2] & lmask) + __popcll(beq[3] & lmask);
      int need = kp - c_gt;
      bool msk[4];
      int own = 0;
#pragma unroll
      for (int e = 0; e < 4; ++e) {
        bool eq = (um[e] == T);
        msk[e] = (um[e] > T) || (eq && (trbase + own) < need);
        own += eq ? 1 : 0;
      }
      float ez[4], zs = 0.f;
#pragma unroll
      for (int e = 0; e < 4; ++e) { ez[e] = msk[e] ? __expf(sv[e] - m) : 0.f; zs += ez[e]; }
      zs = wave_sum64(zs);
      float at[4];
#pragma unroll
      for (int e = 0; e < 4; ++e) at[e] = ez[e] / zs;
      if (lvl > 0) {
        size_t baseLo = ((((size_t)b * prev_ng + plo_) * 8 + h) * GS + i) * WIN + lane * 4;
        size_t baseHi = ((((size_t)b * prev_ng + phi_) * 8 + h) * GS + i) * WIN + lane * 4;
        uint2 rlo = *reinterpret_cast<const uint2*>(prevA + baseLo);
        uint2 rhi = *reinterpret_cast<const uint2*>(prevA + baseHi);
        float pl[4] = { b2f_lo(rlo.x), b2f_hi(rlo.x), b2f_lo(rlo.y), b2f_hi(rlo.y) };
        float ph[4] = { b2f_lo(rhi.x), b2f_hi(rhi.x), b2f_lo(rhi.y), b2f_hi(rhi.y) };
        // prior rows are stored normalized; skip re-normalizing reduction
#pragma unroll
        for (int e = 0; e < 4; ++e) {
          float pr = fmaxf((1.f - wgt) * pl[e] + wgt * ph[e], 0.f);
          at[e] = (1.f - beta) * at[e] + beta * pr;
        }
      }
      atp[half * 4 + j][0] = (unsigned)f2b(at[0]) | ((unsigned)f2b(at[1]) << 16);
      atp[half * 4 + j][1] = (unsigned)f2b(at[2]) | ((unsigned)f2b(at[3]) << 16);
      if (curA != nullptr) {
        uint2 o = { atp[half * 4 + j][0], atp[half * 4 + j][1] };
        *reinterpret_cast<uint2*>(curA + ((size_t)bgh * GS + i) * WIN + lane * 4) = o;
      }
    }
    __syncthreads();   // S half consumed before next half's write / P_half
  }

  // ---- PV via MFMA: O(64x64) = P(64x256) @ V(256x64), per-j-half P ----
  const u16* vbase = vbf + (size_t)b * n_l * DIMC + h * DV;
  int rf   = wave >> 1;                  // q-row frag 0..3
  int cf0  = (wave & 1) * 2;             // dv col frag base {0,2}
  int frow = lane & 15;
  int fk   = (lane >> 4) * 8;
  f32x4 oacc0 = { 0.f, 0.f, 0.f, 0.f };
  f32x4 oacc1 = { 0.f, 0.f, 0.f, 0.f };
  int jlo = t & 15, vd4 = (t >> 4) & 15, jh2 = t >> 8;

#pragma unroll
  for (int jp = 0; jp < 2; ++jp) {
    // stage Vt half (transposed V)
#pragma unroll
    for (int it = 0; it < 4; ++it) {
      int j = (jh2 * 4 + it) * 16 + jlo;           // 0..127
      int pp = g * GS + jp * 128 + j;
      int src = (pp < n_l) ? pp : (2 * n_l - 1 - pp);
      ushort4 vv = *reinterpret_cast<const ushort4*>(vbase + (size_t)src * DIMC + vd4 * 4);
      Vt[(vd4 * 4 + 0) * 136 + j] = vv.x;
      Vt[(vd4 * 4 + 1) * 136 + j] = vv.y;
      Vt[(vd4 * 4 + 2) * 136 + j] = vv.z;
      Vt[(vd4 * 4 + 3) * 136 + j] = vv.w;
    }
    // write this half's P from retained regs (lanes owning these keys)
    if ((lane >> 5) == jp) {
      int kl = (lane & 31) * 4;          // local key base within half
#pragma unroll
      for (int j = 0; j < 4; ++j) {
        uint2 oA = { atp[j][0], atp[j][1] };
        uint2 oB = { atp[4 + j][0], atp[4 + j][1] };
        *reinterpret_cast<uint2*>(&P_half[(wave * 4 + j) * 136 + kl]) = oA;
        *reinterpret_cast<uint2*>(&P_half[(32 + wave * 4 + j) * 136 + kl]) = oB;
      }
    }
    __syncthreads();
    __builtin_amdgcn_s_setprio(1);
#pragma unroll
    for (int ks = 0; ks < 4; ++ks) {
      bf16x8 a  = *reinterpret_cast<const bf16x8*>(&P_half[(rf * 16 + frow) * 136 + ks * 32 + fk]);
      bf16x8 b0 = *reinterpret_cast<const bf16x8*>(&Vt[(cf0 * 16 + frow) * 136 + ks * 32 + fk]);
      bf16x8 b1 = *reinterpret_cast<const bf16x8*>(&Vt[((cf0 + 1) * 16 + frow) * 136 + ks * 32 + fk]);
      oacc0 = __builtin_amdgcn_mfma_f32_16x16x32_bf16(a, b0, oacc0, 0, 0, 0);
      oacc1 = __builtin_amdgcn_mfma_f32_16x16x32_bf16(a, b1, oacc1, 0, 0, 0);
    }
    __builtin_amdgcn_s_setprio(0);
    __syncthreads();
  }

  u16* obase = outp + ((size_t)b * n_l + (size_t)g * GS + p * 64 + rf * 16) * DIMC + h * DV;
#pragma unroll
  for (int rr = 0; rr < 4; ++rr) {
    int qrow = (lane >> 4) * 4 + rr;
    obase[(size_t)qrow * DIMC + cf0 * 16 + frow]       = f2b(oacc0[rr]);
    obase[(size_t)qrow * DIMC + (cf0 + 1) * 16 + frow] = f2b(oacc1[rr]);
  }
}

// ---------------------------------------------------------------------------
extern "C" void kernel_launch(void* const* d_in, const int* in_sizes, int n_in,
                              void* d_out, int out_size, void* d_ws, size_t ws_size,
                              hipStream_t stream) {
  (void)in_sizes; (void)n_in; (void)out_size; (void)ws_size;
  const float* x        = (const float*)d_in[0];
  const int*   labels   = (const int*)d_in[1];
  const float* scores   = (const float*)d_in[2];
  const int*   idx_last = (const int*)d_in[3];
  const float* Wq       = (const float*)d_in[4];
  const float* Wk       = (const float*)d_in[5];
  const float* Wv       = (const float*)d_in[6];
  const float* Wp       = (const float*)d_in[7];
  const float* betaL    = (const float*)d_in[8];
  float* out = (float*)d_out;

  char* w = (char*)d_ws;
  size_t off = 0;
  auto take = [&](size_t bytes) -> char* {
    char* p = w + off;
    off += (bytes + 255) & ~(size_t)255;
    return p;
  };
  u16*   qhib   = (u16*)  take(16777216);   // q hi bf16 (16384 rows x 512)
  u16*   qlob   = (u16*)  take(16777216);   // q lo
  u16*   khib   = (u16*)  take(16777216);   // k hi
  u16*   klob   = (u16*)  take(16777216);   // k lo
  u16*   vbf    = (u16*)  take(16777216);   // v bf16
  u16*   xhi    = (u16*)  take(16777216);   // pooled x hi -> lvl0/1 attn outs
  u16*   xlo    = (u16*)  take(16777216);   // pooled x lo
  u16*   attnA  = (u16*)  take(16777216);   // lvl0 attn state / lvl2 x-hi / lvl2 attn out
  u16*   attnB  = (u16*)  take(33554432);   // lvl1 attn bf16
  u16*   x2lo   = (u16*)  take(16777216);   // lvl2 x lo
  u16*   whiAll = (u16*)  take(6291456);    // 12 x [512][512] bf16 hi
  u16*   wloAll = (u16*)  take(3145728);    // 6  x [512][512] bf16 lo (q,k)
  float* sl     = (float*)take(65536);      // pooled scores lvl0 [0,4096) lvl1 [4096,12288)
  int*   ll     = (int*)  take(65536);      // pooled labels, same offsets
  int*   keepb  = (int*)  take(1024);       // keep: lvl0 @0, lvl1 @32, lvl2 @96
  // total ~194 MB

  const size_t ROW1 = 4096;                 // lvl1 row offset in shared buffers

  wprep_kernel<<<3072, 256, 0, stream>>>(Wq, Wk, Wv, Wp, whiAll, wloAll);
  pool_split01_kernel<<<6144, 256, 0, stream>>>(x, scores, xhi, xlo, sl);
  pool_label01_kernel<<<48, 256, 0, stream>>>(labels, scores, ll);
  keep_all_kernel<<<2, 128, 0, stream>>>(ll, sl, labels, scores, keepb);

  {
    dim3 gq(12, 96);
    qkv_gemm_kernel<<<gq, 256, 0, stream>>>(xhi, xlo, whiAll, wloAll,
                                            qhib, qlob, khib, klob, vbf,
                                            0, 1, 32, (int)ROW1);
  }

  // ---- level 0: attn output -> xhi rows [0,4096) (pooled x consumed) ----
  attn_fused_kernel<<<2 * 16 * 8 * 2, 512, 0, stream>>>(
      qhib, qlob, khib, klob, vbf, keepb, nullptr, attnA,
      betaL, xhi, 0, 2048, 16, 8);

  // ---- level 1: attn output -> xhi rows [4096,12288) ----
  attn_fused_kernel<<<2 * 32 * 8 * 2, 512, 0, stream>>>(
      qhib + ROW1 * DIMC, qlob + ROW1 * DIMC, khib + ROW1 * DIMC, klob + ROW1 * DIMC,
      vbf + ROW1 * DIMC, keepb + 32, attnA, attnB,
      betaL, xhi + ROW1 * DIMC, 1, 4096, 32, 16);

  // ---- level 2: x split -> attnA(hi)/x2lo(lo) (attnA dead after attn1) ----
  asplit_kernel<<<(2 * NTOK * 128) / 256, 256, 0, stream>>>(x, attnA, x2lo);
  {
    dim3 gq(12, 128);
    qkv_gemm_kernel<<<gq, 256, 0, stream>>>(attnA, x2lo, whiAll, wloAll,
                                            qhib, qlob, khib, klob, vbf,
                                            2, 2, 1 << 20, 0);
  }
  // attn2 output -> attnA (free again after qkv2 consumed it)
  attn_fused_kernel<<<2 * 64 * 8 * 2, 512, 0, stream>>>(
      qhib, qlob, khib, klob, vbf, keepb + 96, attnB, nullptr,
      betaL, attnA, 2, 8192, 64, 32);

  // ---- merged Wp: all 3 levels, single launch, pure stores ----
  {
    dim3 gp(4, 128);
    wp_merged_kernel<<<gp, 256, 0, stream>>>(xhi, attnA, whiAll, out, idx_last);
  }
}

// Round 19
// 438.666 us; speedup vs baseline: 1.3007x; 1.0137x over previous
//
#include <hip/hip_runtime.h>
#include <math.h>

// ---------------------------------------------------------------------------
// LowToHighMultiLevelReconstruction — round 19.
// 1. REVERT round-18 f16 q/k (absmax 4.0e-3 FAIL: top-k boundary flips cost
//    ~2e-3 each — sim must stay split-bf16 exact). Back to round-17 numerics.
// 2. pool_fused: ONE x pass produces lvl0 (4-row) AND lvl1 (2-row) pooled
//    split-bf16 outputs with identical accumulation order (bit-identical);
//    halves pooling HBM reads and drops one launch.
// ---------------------------------------------------------------------------

#define GS   128
#define WIN  256        // 2*GS
#define DQK  64
#define DV   64
#define DIMC 512
#define NTOK 8192
#define WSZ  262144     // 512*512 elements per weight matrix

typedef unsigned long long u64;
typedef unsigned short u16;
typedef __attribute__((ext_vector_type(8))) short bf16x8;
typedef __attribute__((ext_vector_type(4))) float f32x4;

__device__ __forceinline__ u16 f2b(float f) {     // f32 -> bf16 RNE
  unsigned u = __float_as_uint(f);
  u = (u + 0x7fffu + ((u >> 16) & 1u)) >> 16;
  return (u16)u;
}
__device__ __forceinline__ float b2f(u16 h) { return __uint_as_float(((unsigned)h) << 16); }
__device__ __forceinline__ float b2f_lo(unsigned u) { return __uint_as_float(u << 16); }
__device__ __forceinline__ float b2f_hi(unsigned u) { return __uint_as_float(u & 0xffff0000u); }

__device__ __forceinline__ float wave_max64(float v) {
#pragma unroll
  for (int m = 1; m < 64; m <<= 1) v = fmaxf(v, __shfl_xor(v, m, 64));
  return v;
}
__device__ __forceinline__ float wave_sum64(float v) {
#pragma unroll
  for (int m = 1; m < 64; m <<= 1) v += __shfl_xor(v, m, 64);
  return v;
}

// ---------------- fused pooling: ONE x pass -> lvl0 + lvl1 split bf16 -------
// thread = (b, group-of-4 g4, c4 chunk). Reads 4 rows' float4 once; emits
// lvl0 pooled row (b*2048+g4) and lvl1 rows (4096 + b*4096 + 2*g4 + {0,1}).
// Accumulation order identical to the old per-scale loops (bit-identical).
__global__ void pool_fused_kernel(const float* __restrict__ x,
                                  const float* __restrict__ scores,
                                  u16* __restrict__ xhi, u16* __restrict__ xlo,
                                  float* __restrict__ sl) {
  int tid = blockIdx.x * 256 + threadIdx.x;     // 0..524287
  int c4 = tid & 127;
  int g4 = (tid >> 7) & 2047;
  int b  = tid >> 18;
  const float* sp = scores + (size_t)b * NTOK + (size_t)g4 * 4;
  float s0 = sp[0], s1 = sp[1], s2 = sp[2], s3 = sp[3];
  float w0 = fmaxf(s0, 1e-6f), w1 = fmaxf(s1, 1e-6f);
  float w2 = fmaxf(s2, 1e-6f), w3 = fmaxf(s3, 1e-6f);
  const float* xp = x + ((size_t)b * NTOK + (size_t)g4 * 4) * DIMC + c4 * 4;
  float4 x0 = *reinterpret_cast<const float4*>(xp);
  float4 x1 = *reinterpret_cast<const float4*>(xp + DIMC);
  float4 x2 = *reinterpret_cast<const float4*>(xp + 2 * DIMC);
  float4 x3 = *reinterpret_cast<const float4*>(xp + 3 * DIMC);

  auto emit = [&](float a0, float a1, float a2, float a3, size_t row) {
    ushort4 h, l;
    h.x = f2b(a0); h.y = f2b(a1); h.z = f2b(a2); h.w = f2b(a3);
    l.x = f2b(a0 - b2f(h.x)); l.y = f2b(a1 - b2f(h.y));
    l.z = f2b(a2 - b2f(h.z)); l.w = f2b(a3 - b2f(h.w));
    size_t off = row * DIMC + c4 * 4;
    *reinterpret_cast<ushort4*>(xhi + off) = h;
    *reinterpret_cast<ushort4*>(xlo + off) = l;
  };

  // lvl0: sequential s=0..3 accumulation (matches old scale-4 loop)
  {
    float ax = x0.x * w0 + x1.x * w1 + x2.x * w2 + x3.x * w3;
    float ay = x0.y * w0 + x1.y * w1 + x2.y * w2 + x3.y * w3;
    float az = x0.z * w0 + x1.z * w1 + x2.z * w2 + x3.z * w3;
    float aw = x0.w * w0 + x1.w * w1 + x2.w * w2 + x3.w * w3;
    float ws = w0 + w1 + w2 + w3;
    size_t row = (size_t)b * 2048 + g4;
    emit(ax / ws, ay / ws, az / ws, aw / ws, row);
    if (c4 == 0) sl[row] = (s0 + s1 + s2 + s3) / 4.0f;
  }
  // lvl1 pair 0 (rows 4*g4, 4*g4+1)  (matches old scale-2 loop order)
  {
    float ws = w0 + w1;
    size_t row = 4096 + (size_t)b * 4096 + (size_t)g4 * 2;
    emit((x0.x * w0 + x1.x * w1) / ws, (x0.y * w0 + x1.y * w1) / ws,
         (x0.z * w0 + x1.z * w1) / ws, (x0.w * w0 + x1.w * w1) / ws, row);
    if (c4 == 0) sl[row] = (s0 + s1) / 2.0f;
  }
  // lvl1 pair 1 (rows 4*g4+2, 4*g4+3)
  {
    float ws = w2 + w3;
    size_t row = 4096 + (size_t)b * 4096 + (size_t)g4 * 2 + 1;
    emit((x2.x * w2 + x3.x * w3) / ws, (x2.y * w2 + x3.y * w3) / ws,
         (x2.z * w2 + x3.z * w3) / ws, (x2.w * w2 + x3.w * w3) / ws, row);
    if (c4 == 0) sl[row] = (s2 + s3) / 2.0f;
  }
}

__global__ void pool_label01_kernel(const int* __restrict__ labels,
                                    const float* __restrict__ scores,
                                    int* __restrict__ ll) {
  int tid = blockIdx.x * 256 + threadIdx.x;     // 0..12287
  int scale, npool, rowoff;
  if (tid < 4096) { scale = 4; npool = 2048; rowoff = 0; }
  else { tid -= 4096; scale = 2; npool = 4096; rowoff = 4096; }
  int b = tid / npool, g = tid % npool;
  float counts[4] = {0.f, 0.f, 0.f, 0.f};
  float ssum[4]   = {0.f, 0.f, 0.f, 0.f};
  int firstp[4];
  for (int c = 0; c < 4; ++c) firstp[c] = scale;
  for (int s = 0; s < scale; ++s) {
    int   L = labels[(size_t)b * NTOK + (size_t)g * scale + s];
    float S = scores[(size_t)b * NTOK + (size_t)g * scale + s];
    counts[L] += 1.0f;
    ssum[L]   += S;
    if (s < firstp[L]) firstp[L] = s;
  }
  float cmax = fmaxf(fmaxf(counts[0], counts[1]), fmaxf(counts[2], counts[3]));
  float s2[4];
  for (int c = 0; c < 4; ++c) s2[c] = (counts[c] == cmax) ? ssum[c] : -1e9f;
  float smax = fmaxf(fmaxf(s2[0], s2[1]), fmaxf(s2[2], s2[3]));
  int fp[4];
  for (int c = 0; c < 4; ++c) fp[c] = (s2[c] == smax) ? firstp[c] : scale;
  int best = 0, bv = fp[0];
  for (int c = 1; c < 4; ++c) if (fp[c] < bv) { bv = fp[c]; best = c; }
  ll[rowoff + b * npool + g] = best;
}

// --------------------------------------------------- raw x split (lvl 2) ----
__global__ void asplit_kernel(const float* __restrict__ x,
                              u16* __restrict__ xhi, u16* __restrict__ xlo) {
  int tid = blockIdx.x * 256 + threadIdx.x;     // over 2*NTOK*128 float4s
  float4 v = *reinterpret_cast<const float4*>(x + (size_t)tid * 4);
  ushort4 h, l;
  h.x = f2b(v.x); h.y = f2b(v.y); h.z = f2b(v.z); h.w = f2b(v.w);
  l.x = f2b(v.x - b2f(h.x)); l.y = f2b(v.y - b2f(h.y));
  l.z = f2b(v.z - b2f(h.z)); l.w = f2b(v.w - b2f(h.w));
  *reinterpret_cast<ushort4*>(xhi + (size_t)tid * 4) = h;
  *reinterpret_cast<ushort4*>(xlo + (size_t)tid * 4) = l;
}

// -------------------------- keep for ALL levels in one launch ---------------
__global__ void keep_all_kernel(const int* __restrict__ ll, const float* __restrict__ sl,
                                const int* __restrict__ labels,
                                const float* __restrict__ scores,
                                int* __restrict__ keep) {
  int tid = blockIdx.x * 128 + threadIdx.x;
  if (tid >= 224) return;
  const int* lp; const float* sp;
  if (tid < 32) {
    int b = tid >> 4, g = tid & 15;
    lp = ll + (b * 2048 + g * GS);
    sp = sl + (b * 2048 + g * GS);
  } else if (tid < 96) {
    int e = tid - 32;
    int b = e >> 5, g = e & 31;
    lp = ll + 4096 + (b * 4096 + g * GS);
    sp = sl + 4096 + (b * 4096 + g * GS);
  } else {
    int e = tid - 96;
    int b = e >> 6, g = e & 63;
    lp = labels + ((size_t)b * NTOK + g * GS);
    sp = scores + ((size_t)b * NTOK + g * GS);
  }
  float counts[4] = {0.f, 0.f, 0.f, 0.f};
  for (int i = 0; i < GS; ++i) counts[lp[i]] += 1.f;
  int mode = 0; float bv = counts[0];
  for (int c = 1; c < 4; ++c) if (counts[c] > bv) { bv = counts[c]; mode = c; }
  float pm = 0.f, mean = 0.f;
  for (int i = 0; i < GS; ++i) { pm += (lp[i] == mode) ? 1.f : 0.f; mean += sp[i]; }
  float purity = pm / (float)GS;
  mean /= (float)GS;
  float var = 0.f;
  for (int i = 0; i < GS; ++i) { float d = sp[i] - mean; var += d * d; }
  var /= (float)GS;
  float focus = 0.5f + 0.25f * purity - 0.25f * var;
  focus = fminf(fmaxf(focus, 0.25f), 0.75f);
  keep[tid] = (int)ceilf(focus * (float)WIN);
}

// --------------------- ALL weight transpose+split in one launch (12 mats) ---
__global__ __launch_bounds__(256) void wprep_kernel(
    const float* __restrict__ Wq, const float* __restrict__ Wk,
    const float* __restrict__ Wv, const float* __restrict__ Wp,
    u16* __restrict__ whiAll, u16* __restrict__ wloAll) {
  __shared__ float tile[32][33];
  int blk = blockIdx.x;            // 0..3071
  int mat = blk >> 8;              // 0..11
  int sub = blk & 255;
  int kind = mat / 3, lvl = mat % 3;
  const float* W = (kind == 0 ? Wq : kind == 1 ? Wk : kind == 2 ? Wv : Wp)
                   + (size_t)lvl * WSZ;
  u16* bthi = whiAll + (size_t)mat * WSZ;
  u16* btlo = (mat < 6) ? (wloAll + (size_t)mat * WSZ) : nullptr;

  int bx = sub & 15;               // n block
  int by = sub >> 4;               // k block
  int tx = threadIdx.x & 31;
  int ty = threadIdx.x >> 5;       // 0..7
#pragma unroll
  for (int i = 0; i < 4; ++i) {
    int kk = ty + i * 8;
    tile[kk][tx] = W[(size_t)(by * 32 + kk) * 512 + bx * 32 + tx];
  }
  __syncthreads();
#pragma unroll
  for (int i = 0; i < 4; ++i) {
    int nn = ty + i * 8;
    float v = tile[tx][nn];        // = W[by*32+tx][bx*32+nn]
    u16 h = f2b(v);
    size_t o = (size_t)(bx * 32 + nn) * 512 + by * 32 + tx;
    bthi[o] = h;
    if (btlo) btlo[o] = f2b(v - b2f(h));
  }
}

// ---------------------------------------------------- fused q/k/v GEMM ------
__global__ __launch_bounds__(256) void qkv_gemm_kernel(
    const u16* __restrict__ Ahi, const u16* __restrict__ Alo,
    const u16* __restrict__ whiAll, const u16* __restrict__ wloAll,
    u16* __restrict__ qhi, u16* __restrict__ qlo,
    u16* __restrict__ khi, u16* __restrict__ klo, u16* __restrict__ vbf,
    int lvlA, int lvlB, int ysplit, int rowB) {
  __shared__ u16 smem[4 * 4096];
  u16* sAhi = smem;
  u16* sBhi = smem + 4096;
  u16* sAlo = smem + 2 * 4096;
  u16* sBlo = smem + 3 * 4096;

  int lin = blockIdx.y * 12 + blockIdx.x;
  int n = gridDim.y * 12;
  int swz = (lin & 7) * (n >> 3) + (lin >> 3);
  int xx = swz % 12;
  int ry = swz / 12;
  int sel = xx >> 2;               // 0=q, 1=k, 2=v
  int cx  = xx & 3;
  bool split = (sel < 2);
  int lvl   = (ry < ysplit) ? lvlA : lvlB;
  int row0  = (ry < ysplit) ? ry * 128 : rowB + (ry - ysplit) * 128;
  const u16* Bh = whiAll + (size_t)(sel * 3 + lvl) * WSZ;
  const u16* Bl = wloAll + (size_t)(sel * 3 + lvl) * WSZ;   // valid only sel<2

  int t = threadIdx.x, lane = t & 63, wave = t >> 6;
  int wr = wave >> 1, wc = wave & 1;
  int col0 = cx * 128;

  int srow = (lane >> 2);
  int schk = (lane & 3) * 8;

  const f32x4 zero = { 0.f, 0.f, 0.f, 0.f };
  f32x4 acc[4][4];
#pragma unroll
  for (int i = 0; i < 4; ++i)
#pragma unroll
    for (int j = 0; j < 4; ++j) acc[i][j] = zero;

  for (int k0 = 0; k0 < 512; k0 += 32) {
#pragma unroll
    for (int j = 0; j < 2; ++j) {
      int r = wave * 32 + j * 16 + srow;
      const u16* gA = Ahi + (size_t)(row0 + r) * 512 + k0 + schk;
      const u16* gB = Bh + (size_t)(col0 + r) * 512 + k0 + schk;
      __builtin_amdgcn_global_load_lds(
          (const __attribute__((address_space(1))) void*)gA,
          (__attribute__((address_space(3))) void*)&sAhi[(wave * 32 + j * 16) * 32],
          16, 0, 0);
      __builtin_amdgcn_global_load_lds(
          (const __attribute__((address_space(1))) void*)gB,
          (__attribute__((address_space(3))) void*)&sBhi[(wave * 32 + j * 16) * 32],
          16, 0, 0);
      if (split) {
        const u16* gAl = Alo + (size_t)(row0 + r) * 512 + k0 + schk;
        const u16* gBl = Bl + (size_t)(col0 + r) * 512 + k0 + schk;
        __builtin_amdgcn_global_load_lds(
            (const __attribute__((address_space(1))) void*)gAl,
            (__attribute__((address_space(3))) void*)&sAlo[(wave * 32 + j * 16) * 32],
            16, 0, 0);
        __builtin_amdgcn_global_load_lds(
            (const __attribute__((address_space(1))) void*)gBl,
            (__attribute__((address_space(3))) void*)&sBlo[(wave * 32 + j * 16) * 32],
            16, 0, 0);
      }
    }
    __syncthreads();

    int fr = lane & 15;
    int kf = (lane >> 4) * 8;
    bf16x8 ah[4], bh[4], al[4], bl[4];
#pragma unroll
    for (int i = 0; i < 4; ++i) {
      ah[i] = *reinterpret_cast<const bf16x8*>(&sAhi[(wr * 64 + i * 16 + fr) * 32 + kf]);
      bh[i] = *reinterpret_cast<const bf16x8*>(&sBhi[(wc * 64 + i * 16 + fr) * 32 + kf]);
      if (split) {
        al[i] = *reinterpret_cast<const bf16x8*>(&sAlo[(wr * 64 + i * 16 + fr) * 32 + kf]);
        bl[i] = *reinterpret_cast<const bf16x8*>(&sBlo[(wc * 64 + i * 16 + fr) * 32 + kf]);
      }
    }
#pragma unroll
    for (int i = 0; i < 4; ++i)
#pragma unroll
      for (int j = 0; j < 4; ++j) {
        acc[i][j] = __builtin_amdgcn_mfma_f32_16x16x32_bf16(ah[i], bh[j], acc[i][j], 0, 0, 0);
        if (split) {
          acc[i][j] = __builtin_amdgcn_mfma_f32_16x16x32_bf16(ah[i], bl[j], acc[i][j], 0, 0, 0);
          acc[i][j] = __builtin_amdgcn_mfma_f32_16x16x32_bf16(al[i], bh[j], acc[i][j], 0, 0, 0);
        }
      }
    __syncthreads();
  }

  int ccol = col0 + wc * 64 + (lane & 15);
  int crow = row0 + wr * 64 + (lane >> 4) * 4;
  if (sel == 2) {
#pragma unroll
    for (int i = 0; i < 4; ++i)
#pragma unroll
      for (int r = 0; r < 4; ++r) {
        int gr = crow + i * 16 + r;
#pragma unroll
        for (int j = 0; j < 4; ++j)
          vbf[(size_t)gr * 512 + ccol + j * 16] = f2b(acc[i][j][r]);
      }
  } else {
    u16* Ch = (sel == 0) ? qhi : khi;
    u16* Cl = (sel == 0) ? qlo : klo;
#pragma unroll
    for (int i = 0; i < 4; ++i)
#pragma unroll
      for (int r = 0; r < 4; ++r) {
        int gr = crow + i * 16 + r;
#pragma unroll
        for (int j = 0; j < 4; ++j) {
          float v = acc[i][j][r];
          u16 hh = f2b(v);
          Ch[(size_t)gr * 512 + ccol + j * 16] = hh;
          Cl[(size_t)gr * 512 + ccol + j * 16] = f2b(v - b2f(hh));
        }
      }
  }
}

// --------------------------- merged Wp GEMM (all 3 levels, gather-sum) ------
__global__ __launch_bounds__(256) void wp_merged_kernel(
    const u16* __restrict__ xOut01, const u16* __restrict__ xOut2,
    const u16* __restrict__ whiAll, float* __restrict__ out,
    const int* __restrict__ idx) {
  __shared__ u64 smem8[6144];            // 49152 B
  u16* sA2 = (u16*)smem8;                // [128][32] @0
  u16* sA1 = sA2 + 4096;                 // [64][32]  @8192B
  u16* sA0 = sA1 + 2048;                 // [32][32]  @12288B
  u16* sB2 = sA0 + 1024;                 // [128][32] @14336B
  u16* sB1 = sB2 + 4096;                 // [128][32] @22528B
  u16* sB0 = sB1 + 4096;                 // [128][32] @30720B (..38912B)
  float* acc1f = (float*)smem8;          // [64][128] @0..32768 (epilogue)
  float* acc0f = (float*)smem8 + 8192;   // [32][128] @32768..49152

  int lin = blockIdx.y * 4 + blockIdx.x;
  int swz = (lin & 7) * 64 + (lin >> 3);
  int ry = swz >> 2, cx = swz & 3;
  int col0 = cx * 128;
  int i0  = ry * 128;                    // lvl2 source row base
  int bb  = i0 >> 13;                    // batch (8192 rows each)
  int il0 = i0 & 8191;
  const u16* A2 = xOut2 + (size_t)i0 * 512;
  const u16* A1 = xOut01 + (size_t)(4096 + bb * 4096 + (il0 >> 1)) * 512;
  const u16* A0 = xOut01 + (size_t)(bb * 2048 + (il0 >> 2)) * 512;
  const u16* B2 = whiAll + (size_t)11 * WSZ;
  const u16* B1 = whiAll + (size_t)10 * WSZ;
  const u16* B0 = whiAll + (size_t)9  * WSZ;

  int t = threadIdx.x, lane = t & 63, wave = t >> 6;
  int wr = wave >> 1, wc = wave & 1;
  int srow = lane >> 2, schk = (lane & 3) * 8;

  const f32x4 zero = { 0.f, 0.f, 0.f, 0.f };
  f32x4 acc2[4][4], acc1[2][4], acc0[4];
#pragma unroll
  for (int i = 0; i < 4; ++i)
#pragma unroll
    for (int j = 0; j < 4; ++j) acc2[i][j] = zero;
#pragma unroll
  for (int i = 0; i < 2; ++i)
#pragma unroll
    for (int j = 0; j < 4; ++j) acc1[i][j] = zero;
#pragma unroll
  for (int j = 0; j < 4; ++j) acc0[j] = zero;

  for (int k0 = 0; k0 < 512; k0 += 32) {
#pragma unroll
    for (int j = 0; j < 2; ++j) {
      int r = wave * 32 + j * 16 + srow;
      __builtin_amdgcn_global_load_lds(
          (const __attribute__((address_space(1))) void*)(A2 + (size_t)r * 512 + k0 + schk),
          (__attribute__((address_space(3))) void*)&sA2[(wave * 32 + j * 16) * 32], 16, 0, 0);
      __builtin_amdgcn_global_load_lds(
          (const __attribute__((address_space(1))) void*)(B2 + (size_t)(col0 + r) * 512 + k0 + schk),
          (__attribute__((address_space(3))) void*)&sB2[(wave * 32 + j * 16) * 32], 16, 0, 0);
      __builtin_amdgcn_global_load_lds(
          (const __attribute__((address_space(1))) void*)(B1 + (size_t)(col0 + r) * 512 + k0 + schk),
          (__attribute__((address_space(3))) void*)&sB1[(wave * 32 + j * 16) * 32], 16, 0, 0);
      __builtin_amdgcn_global_load_lds(
          (const __attribute__((address_space(1))) void*)(B0 + (size_t)(col0 + r) * 512 + k0 + schk),
          (__attribute__((address_space(3))) void*)&sB0[(wave * 32 + j * 16) * 32], 16, 0, 0);
    }
    {
      int r = wave * 16 + srow;
      __builtin_amdgcn_global_load_lds(
          (const __attribute__((address_space(1))) void*)(A1 + (size_t)r * 512 + k0 + schk),
          (__attribute__((address_space(3))) void*)&sA1[(wave * 16) * 32], 16, 0, 0);
    }
    if (wave < 2) {
      int r = wave * 16 + srow;
      __builtin_amdgcn_global_load_lds(
          (const __attribute__((address_space(1))) void*)(A0 + (size_t)r * 512 + k0 + schk),
          (__attribute__((address_space(3))) void*)&sA0[(wave * 16) * 32], 16, 0, 0);
    }
    __syncthreads();

    int fr = lane & 15;
    int kfo = (lane >> 4) * 8;
    {
      bf16x8 a[4], b[4];
#pragma unroll
      for (int i = 0; i < 4; ++i) {
        a[i] = *reinterpret_cast<const bf16x8*>(&sA2[(wr * 64 + i * 16 + fr) * 32 + kfo]);
        b[i] = *reinterpret_cast<const bf16x8*>(&sB2[(wc * 64 + i * 16 + fr) * 32 + kfo]);
      }
#pragma unroll
      for (int i = 0; i < 4; ++i)
#pragma unroll
        for (int j = 0; j < 4; ++j)
          acc2[i][j] = __builtin_amdgcn_mfma_f32_16x16x32_bf16(a[i], b[j], acc2[i][j], 0, 0, 0);
    }
    {
      bf16x8 a[2], b[4];
#pragma unroll
      for (int i = 0; i < 2; ++i)
        a[i] = *reinterpret_cast<const bf16x8*>(&sA1[(wr * 32 + i * 16 + fr) * 32 + kfo]);
#pragma unroll
      for (int j = 0; j < 4; ++j)
        b[j] = *reinterpret_cast<const bf16x8*>(&sB1[(wc * 64 + j * 16 + fr) * 32 + kfo]);
#pragma unroll
      for (int i = 0; i < 2; ++i)
#pragma unroll
        for (int j = 0; j < 4; ++j)
          acc1[i][j] = __builtin_amdgcn_mfma_f32_16x16x32_bf16(a[i], b[j], acc1[i][j], 0, 0, 0);
    }
    {
      bf16x8 a = *reinterpret_cast<const bf16x8*>(&sA0[(wr * 16 + fr) * 32 + kfo]);
      bf16x8 b[4];
#pragma unroll
      for (int j = 0; j < 4; ++j)
        b[j] = *reinterpret_cast<const bf16x8*>(&sB0[(wc * 64 + j * 16 + fr) * 32 + kfo]);
#pragma unroll
      for (int j = 0; j < 4; ++j)
        acc0[j] = __builtin_amdgcn_mfma_f32_16x16x32_bf16(a, b[j], acc0[j], 0, 0, 0);
    }
    __syncthreads();
  }

  int rbase = (lane >> 4) * 4;
  int lcb = wc * 64 + (lane & 15);
#pragma unroll
  for (int i = 0; i < 2; ++i)
#pragma unroll
    for (int j = 0; j < 4; ++j)
#pragma unroll
      for (int rr = 0; rr < 4; ++rr)
        acc1f[(wr * 32 + i * 16 + rbase + rr) * 128 + lcb + j * 16] = acc1[i][j][rr];
#pragma unroll
  for (int j = 0; j < 4; ++j)
#pragma unroll
    for (int rr = 0; rr < 4; ++rr)
      acc0f[(wr * 16 + rbase + rr) * 128 + lcb + j * 16] = acc0[j][rr];
  __syncthreads();

#pragma unroll
  for (int i = 0; i < 4; ++i) {
#pragma unroll
    for (int rr = 0; rr < 4; ++rr) {
      int grl = wr * 64 + i * 16 + rbase + rr;     // 0..127 local lvl2 row
      int dst = idx[(size_t)bb * NTOK + (il0 + grl)];
      float* p = out + ((size_t)bb * NTOK + dst) * 512 + col0;
#pragma unroll
      for (int j = 0; j < 4; ++j) {
        int lcol = lcb + j * 16;
        p[lcol] = acc2[i][j][rr] + acc1f[(grl >> 1) * 128 + lcol]
                                 + acc0f[(grl >> 2) * 128 + lcol];
      }
    }
  }
}

// ----------------------------------------------- fused windowed attention ---
// (round-17 structure: split-bf16 sim, round-14 ballot + setprio + swizzle)
__global__ __launch_bounds__(512) void attn_fused_kernel(
    const u16* __restrict__ qhi, const u16* __restrict__ qlo,
    const u16* __restrict__ khi, const u16* __restrict__ klo,
    const u16* __restrict__ vbf, const int* __restrict__ keepArr,
    const u16* __restrict__ prevA, u16* __restrict__ curA,
    const float* __restrict__ betaL, u16* __restrict__ outp,
    int lvl, int n_l, int ng, int prev_ng) {
  __shared__ u64 smem8[5120];             // 40960 B
  u16*   Khi_s  = (u16*)smem8;            // [256][32] @0     (phase A stage)
  u16*   Klo_s  = Khi_s + 256 * 32;       // @16384
  u16*   Qhi_s  = Klo_s + 256 * 32;       // [64][32] @32768
  u16*   Qlo_s  = Qhi_s + 64 * 32;        // @36864 (..40960)
  float* S_lds  = (float*)smem8;          // [32][264] f32 @0..33792
  u16*   P_half = (u16*)smem8;            // [64][136] @0..17408   (phase B)
  u16*   Vt     = P_half + 64 * 136;      // [64][136] @17408..34816

  int t = threadIdx.x;
  int lane = t & 63, wave = t >> 6;
  int nwg = gridDim.x;
  int bid = (blockIdx.x & 7) * (nwg >> 3) + (blockIdx.x >> 3);
  int p   = bid & 1;
  int h   = (bid >> 1) & 7;
  int gl  = bid >> 4;
  int g   = gl % ng;
  int b   = gl / ng;
  int bgh = bid >> 1;                     // (b,g,h) index for attn state

  const u16* qhbase = qhi + ((size_t)b * n_l + (size_t)g * GS + p * 64) * DIMC + h * DQK;
  const u16* qlbase = qlo + ((size_t)b * n_l + (size_t)g * GS + p * 64) * DIMC + h * DQK;
  const u16* khbase = khi + (size_t)b * n_l * DIMC + h * DQK;
  const u16* klbase = klo + (size_t)b * n_l * DIMC + h * DQK;

  // ---- phase A: sim via MFMA (3-product split), acc over 2 d-halves ----
  int qt  = wave >> 1;                    // q-tile 0..3
  int ktb = (wave & 1) * 8;               // key-tile base 0 or 8
  f32x4 acc[8];
#pragma unroll
  for (int i = 0; i < 8; ++i) acc[i] = (f32x4){0.f, 0.f, 0.f, 0.f};

#pragma unroll
  for (int dp = 0; dp < 2; ++dp) {
    if (dp) __syncthreads();              // previous half's frags consumed
    int d0 = dp * 32;
#pragma unroll
    for (int ii = 0; ii < 2; ++ii) {
      int row = wave * 32 + ii * 16 + (lane >> 2);
      int pp = g * GS + row;
      int src = (pp < n_l) ? pp : (2 * n_l - 1 - pp);
      const u16* gH = khbase + (size_t)src * DIMC + d0 + (lane & 3) * 8;
      const u16* gL = klbase + (size_t)src * DIMC + d0 + (lane & 3) * 8;
      __builtin_amdgcn_global_load_lds(
          (const __attribute__((address_space(1))) void*)gH,
          (__attribute__((address_space(3))) void*)&Khi_s[(wave * 32 + ii * 16) * 32],
          16, 0, 0);
      __builtin_amdgcn_global_load_lds(
          (const __attribute__((address_space(1))) void*)gL,
          (__attribute__((address_space(3))) void*)&Klo_s[(wave * 32 + ii * 16) * 32],
          16, 0, 0);
    }
    if (wave < 4) {
      int row = wave * 16 + (lane >> 2);
      const u16* gH = qhbase + (size_t)row * DIMC + d0 + (lane & 3) * 8;
      __builtin_amdgcn_global_load_lds(
          (const __attribute__((address_space(1))) void*)gH,
          (__attribute__((address_space(3))) void*)&Qhi_s[(wave * 16) * 32],
          16, 0, 0);
    } else {
      int row = (wave - 4) * 16 + (lane >> 2);
      const u16* gL = qlbase + (size_t)row * DIMC + d0 + (lane & 3) * 8;
      __builtin_amdgcn_global_load_lds(
          (const __attribute__((address_space(1))) void*)gL,
          (__attribute__((address_space(3))) void*)&Qlo_s[((wave - 4) * 16) * 32],
          16, 0, 0);
    }
    __syncthreads();

    int fr = lane & 15;
    int kf = (lane >> 4) * 8;
    bf16x8 bqh = *reinterpret_cast<const bf16x8*>(&Qhi_s[(qt * 16 + fr) * 32 + kf]);
    bf16x8 bql = *reinterpret_cast<const bf16x8*>(&Qlo_s[(qt * 16 + fr) * 32 + kf]);
    __builtin_amdgcn_s_setprio(1);
#pragma unroll
    for (int kt = 0; kt < 8; ++kt) {
      bf16x8 akh = *reinterpret_cast<const bf16x8*>(&Khi_s[((ktb + kt) * 16 + fr) * 32 + kf]);
      bf16x8 akl = *reinterpret_cast<const bf16x8*>(&Klo_s[((ktb + kt) * 16 + fr) * 32 + kf]);
      acc[kt] = __builtin_amdgcn_mfma_f32_16x16x32_bf16(akh, bqh, acc[kt], 0, 0, 0);
      acc[kt] = __builtin_amdgcn_mfma_f32_16x16x32_bf16(akh, bql, acc[kt], 0, 0, 0);
      acc[kt] = __builtin_amdgcn_mfma_f32_16x16x32_bf16(akl, bqh, acc[kt], 0, 0, 0);
    }
    __builtin_amdgcn_s_setprio(0);
  }
  __syncthreads();   // staging LDS dead; S_lds may overwrite

  int kp = keepArr[b * ng + g];
  float beta = 0.f, wgt = 0.f;
  int plo_ = 0, phi_ = 0;
  if (lvl > 0) {
    beta = 1.f / (1.f + expf(-betaL[lvl]));
    float pos = ((float)g + 0.5f) * ((float)prev_ng / (float)ng) - 0.5f;
    float fl = floorf(pos);
    plo_ = (int)fl;
    if (plo_ < 0) plo_ = 0;
    if (plo_ > prev_ng - 1) plo_ = prev_ng - 1;
    phi_ = plo_ + 1; if (phi_ > prev_ng - 1) phi_ = prev_ng - 1;
    wgt = fminf(fmaxf(pos - fl, 0.f), 1.f);
  }
  u64 lmask = (1ull << lane) - 1ull;

  // ---- S halves -> ballot top-k -> softmax -> prior; retain packed bf16 ----
  unsigned atp[8][2];
#pragma unroll
  for (int half = 0; half < 2; ++half) {
    if ((wave >> 2) == half) {
      int ql = ((wave >> 1) & 1) * 16 + (lane & 15);   // q-local within half
#pragma unroll
      for (int kt = 0; kt < 8; ++kt) {
        int key = (ktb + kt) * 16 + (lane >> 4) * 4;
        *reinterpret_cast<f32x4*>(&S_lds[ql * 264 + key]) = acc[kt];
      }
    }
    __syncthreads();
#pragma unroll
    for (int j = 0; j < 4; ++j) {
      int lrow = wave * 4 + j;            // 0..31 within half
      int i = p * 64 + half * 32 + lrow;  // row within 128-row group
      f32x4 s4 = *reinterpret_cast<const f32x4*>(&S_lds[lrow * 264 + lane * 4]);
      float sv[4];
      unsigned um[4];
#pragma unroll
      for (int e = 0; e < 4; ++e) {
        sv[e] = s4[e] * 0.125f;
        unsigned u = __float_as_uint(sv[e]);
        um[e] = (u & 0x80000000u) ? ~u : (u | 0x80000000u);
      }
      // unmasked row max == masked max (top element always kept)
      float m = wave_max64(fmaxf(fmaxf(sv[0], sv[1]), fmaxf(sv[2], sv[3])));
      unsigned T = 0u;
      for (int bit = 31; bit >= 0; --bit) {
        unsigned T2 = T | (1u << bit);
        int c = __popcll(__ballot(um[0] >= T2)) + __popcll(__ballot(um[1] >= T2))
              + __popcll(__ballot(um[2] >= T2)) + __popcll(__ballot(um[3] >= T2));
        if (c >= kp) { T = T2; if (c == kp) break; }
      }
      int c_gt = __popcll(__ballot(um[0] > T)) + __popcll(__ballot(um[1] > T))
               + __popcll(__ballot(um[2] > T)) + __popcll(__ballot(um[3] > T));
      u64 beq[4];
#pragma unroll
      for (int e = 0; e < 4; ++e) beq[e] = __ballot(um[e] == T);
      int trbase = __popcll(beq[0] & lmask) + __popcll(beq[1] & lmask)
                 + __popcll(beq[2] & lmask) + __popcll(beq[3] & lmask);
      int need = kp - c_gt;
      bool msk[4];
      int own = 0;
#pragma unroll
      for (int e = 0; e < 4; ++e) {
        bool eq = (um[e] == T);
        msk[e] = (um[e] > T) || (eq && (trbase + own) < need);
        own += eq ? 1 : 0;
      }
      float ez[4], zs = 0.f;
#pragma unroll
      for (int e = 0; e < 4; ++e) { ez[e] = msk[e] ? __expf(sv[e] - m) : 0.f; zs += ez[e]; }
      zs = wave_sum64(zs);
      float at[4];
#pragma unroll
      for (int e = 0; e < 4; ++e) at[e] = ez[e] / zs;
      if (lvl > 0) {
        size_t baseLo = ((((size_t)b * prev_ng + plo_) * 8 + h) * GS + i) * WIN + lane * 4;
        size_t baseHi = ((((size_t)b * prev_ng + phi_) * 8 + h) * GS + i) * WIN + lane * 4;
        uint2 rlo = *reinterpret_cast<const uint2*>(prevA + baseLo);
        uint2 rhi = *reinterpret_cast<const uint2*>(prevA + baseHi);
        float pl[4] = { b2f_lo(rlo.x), b2f_hi(rlo.x), b2f_lo(rlo.y), b2f_hi(rlo.y) };
        float ph[4] = { b2f_lo(rhi.x), b2f_hi(rhi.x), b2f_lo(rhi.y), b2f_hi(rhi.y) };
        // prior rows are stored normalized; skip re-normalizing reduction
#pragma unroll
        for (int e = 0; e < 4; ++e) {
          float pr = fmaxf((1.f - wgt) * pl[e] + wgt * ph[e], 0.f);
          at[e] = (1.f - beta) * at[e] + beta * pr;
        }
      }
      atp[half * 4 + j][0] = (unsigned)f2b(at[0]) | ((unsigned)f2b(at[1]) << 16);
      atp[half * 4 + j][1] = (unsigned)f2b(at[2]) | ((unsigned)f2b(at[3]) << 16);
      if (curA != nullptr) {
        uint2 o = { atp[half * 4 + j][0], atp[half * 4 + j][1] };
        *reinterpret_cast<uint2*>(curA + ((size_t)bgh * GS + i) * WIN + lane * 4) = o;
      }
    }
    __syncthreads();   // S half consumed before next half's write / P_half
  }

  // ---- PV via MFMA: O(64x64) = P(64x256) @ V(256x64), per-j-half P ----
  const u16* vbase = vbf + (size_t)b * n_l * DIMC + h * DV;
  int rf   = wave >> 1;                  // q-row frag 0..3
  int cf0  = (wave & 1) * 2;             // dv col frag base {0,2}
  int frow = lane & 15;
  int fk   = (lane >> 4) * 8;
  f32x4 oacc0 = { 0.f, 0.f, 0.f, 0.f };
  f32x4 oacc1 = { 0.f, 0.f, 0.f, 0.f };
  int jlo = t & 15, vd4 = (t >> 4) & 15, jh2 = t >> 8;

#pragma unroll
  for (int jp = 0; jp < 2; ++jp) {
    // stage Vt half (transposed V)
#pragma unroll
    for (int it = 0; it < 4; ++it) {
      int j = (jh2 * 4 + it) * 16 + jlo;           // 0..127
      int pp = g * GS + jp * 128 + j;
      int src = (pp < n_l) ? pp : (2 * n_l - 1 - pp);
      ushort4 vv = *reinterpret_cast<const ushort4*>(vbase + (size_t)src * DIMC + vd4 * 4);
      Vt[(vd4 * 4 + 0) * 136 + j] = vv.x;
      Vt[(vd4 * 4 + 1) * 136 + j] = vv.y;
      Vt[(vd4 * 4 + 2) * 136 + j] = vv.z;
      Vt[(vd4 * 4 + 3) * 136 + j] = vv.w;
    }
    // write this half's P from retained regs (lanes owning these keys)
    if ((lane >> 5) == jp) {
      int kl = (lane & 31) * 4;          // local key base within half
#pragma unroll
      for (int j = 0; j < 4; ++j) {
        uint2 oA = { atp[j][0], atp[j][1] };
        uint2 oB = { atp[4 + j][0], atp[4 + j][1] };
        *reinterpret_cast<uint2*>(&P_half[(wave * 4 + j) * 136 + kl]) = oA;
        *reinterpret_cast<uint2*>(&P_half[(32 + wave * 4 + j) * 136 + kl]) = oB;
      }
    }
    __syncthreads();
    __builtin_amdgcn_s_setprio(1);
#pragma unroll
    for (int ks = 0; ks < 4; ++ks) {
      bf16x8 a  = *reinterpret_cast<const bf16x8*>(&P_half[(rf * 16 + frow) * 136 + ks * 32 + fk]);
      bf16x8 b0 = *reinterpret_cast<const bf16x8*>(&Vt[(cf0 * 16 + frow) * 136 + ks * 32 + fk]);
      bf16x8 b1 = *reinterpret_cast<const bf16x8*>(&Vt[((cf0 + 1) * 16 + frow) * 136 + ks * 32 + fk]);
      oacc0 = __builtin_amdgcn_mfma_f32_16x16x32_bf16(a, b0, oacc0, 0, 0, 0);
      oacc1 = __builtin_amdgcn_mfma_f32_16x16x32_bf16(a, b1, oacc1, 0, 0, 0);
    }
    __builtin_amdgcn_s_setprio(0);
    __syncthreads();
  }

  u16* obase = outp + ((size_t)b * n_l + (size_t)g * GS + p * 64 + rf * 16) * DIMC + h * DV;
#pragma unroll
  for (int rr = 0; rr < 4; ++rr) {
    int qrow = (lane >> 4) * 4 + rr;
    obase[(size_t)qrow * DIMC + cf0 * 16 + frow]       = f2b(oacc0[rr]);
    obase[(size_t)qrow * DIMC + (cf0 + 1) * 16 + frow] = f2b(oacc1[rr]);
  }
}

// ---------------------------------------------------------------------------
extern "C" void kernel_launch(void* const* d_in, const int* in_sizes, int n_in,
                              void* d_out, int out_size, void* d_ws, size_t ws_size,
                              hipStream_t stream) {
  (void)in_sizes; (void)n_in; (void)out_size; (void)ws_size;
  const float* x        = (const float*)d_in[0];
  const int*   labels   = (const int*)d_in[1];
  const float* scores   = (const float*)d_in[2];
  const int*   idx_last = (const int*)d_in[3];
  const float* Wq       = (const float*)d_in[4];
  const float* Wk       = (const float*)d_in[5];
  const float* Wv       = (const float*)d_in[6];
  const float* Wp       = (const float*)d_in[7];
  const float* betaL    = (const float*)d_in[8];
  float* out = (float*)d_out;

  char* w = (char*)d_ws;
  size_t off = 0;
  auto take = [&](size_t bytes) -> char* {
    char* p = w + off;
    off += (bytes + 255) & ~(size_t)255;
    return p;
  };
  u16*   qhib   = (u16*)  take(16777216);   // q hi bf16 (16384 rows x 512)
  u16*   qlob   = (u16*)  take(16777216);   // q lo
  u16*   khib   = (u16*)  take(16777216);   // k hi
  u16*   klob   = (u16*)  take(16777216);   // k lo
  u16*   vbf    = (u16*)  take(16777216);   // v bf16
  u16*   xhi    = (u16*)  take(16777216);   // pooled x hi -> lvl0/1 attn outs
  u16*   xlo    = (u16*)  take(16777216);   // pooled x lo
  u16*   attnA  = (u16*)  take(16777216);   // lvl0 attn state / lvl2 x-hi / lvl2 attn out
  u16*   attnB  = (u16*)  take(33554432);   // lvl1 attn bf16
  u16*   x2lo   = (u16*)  take(16777216);   // lvl2 x lo
  u16*   whiAll = (u16*)  take(6291456);    // 12 x [512][512] bf16 hi
  u16*   wloAll = (u16*)  take(3145728);    // 6  x [512][512] bf16 lo (q,k)
  float* sl     = (float*)take(65536);      // pooled scores lvl0 [0,4096) lvl1 [4096,12288)
  int*   ll     = (int*)  take(65536);      // pooled labels, same offsets
  int*   keepb  = (int*)  take(1024);       // keep: lvl0 @0, lvl1 @32, lvl2 @96
  // total ~194 MB

  const size_t ROW1 = 4096;                 // lvl1 row offset in shared buffers

  wprep_kernel<<<3072, 256, 0, stream>>>(Wq, Wk, Wv, Wp, whiAll, wloAll);
  pool_fused_kernel<<<2048, 256, 0, stream>>>(x, scores, xhi, xlo, sl);
  pool_label01_kernel<<<48, 256, 0, stream>>>(labels, scores, ll);
  keep_all_kernel<<<2, 128, 0, stream>>>(ll, sl, labels, scores, keepb);

  {
    dim3 gq(12, 96);
    qkv_gemm_kernel<<<gq, 256, 0, stream>>>(xhi, xlo, whiAll, wloAll,
                                            qhib, qlob, khib, klob, vbf,
                                            0, 1, 32, (int)ROW1);
  }

  // ---- level 0: attn output -> xhi rows [0,4096) (pooled x consumed) ----
  attn_fused_kernel<<<2 * 16 * 8 * 2, 512, 0, stream>>>(
      qhib, qlob, khib, klob, vbf, keepb, nullptr, attnA,
      betaL, xhi, 0, 2048, 16, 8);

  // ---- level 1: attn output -> xhi rows [4096,12288) ----
  attn_fused_kernel<<<2 * 32 * 8 * 2, 512, 0, stream>>>(
      qhib + ROW1 * DIMC, qlob + ROW1 * DIMC, khib + ROW1 * DIMC, klob + ROW1 * DIMC,
      vbf + ROW1 * DIMC, keepb + 32, attnA, attnB,
      betaL, xhi + ROW1 * DIMC, 1, 4096, 32, 16);

  // ---- level 2: x split -> attnA(hi)/x2lo(lo) (attnA dead after attn1) ----
  asplit_kernel<<<(2 * NTOK * 128) / 256, 256, 0, stream>>>(x, attnA, x2lo);
  {
    dim3 gq(12, 128);
    qkv_gemm_kernel<<<gq, 256, 0, stream>>>(attnA, x2lo, whiAll, wloAll,
                                            qhib, qlob, khib, klob, vbf,
                                            2, 2, 1 << 20, 0);
  }
  // attn2 output -> attnA (free again after qkv2 consumed it)
  attn_fused_kernel<<<2 * 64 * 8 * 2, 512, 0, stream>>>(
      qhib, qlob, khib, klob, vbf, keepb + 96, attnB, nullptr,
      betaL, attnA, 2, 8192, 64, 32);

  // ---- merged Wp: all 3 levels, single launch, pure stores ----
  {
    dim3 gp(4, 128);
    wp_merged_kernel<<<gp, 256, 0, stream>>>(xhi, attnA, whiAll, out, idx_last);
  }
}